// Round 1
// baseline (669.338 us; speedup 1.0000x reference)
//
#include <hip/hip_runtime.h>
#include <hip/hip_bf16.h>

#define NDIM 128
#define NHEAD 8
#define EPSV 1e-5f

// ============ BN stats (column mean/var over rows) ============
__global__ __launch_bounds__(256) void k_bn_stats(const float* __restrict__ x, float* __restrict__ sums, int N){
  // sums[0:128] = sum, sums[128:256] = sumsq
  __shared__ float ls[256], ls2[256];
  int t = threadIdx.x, col = t & 127, half = t >> 7;
  int r0 = blockIdx.x * 128; int r1 = r0 + 128; if (r1 > N) r1 = N;
  float s = 0.f, s2 = 0.f;
  for (int r = r0 + half; r < r1; r += 2){ float v = x[(size_t)r*NDIM + col]; s += v; s2 += v*v; }
  ls[t] = s; ls2[t] = s2; __syncthreads();
  if (t < 128){ atomicAdd(&sums[col], ls[t] + ls[t+128]); atomicAdd(&sums[128+col], ls2[t] + ls2[t+128]); }
}

__global__ __launch_bounds__(128) void k_bn_final(const float* __restrict__ sums, const float* __restrict__ g,
                                                  const float* __restrict__ b, float* __restrict__ scsh, int N){
  int c = threadIdx.x;
  float mean = sums[c] / (float)N;
  float var  = sums[128+c] / (float)N - mean*mean;
  float rstd = rsqrtf(var + EPSV);
  float sc = g[c] * rstd;
  scsh[c] = sc; scsh[128+c] = b[c] - mean*sc;
}

// ============ BN1-apply + QKV projection ============
__global__ __launch_bounds__(256) void k_qkv(const float* __restrict__ h, const float* __restrict__ scsh,
                                             const float* __restrict__ Wq, const float* __restrict__ Wk, const float* __restrict__ Wv,
                                             float* __restrict__ Q, float* __restrict__ K, float* __restrict__ V, int N){
  __shared__ float hn[32][NDIM];
  int t = threadIdx.x; int r0 = blockIdx.x * 32;
  #pragma unroll
  for (int i = 0; i < 16; i++){
    int idx = t + 256*i; int r = idx >> 7, c = idx & 127; int rr = r0 + r;
    hn[r][c] = (rr < N) ? h[(size_t)rr*NDIM + c] * scsh[c] + scsh[128+c] : 0.f;
  }
  __syncthreads();
  int col = t & 127, half = t >> 7;
  float aq[16], ak[16], av[16];
  #pragma unroll
  for (int i = 0; i < 16; i++){ aq[i]=0.f; ak[i]=0.f; av[i]=0.f; }
  for (int k0 = 0; k0 < NDIM; k0 += 4){
    float wq[4], wk[4], wv[4];
    #pragma unroll
    for (int j = 0; j < 4; j++){
      wq[j] = Wq[(size_t)(k0+j)*NDIM + col];
      wk[j] = Wk[(size_t)(k0+j)*NDIM + col];
      wv[j] = Wv[(size_t)(k0+j)*NDIM + col];
    }
    #pragma unroll
    for (int i = 0; i < 16; i++){
      float4 xv = *(const float4*)&hn[half + 2*i][k0];
      aq[i] += xv.x*wq[0] + xv.y*wq[1] + xv.z*wq[2] + xv.w*wq[3];
      ak[i] += xv.x*wk[0] + xv.y*wk[1] + xv.z*wk[2] + xv.w*wk[3];
      av[i] += xv.x*wv[0] + xv.y*wv[1] + xv.z*wv[2] + xv.w*wv[3];
    }
  }
  #pragma unroll
  for (int i = 0; i < 16; i++){
    int rr = r0 + half + 2*i;
    if (rr < N){
      Q[(size_t)rr*NDIM + col] = aq[i];
      K[(size_t)rr*NDIM + col] = ak[i];
      V[(size_t)rr*NDIM + col] = av[i];
    }
  }
}

// ============ CSR build ============
__global__ __launch_bounds__(256) void k_deg(const int* __restrict__ dst, int* __restrict__ deg, int E){
  int e = blockIdx.x*256 + threadIdx.x;
  if (e < E) atomicAdd(&deg[dst[e]], 1);
}

__global__ __launch_bounds__(256) void k_scan_part(const int* __restrict__ deg, int* __restrict__ bsum, int N){
  __shared__ int ls[256];
  int t = threadIdx.x; int i = blockIdx.x*256 + t;
  ls[t] = (i < N) ? deg[i] : 0; __syncthreads();
  for (int off = 128; off > 0; off >>= 1){
    if (t < off) ls[t] += ls[t + off];
    __syncthreads();
  }
  if (t == 0) bsum[blockIdx.x] = ls[0];
}

__global__ __launch_bounds__(256) void k_scan_top(int* __restrict__ bsum, int nb, int* __restrict__ rowptr, int N, int E){
  __shared__ int ls[256];
  int t = threadIdx.x;
  int v = (t < nb) ? bsum[t] : 0; ls[t] = v; __syncthreads();
  for (int off = 1; off < 256; off <<= 1){
    int add = (t >= off) ? ls[t - off] : 0;
    __syncthreads();
    ls[t] += add;
    __syncthreads();
  }
  if (t < nb) bsum[t] = ls[t] - v;      // exclusive
  if (t == 0) rowptr[N] = E;
}

__global__ __launch_bounds__(256) void k_scan_down(const int* __restrict__ deg, const int* __restrict__ bsum,
                                                   int* __restrict__ rowptr, int N){
  __shared__ int ls[256];
  int t = threadIdx.x; int i = blockIdx.x*256 + t;
  int v = (i < N) ? deg[i] : 0; ls[t] = v; __syncthreads();
  for (int off = 1; off < 256; off <<= 1){
    int add = (t >= off) ? ls[t - off] : 0;
    __syncthreads();
    ls[t] += add;
    __syncthreads();
  }
  if (i < N) rowptr[i] = ls[t] - v + bsum[blockIdx.x];
}

__global__ __launch_bounds__(256) void k_scatter(const int* __restrict__ src, const int* __restrict__ dst,
                                                 int* __restrict__ cursor, int* __restrict__ csr_src,
                                                 int* __restrict__ csr_eid, int E){
  int e = blockIdx.x*256 + threadIdx.x;
  if (e < E){
    int d = dst[e];
    int slot = atomicAdd(&cursor[d], 1);
    csr_src[slot] = src[e];
    csr_eid[slot] = e;
  }
}

// ============ edge scores ============
__global__ __launch_bounds__(256) void k_score(const int* __restrict__ src, const int* __restrict__ dst,
                                               const float* __restrict__ Q, const float* __restrict__ K,
                                               float* __restrict__ score, int E){
  int tid = blockIdx.x*256 + threadIdx.x;
  if (tid >= E*NHEAD) return;
  int e = tid >> 3, hh = tid & 7;
  const float4* kr = (const float4*)(K + (size_t)src[e]*NDIM + hh*16);
  const float4* qr = (const float4*)(Q + (size_t)dst[e]*NDIM + hh*16);
  float acc = 0.f;
  #pragma unroll
  for (int i = 0; i < 4; i++){
    float4 a = kr[i], b = qr[i];
    acc += a.x*b.x + a.y*b.y + a.z*b.z + a.w*b.w;
  }
  acc *= 0.25f;
  acc = fminf(5.f, fmaxf(-5.f, acc));
  score[tid] = acc;
}

// ============ per-node softmax + weighted V aggregation ============
__global__ __launch_bounds__(64) void k_agg(const int* __restrict__ rowptr, const int* __restrict__ csr_src,
                                            const int* __restrict__ csr_eid, const float* __restrict__ score,
                                            const float* __restrict__ V, float* __restrict__ wV){
  int n = blockIdx.x;
  int e0 = rowptr[n], e1 = rowptr[n+1]; int deg = e1 - e0;
  int l = threadIdx.x; int hh = l >> 3, j = l & 7;
  float m = -1e30f;
  for (int i = j; i < deg; i += 8){ int eid = csr_eid[e0+i]; m = fmaxf(m, score[(size_t)eid*NHEAD + hh]); }
  m = fmaxf(m, __shfl_xor(m, 1)); m = fmaxf(m, __shfl_xor(m, 2)); m = fmaxf(m, __shfl_xor(m, 4));
  float ssum = 0.f;
  for (int i = j; i < deg; i += 8){ int eid = csr_eid[e0+i]; ssum += __expf(score[(size_t)eid*NHEAD + hh] - m); }
  ssum += __shfl_xor(ssum, 1); ssum += __shfl_xor(ssum, 2); ssum += __shfl_xor(ssum, 4);
  float inv = (deg > 0) ? 1.f / ssum : 0.f;
  int d0 = l * 2;
  float a0 = 0.f, a1 = 0.f;
  for (int i = 0; i < deg; i++){
    int eid = csr_eid[e0+i]; int s = csr_src[e0+i];
    float w = __expf(score[(size_t)eid*NHEAD + hh] - m) * inv;
    float2 v = *(const float2*)(V + (size_t)s*NDIM + d0);
    a0 += w * v.x; a1 += w * v.y;
  }
  *(float2*)(wV + (size_t)n*NDIM + d0) = make_float2(a0, a1);
}

// ============ O-projection + residual + BN2 stats ============
__global__ __launch_bounds__(256) void k_h2(const float* __restrict__ wV, const float* __restrict__ Wo,
                                            const float* __restrict__ bo, const float* __restrict__ h,
                                            float* __restrict__ h2, float* __restrict__ sums2, int N){
  __shared__ float tw[32][NDIM];
  __shared__ float r0s[256], r1s[256], r0q[256], r1q[256];
  int t = threadIdx.x; int r0 = blockIdx.x * 32;
  #pragma unroll
  for (int i = 0; i < 16; i++){
    int idx = t + 256*i; int r = idx >> 7, c = idx & 127; int rr = r0 + r;
    tw[r][c] = (rr < N) ? wV[(size_t)rr*NDIM + c] : 0.f;
  }
  __syncthreads();
  int cq = t & 63, q = t >> 6; int c0 = 2*cq;
  float a0[8], a1[8];
  #pragma unroll
  for (int i = 0; i < 8; i++){ a0[i]=0.f; a1[i]=0.f; }
  for (int k0 = 0; k0 < NDIM; k0 += 4){
    float w0[4], w1[4];
    #pragma unroll
    for (int j = 0; j < 4; j++){
      float2 ww = *(const float2*)(Wo + (size_t)(k0+j)*NDIM + c0);
      w0[j] = ww.x; w1[j] = ww.y;
    }
    #pragma unroll
    for (int i = 0; i < 8; i++){
      float4 xv = *(const float4*)&tw[q + 4*i][k0];
      a0[i] += xv.x*w0[0] + xv.y*w0[1] + xv.z*w0[2] + xv.w*w0[3];
      a1[i] += xv.x*w1[0] + xv.y*w1[1] + xv.z*w1[2] + xv.w*w1[3];
    }
  }
  float bo0 = bo[c0], bo1 = bo[c0+1];
  float s0=0.f, s1=0.f, q0=0.f, q1=0.f;
  #pragma unroll
  for (int i = 0; i < 8; i++){
    int rr = r0 + q + 4*i;
    if (rr < N){
      float2 hv = *(const float2*)(h + (size_t)rr*NDIM + c0);
      float v0 = a0[i] + bo0 + hv.x;
      float v1 = a1[i] + bo1 + hv.y;
      *(float2*)(h2 + (size_t)rr*NDIM + c0) = make_float2(v0, v1);
      s0 += v0; q0 += v0*v0; s1 += v1; q1 += v1*v1;
    }
  }
  r0s[t]=s0; r1s[t]=s1; r0q[t]=q0; r1q[t]=q1; __syncthreads();
  if (t < 64){
    float S0=0.f,S1=0.f,Q0=0.f,Q1=0.f;
    #pragma unroll
    for (int qq = 0; qq < 4; qq++){ S0+=r0s[t+64*qq]; S1+=r1s[t+64*qq]; Q0+=r0q[t+64*qq]; Q1+=r1q[t+64*qq]; }
    atomicAdd(&sums2[2*t],   S0); atomicAdd(&sums2[2*t+1],   S1);
    atomicAdd(&sums2[128+2*t], Q0); atomicAdd(&sums2[128+2*t+1], Q1);
  }
}

// ============ BN2-apply + FFN + residual ============
__global__ __launch_bounds__(256) void k_ffn(const float* __restrict__ h2, const float* __restrict__ scsh,
                                             const float* __restrict__ W1, const float* __restrict__ b1,
                                             const float* __restrict__ W2, const float* __restrict__ b2,
                                             float* __restrict__ out, int N){
  __shared__ float x[32][NDIM];
  __shared__ float tt[32][2*NDIM];
  int t = threadIdx.x; int r0 = blockIdx.x * 32;
  #pragma unroll
  for (int i = 0; i < 16; i++){
    int idx = t + 256*i; int r = idx >> 7, c = idx & 127; int rr = r0 + r;
    x[r][c] = (rr < N) ? h2[(size_t)rr*NDIM + c] * scsh[c] + scsh[128+c] : 0.f;
  }
  __syncthreads();
  {
    int cp = t & 127, half = t >> 7; int c0 = 2*cp;
    float a0[16], a1[16];
    #pragma unroll
    for (int i = 0; i < 16; i++){ a0[i]=0.f; a1[i]=0.f; }
    for (int k0 = 0; k0 < NDIM; k0 += 4){
      float w0[4], w1[4];
      #pragma unroll
      for (int j = 0; j < 4; j++){
        float2 ww = *(const float2*)(W1 + (size_t)(k0+j)*256 + c0);
        w0[j] = ww.x; w1[j] = ww.y;
      }
      #pragma unroll
      for (int i = 0; i < 16; i++){
        float4 xv = *(const float4*)&x[half + 2*i][k0];
        a0[i] += xv.x*w0[0] + xv.y*w0[1] + xv.z*w0[2] + xv.w*w0[3];
        a1[i] += xv.x*w1[0] + xv.y*w1[1] + xv.z*w1[2] + xv.w*w1[3];
      }
    }
    float bb0 = b1[c0], bb1 = b1[c0+1];
    #pragma unroll
    for (int i = 0; i < 16; i++){
      int r = half + 2*i;
      tt[r][c0]   = fmaxf(a0[i] + bb0, 0.f);
      tt[r][c0+1] = fmaxf(a1[i] + bb1, 0.f);
    }
  }
  __syncthreads();
  {
    int cq = t & 63, q = t >> 6; int c0 = 2*cq;
    float a0[8], a1[8];
    #pragma unroll
    for (int i = 0; i < 8; i++){ a0[i]=0.f; a1[i]=0.f; }
    for (int k0 = 0; k0 < 2*NDIM; k0 += 4){
      float w0[4], w1[4];
      #pragma unroll
      for (int j = 0; j < 4; j++){
        float2 ww = *(const float2*)(W2 + (size_t)(k0+j)*NDIM + c0);
        w0[j] = ww.x; w1[j] = ww.y;
      }
      #pragma unroll
      for (int i = 0; i < 8; i++){
        float4 xv = *(const float4*)&tt[q + 4*i][k0];
        a0[i] += xv.x*w0[0] + xv.y*w0[1] + xv.z*w0[2] + xv.w*w0[3];
        a1[i] += xv.x*w1[0] + xv.y*w1[1] + xv.z*w1[2] + xv.w*w1[3];
      }
    }
    float bb0 = b2[c0], bb1 = b2[c0+1];
    #pragma unroll
    for (int i = 0; i < 8; i++){
      int rr = r0 + q + 4*i;
      if (rr < N){
        float2 hv = *(const float2*)(h2 + (size_t)rr*NDIM + c0);
        *(float2*)(out + (size_t)rr*NDIM + c0) = make_float2(hv.x + a0[i] + bb0, hv.y + a1[i] + bb1);
      }
    }
  }
}

extern "C" void kernel_launch(void* const* d_in, const int* in_sizes, int n_in,
                              void* d_out, int out_size, void* d_ws, size_t ws_size,
                              hipStream_t stream) {
  const float* h    = (const float*)d_in[0];
  const int*   src  = (const int*)d_in[1];
  const int*   dst  = (const int*)d_in[2];
  const float* Wq   = (const float*)d_in[3];
  const float* Wk   = (const float*)d_in[4];
  const float* Wv   = (const float*)d_in[5];
  const float* Wo   = (const float*)d_in[6];
  const float* bo   = (const float*)d_in[7];
  const float* bn1g = (const float*)d_in[8];
  const float* bn1b = (const float*)d_in[9];
  const float* bn2g = (const float*)d_in[10];
  const float* bn2b = (const float*)d_in[11];
  const float* W1   = (const float*)d_in[12];
  const float* b1   = (const float*)d_in[13];
  const float* W2   = (const float*)d_in[14];
  const float* b2   = (const float*)d_in[15];
  float* out = (float*)d_out;

  int N = in_sizes[0] / NDIM;
  int E = in_sizes[1];
  size_t fN = (size_t)N * NDIM;

  float* Q     = (float*)d_ws;
  float* Kb    = Q + fN;
  float* V     = Kb + fN;
  float* score = V + fN;                       // E*NHEAD floats
  float* wV    = Q;                            // reuse (Q dead after k_score)
  float* h2    = Kb;                           // reuse (K dead after k_score)
  int* deg     = (int*)(score + (size_t)E*NHEAD);
  int* rowptr  = deg + N;                      // N+1
  int* cursor  = rowptr + (N + 1);             // N
  int* bsum    = cursor + N;                   // 256
  int* csr_src = bsum + 256;                   // E
  int* csr_eid = csr_src + E;                  // E
  float* sums1 = (float*)(csr_eid + E);        // 256
  float* sums2 = sums1 + 256;                  // 256
  float* scsh1 = sums2 + 256;                  // 256
  float* scsh2 = scsh1 + 256;                  // 256

  hipMemsetAsync(deg, 0, (size_t)N * sizeof(int), stream);
  hipMemsetAsync(sums1, 0, 512 * sizeof(float), stream);

  int nb = (N + 255) / 256;

  k_bn_stats<<<(N + 127) / 128, 256, 0, stream>>>(h, sums1, N);
  k_bn_final<<<1, 128, 0, stream>>>(sums1, bn1g, bn1b, scsh1, N);
  k_qkv<<<(N + 31) / 32, 256, 0, stream>>>(h, scsh1, Wq, Wk, Wv, Q, Kb, V, N);

  k_deg<<<(E + 255) / 256, 256, 0, stream>>>(dst, deg, E);
  k_scan_part<<<nb, 256, 0, stream>>>(deg, bsum, N);
  k_scan_top<<<1, 256, 0, stream>>>(bsum, nb, rowptr, N, E);
  k_scan_down<<<nb, 256, 0, stream>>>(deg, bsum, rowptr, N);
  hipMemcpyAsync(cursor, rowptr, (size_t)N * sizeof(int), hipMemcpyDeviceToDevice, stream);
  k_scatter<<<(E + 255) / 256, 256, 0, stream>>>(src, dst, cursor, csr_src, csr_eid, E);

  k_score<<<((size_t)E * NHEAD + 255) / 256, 256, 0, stream>>>(src, dst, Q, Kb, score, E);
  k_agg<<<N, 64, 0, stream>>>(rowptr, csr_src, csr_eid, score, V, wV);

  k_h2<<<(N + 31) / 32, 256, 0, stream>>>(wV, Wo, bo, h, h2, sums2, N);
  k_bn_final<<<1, 128, 0, stream>>>(sums2, bn2g, bn2b, scsh2, N);
  k_ffn<<<(N + 31) / 32, 256, 0, stream>>>(h2, scsh2, W1, b1, W2, b2, out, N);
}

// Round 2
// 415.975 us; speedup vs baseline: 1.6091x; 1.6091x over previous
//
#include <hip/hip_runtime.h>
#include <hip/hip_bf16.h>

#define NDIM 128
#define NHEAD 8
#define EPSV 1e-5f

typedef unsigned short u16;
using bf16x8 = __attribute__((ext_vector_type(8))) short;
using f32x4  = __attribute__((ext_vector_type(4))) float;
using us8    = __attribute__((ext_vector_type(8))) unsigned short;
using us4    = __attribute__((ext_vector_type(4))) unsigned short;

__device__ __forceinline__ u16 f2b(float x){
  union { float f; unsigned u; } v; v.f = x;
  unsigned r = v.u + 0x7FFFu + ((v.u >> 16) & 1u);
  return (u16)(r >> 16);
}
__device__ __forceinline__ float b2f(u16 u){
  union { unsigned u; float f; } v; v.u = ((unsigned)u) << 16; return v.f;
}

// A-frag: lane provides A[lane%16][(lane/16)*8 + j]; B-frag: B[(lane/16)*8+j][lane%16]
// C/D: col = lane&15, row = (lane>>4)*4 + reg   (measured m89)
template<int NT, int KS, int WTLD, int XSTR>
__device__ __forceinline__ void gemm_tiles(const u16* X, const u16* __restrict__ WT,
                                           int lr, int kg, int colbase, f32x4 (&acc)[NT][4]){
  #pragma unroll
  for (int ks = 0; ks < KS; ks++){
    bf16x8 a[4];
    #pragma unroll
    for (int m = 0; m < 4; m++)
      a[m] = *(const bf16x8*)(X + (size_t)(m*16 + lr)*XSTR + ks*32 + kg*8);
    #pragma unroll
    for (int n = 0; n < NT; n++){
      int col = colbase + n*16 + lr;
      bf16x8 b = *(const bf16x8*)(WT + (size_t)col*WTLD + ks*32 + kg*8);
      #pragma unroll
      for (int m = 0; m < 4; m++)
        acc[n][m] = __builtin_amdgcn_mfma_f32_16x16x32_bf16(a[m], b, acc[n][m], 0, 0, 0);
    }
  }
}

// ============ weight convert + transpose: W[rows][cols] f32 -> WT[cols][rows] bf16 ============
__global__ __launch_bounds__(256) void k_wconv(const float* __restrict__ W, u16* __restrict__ WT,
                                               int rows, int cols){
  int i = blockIdx.x*256 + threadIdx.x;
  if (i < rows*cols){
    int r = i / cols, c = i % cols;
    WT[(size_t)c*rows + r] = f2b(W[i]);
  }
}

// ============ BN stats ============
__global__ __launch_bounds__(256) void k_bn_stats(const float* __restrict__ x, float* __restrict__ sums, int N){
  __shared__ float ls[256], ls2[256];
  int t = threadIdx.x, col = t & 127, half = t >> 7;
  int r0 = blockIdx.x * 128; int r1 = r0 + 128; if (r1 > N) r1 = N;
  float s = 0.f, s2 = 0.f;
  for (int r = r0 + half; r < r1; r += 2){ float v = x[(size_t)r*NDIM + col]; s += v; s2 += v*v; }
  ls[t] = s; ls2[t] = s2; __syncthreads();
  if (t < 128){ atomicAdd(&sums[col], ls[t] + ls[t+128]); atomicAdd(&sums[128+col], ls2[t] + ls2[t+128]); }
}

__global__ __launch_bounds__(128) void k_bn_final(const float* __restrict__ sums, const float* __restrict__ g,
                                                  const float* __restrict__ b, float* __restrict__ scsh, int N){
  int c = threadIdx.x;
  float mean = sums[c] / (float)N;
  float var  = sums[128+c] / (float)N - mean*mean;
  float rstd = rsqrtf(var + EPSV);
  float sc = g[c] * rstd;
  scsh[c] = sc; scsh[128+c] = b[c] - mean*sc;
}

// ============ BN1-apply + QKV projection (MFMA) ============
__global__ __launch_bounds__(256) void k_qkv(const float* __restrict__ h, const float* __restrict__ scsh,
                                             const u16* __restrict__ WTq, const u16* __restrict__ WTk, const u16* __restrict__ WTv,
                                             u16* __restrict__ Q, u16* __restrict__ K, u16* __restrict__ V, int N){
  __shared__ u16 hn[64][136];
  int t = threadIdx.x; int r0 = blockIdx.x * 64;
  {
    int row = t >> 2, c0 = (t & 3) * 32; int rr = r0 + row;
    #pragma unroll
    for (int j = 0; j < 8; j++){
      int c = c0 + 4*j;
      float4 v = make_float4(0.f,0.f,0.f,0.f);
      if (rr < N) v = *(const float4*)(h + (size_t)rr*NDIM + c);
      us4 o;
      o.x = f2b(v.x * scsh[c]   + scsh[128+c]);
      o.y = f2b(v.y * scsh[c+1] + scsh[129+c]);
      o.z = f2b(v.z * scsh[c+2] + scsh[130+c]);
      o.w = f2b(v.w * scsh[c+3] + scsh[131+c]);
      *(us4*)&hn[row][c] = o;
    }
  }
  __syncthreads();
  int lane = t & 63, w = t >> 6;
  int lr = lane & 15, kg = lane >> 4;
  f32x4 zero = {0.f,0.f,0.f,0.f};

  #define DO_PASS(WT, OUT) { \
    f32x4 acc[2][4]; \
    _Pragma("unroll") for (int n = 0; n < 2; n++) _Pragma("unroll") for (int m = 0; m < 4; m++) acc[n][m] = zero; \
    gemm_tiles<2,4,128,136>(&hn[0][0], WT, lr, kg, w*32, acc); \
    _Pragma("unroll") for (int n = 0; n < 2; n++){ \
      int col = w*32 + n*16 + lr; \
      _Pragma("unroll") for (int m = 0; m < 4; m++) \
        _Pragma("unroll") for (int r = 0; r < 4; r++){ \
          int rr = r0 + m*16 + kg*4 + r; \
          if (rr < N) OUT[(size_t)rr*NDIM + col] = f2b(acc[n][m][r]); \
        } \
    } }
  DO_PASS(WTq, Q)
  DO_PASS(WTk, K)
  DO_PASS(WTv, V)
  #undef DO_PASS
}

// ============ CSR build ============
__global__ __launch_bounds__(256) void k_deg(const int* __restrict__ dst, int* __restrict__ deg, int E){
  int e = blockIdx.x*256 + threadIdx.x;
  if (e < E) atomicAdd(&deg[dst[e]], 1);
}

__global__ __launch_bounds__(256) void k_scan_part(const int* __restrict__ deg, int* __restrict__ bsum, int N){
  __shared__ int ls[256];
  int t = threadIdx.x; int i = blockIdx.x*256 + t;
  ls[t] = (i < N) ? deg[i] : 0; __syncthreads();
  for (int off = 128; off > 0; off >>= 1){
    if (t < off) ls[t] += ls[t + off];
    __syncthreads();
  }
  if (t == 0) bsum[blockIdx.x] = ls[0];
}

__global__ __launch_bounds__(256) void k_scan_top(int* __restrict__ bsum, int nb, int* __restrict__ rowptr, int N, int E){
  __shared__ int ls[256];
  int t = threadIdx.x;
  int v = (t < nb) ? bsum[t] : 0; ls[t] = v; __syncthreads();
  for (int off = 1; off < 256; off <<= 1){
    int add = (t >= off) ? ls[t - off] : 0;
    __syncthreads();
    ls[t] += add;
    __syncthreads();
  }
  if (t < nb) bsum[t] = ls[t] - v;
  if (t == 0) rowptr[N] = E;
}

__global__ __launch_bounds__(256) void k_scan_down(const int* __restrict__ deg, const int* __restrict__ bsum,
                                                   int* __restrict__ rowptr, int N){
  __shared__ int ls[256];
  int t = threadIdx.x; int i = blockIdx.x*256 + t;
  int v = (i < N) ? deg[i] : 0; ls[t] = v; __syncthreads();
  for (int off = 1; off < 256; off <<= 1){
    int add = (t >= off) ? ls[t - off] : 0;
    __syncthreads();
    ls[t] += add;
    __syncthreads();
  }
  if (i < N) rowptr[i] = ls[t] - v + bsum[blockIdx.x];
}

__global__ __launch_bounds__(256) void k_scatter(const int* __restrict__ src, const int* __restrict__ dst,
                                                 int* __restrict__ cursor, int* __restrict__ csr_src,
                                                 int* __restrict__ csr_eid, int E){
  int e = blockIdx.x*256 + threadIdx.x;
  if (e < E){
    int d = dst[e];
    int slot = atomicAdd(&cursor[d], 1);
    csr_src[slot] = src[e];
    csr_eid[slot] = e;
  }
}

// ============ edge scores (bf16 gathers) ============
__global__ __launch_bounds__(256) void k_score(const int* __restrict__ src, const int* __restrict__ dst,
                                               const u16* __restrict__ Q, const u16* __restrict__ K,
                                               float* __restrict__ score, int EH){
  int tid = blockIdx.x*256 + threadIdx.x;
  if (tid >= EH) return;
  int e = tid >> 3, hh = tid & 7;
  const us8* kr = (const us8*)(K + (size_t)src[e]*NDIM + hh*16);
  const us8* qr = (const us8*)(Q + (size_t)dst[e]*NDIM + hh*16);
  float acc = 0.f;
  #pragma unroll
  for (int i = 0; i < 2; i++){
    us8 a = kr[i], b = qr[i];
    #pragma unroll
    for (int j = 0; j < 8; j++) acc += b2f(a[j]) * b2f(b[j]);
  }
  acc *= 0.25f;
  acc = fminf(5.f, fmaxf(-5.f, acc));
  score[tid] = acc;
}

// ============ per-node softmax + weighted V aggregation ============
__global__ __launch_bounds__(64) void k_agg(const int* __restrict__ rowptr, const int* __restrict__ csr_src,
                                            const int* __restrict__ csr_eid, const float* __restrict__ score,
                                            const u16* __restrict__ V, u16* __restrict__ wV){
  int n = blockIdx.x;
  int e0 = rowptr[n], e1 = rowptr[n+1]; int deg = e1 - e0;
  int l = threadIdx.x; int hh = l >> 3, j = l & 7;
  float m = -1e30f;
  for (int i = j; i < deg; i += 8){ int eid = csr_eid[e0+i]; m = fmaxf(m, score[(size_t)eid*NHEAD + hh]); }
  m = fmaxf(m, __shfl_xor(m, 1)); m = fmaxf(m, __shfl_xor(m, 2)); m = fmaxf(m, __shfl_xor(m, 4));
  float ssum = 0.f;
  for (int i = j; i < deg; i += 8){ int eid = csr_eid[e0+i]; ssum += __expf(score[(size_t)eid*NHEAD + hh] - m); }
  ssum += __shfl_xor(ssum, 1); ssum += __shfl_xor(ssum, 2); ssum += __shfl_xor(ssum, 4);
  float inv = (deg > 0) ? 1.f / ssum : 0.f;
  int d0 = l * 2;
  float a0 = 0.f, a1 = 0.f;
  for (int i = 0; i < deg; i++){
    int eid = csr_eid[e0+i]; int s = csr_src[e0+i];
    float wgt = __expf(score[(size_t)eid*NHEAD + hh] - m) * inv;
    unsigned vv = *(const unsigned*)(V + (size_t)s*NDIM + d0);
    a0 += wgt * b2f((u16)(vv & 0xFFFFu));
    a1 += wgt * b2f((u16)(vv >> 16));
  }
  unsigned pk = (unsigned)f2b(a0) | ((unsigned)f2b(a1) << 16);
  *(unsigned*)(wV + (size_t)n*NDIM + d0) = pk;
}

// ============ O-projection + residual + BN2 stats (MFMA) ============
__global__ __launch_bounds__(256) void k_h2(const u16* __restrict__ wV, const u16* __restrict__ WTo,
                                            const float* __restrict__ bo, const float* __restrict__ h,
                                            float* __restrict__ h2, float* __restrict__ sums2, int N){
  __shared__ u16 tw[64][136];
  int t = threadIdx.x; int r0 = blockIdx.x * 64;
  {
    int row = t >> 2, c0 = (t & 3) * 32; int rr = r0 + row;
    #pragma unroll
    for (int j = 0; j < 4; j++){
      int c = c0 + 8*j;
      us8 v = {0,0,0,0,0,0,0,0};
      if (rr < N) v = *(const us8*)(wV + (size_t)rr*NDIM + c);
      *(us8*)&tw[row][c] = v;
    }
  }
  __syncthreads();
  int lane = t & 63, w = t >> 6;
  int lr = lane & 15, kg = lane >> 4;
  f32x4 zero = {0.f,0.f,0.f,0.f};
  f32x4 acc[2][4];
  #pragma unroll
  for (int n = 0; n < 2; n++)
    #pragma unroll
    for (int m = 0; m < 4; m++) acc[n][m] = zero;
  gemm_tiles<2,4,128,136>(&tw[0][0], WTo, lr, kg, w*32, acc);

  float sv[2] = {0.f, 0.f}, qv[2] = {0.f, 0.f};
  #pragma unroll
  for (int n = 0; n < 2; n++){
    int col = w*32 + n*16 + lr;
    float bb = bo[col];
    #pragma unroll
    for (int m = 0; m < 4; m++)
      #pragma unroll
      for (int r = 0; r < 4; r++){
        int rr = r0 + m*16 + kg*4 + r;
        if (rr < N){
          size_t o = (size_t)rr*NDIM + col;
          float v = acc[n][m][r] + bb + h[o];
          h2[o] = v;
          sv[n] += v; qv[n] += v*v;
        }
      }
  }
  #pragma unroll
  for (int n = 0; n < 2; n++){
    float s = sv[n], q = qv[n];
    s += __shfl_xor(s, 16); s += __shfl_xor(s, 32);
    q += __shfl_xor(q, 16); q += __shfl_xor(q, 32);
    if (kg == 0){
      int col = w*32 + n*16 + lr;
      atomicAdd(&sums2[col], s);
      atomicAdd(&sums2[128+col], q);
    }
  }
}

// ============ BN2-apply + FFN + residual (MFMA) ============
__global__ __launch_bounds__(256) void k_ffn(const float* __restrict__ h2, const float* __restrict__ scsh,
                                             const u16* __restrict__ WT1, const float* __restrict__ b1,
                                             const u16* __restrict__ WT2, const float* __restrict__ b2,
                                             float* __restrict__ out, int N){
  __shared__ u16 x[64][136];
  __shared__ u16 tt[64][264];
  int t = threadIdx.x; int r0 = blockIdx.x * 64;
  {
    int row = t >> 2, c0 = (t & 3) * 32; int rr = r0 + row;
    #pragma unroll
    for (int j = 0; j < 8; j++){
      int c = c0 + 4*j;
      float4 v = make_float4(0.f,0.f,0.f,0.f);
      if (rr < N) v = *(const float4*)(h2 + (size_t)rr*NDIM + c);
      us4 o;
      o.x = f2b(v.x * scsh[c]   + scsh[128+c]);
      o.y = f2b(v.y * scsh[c+1] + scsh[129+c]);
      o.z = f2b(v.z * scsh[c+2] + scsh[130+c]);
      o.w = f2b(v.w * scsh[c+3] + scsh[131+c]);
      *(us4*)&x[row][c] = o;
    }
  }
  __syncthreads();
  int lane = t & 63, w = t >> 6;
  int lr = lane & 15, kg = lane >> 4;
  f32x4 zero = {0.f,0.f,0.f,0.f};
  {
    f32x4 a1[4][4];
    #pragma unroll
    for (int n = 0; n < 4; n++)
      #pragma unroll
      for (int m = 0; m < 4; m++) a1[n][m] = zero;
    gemm_tiles<4,4,128,136>(&x[0][0], WT1, lr, kg, w*64, a1);
    #pragma unroll
    for (int n = 0; n < 4; n++){
      int col = w*64 + n*16 + lr;
      float bb = b1[col];
      #pragma unroll
      for (int m = 0; m < 4; m++)
        #pragma unroll
        for (int r = 0; r < 4; r++)
          tt[m*16 + kg*4 + r][col] = f2b(fmaxf(a1[n][m][r] + bb, 0.f));
    }
  }
  __syncthreads();
  {
    f32x4 a2[2][4];
    #pragma unroll
    for (int n = 0; n < 2; n++)
      #pragma unroll
      for (int m = 0; m < 4; m++) a2[n][m] = zero;
    gemm_tiles<2,8,256,264>(&tt[0][0], WT2, lr, kg, w*32, a2);
    #pragma unroll
    for (int n = 0; n < 2; n++){
      int col = w*32 + n*16 + lr;
      float bb = b2[col];
      #pragma unroll
      for (int m = 0; m < 4; m++)
        #pragma unroll
        for (int r = 0; r < 4; r++){
          int rr = r0 + m*16 + kg*4 + r;
          if (rr < N){
            size_t o = (size_t)rr*NDIM + col;
            out[o] = h2[o] + a2[n][m][r] + bb;
          }
        }
    }
  }
}

extern "C" void kernel_launch(void* const* d_in, const int* in_sizes, int n_in,
                              void* d_out, int out_size, void* d_ws, size_t ws_size,
                              hipStream_t stream) {
  const float* h    = (const float*)d_in[0];
  const int*   src  = (const int*)d_in[1];
  const int*   dst  = (const int*)d_in[2];
  const float* Wq   = (const float*)d_in[3];
  const float* Wk   = (const float*)d_in[4];
  const float* Wv   = (const float*)d_in[5];
  const float* Wo   = (const float*)d_in[6];
  const float* bo   = (const float*)d_in[7];
  const float* bn1g = (const float*)d_in[8];
  const float* bn1b = (const float*)d_in[9];
  const float* bn2g = (const float*)d_in[10];
  const float* bn2b = (const float*)d_in[11];
  const float* W1   = (const float*)d_in[12];
  const float* b1   = (const float*)d_in[13];
  const float* W2   = (const float*)d_in[14];
  const float* b2   = (const float*)d_in[15];
  float* out = (float*)d_out;

  int N = in_sizes[0] / NDIM;
  int E = in_sizes[1];
  size_t fN = (size_t)N * NDIM;

  u16* Q  = (u16*)d_ws;
  u16* K  = Q + fN;
  u16* V  = K + fN;
  u16* wV = Q;                                  // reuse: Q dead after k_score
  float* score = (float*)(V + fN);              // E*NHEAD floats
  float* h2    = score + (size_t)E*NHEAD;       // fN floats
  int* deg     = (int*)(h2 + fN);
  int* rowptr  = deg + N;
  int* cursor  = rowptr + (N + 1);
  int* bsum    = cursor + N;
  int* csr_src = bsum + 256;
  int* csr_eid = csr_src + E;
  float* sums1 = (float*)(csr_eid + E);
  float* sums2 = sums1 + 256;
  float* scsh1 = sums2 + 256;
  float* scsh2 = scsh1 + 256;
  u16* wtq = (u16*)(scsh2 + 256);
  u16* wtk = wtq + NDIM*NDIM;
  u16* wtv = wtk + NDIM*NDIM;
  u16* wto = wtv + NDIM*NDIM;
  u16* wt1 = wto + NDIM*NDIM;
  u16* wt2 = wt1 + NDIM*2*NDIM;

  hipMemsetAsync(deg, 0, (size_t)N * sizeof(int), stream);
  hipMemsetAsync(sums1, 0, 512 * sizeof(float), stream);

  int nb = (N + 255) / 256;

  k_wconv<<<(NDIM*NDIM + 255)/256, 256, 0, stream>>>(Wq, wtq, NDIM, NDIM);
  k_wconv<<<(NDIM*NDIM + 255)/256, 256, 0, stream>>>(Wk, wtk, NDIM, NDIM);
  k_wconv<<<(NDIM*NDIM + 255)/256, 256, 0, stream>>>(Wv, wtv, NDIM, NDIM);
  k_wconv<<<(NDIM*NDIM + 255)/256, 256, 0, stream>>>(Wo, wto, NDIM, NDIM);
  k_wconv<<<(NDIM*2*NDIM + 255)/256, 256, 0, stream>>>(W1, wt1, NDIM, 2*NDIM);
  k_wconv<<<(NDIM*2*NDIM + 255)/256, 256, 0, stream>>>(W2, wt2, 2*NDIM, NDIM);

  k_bn_stats<<<(N + 127)/128, 256, 0, stream>>>(h, sums1, N);
  k_bn_final<<<1, 128, 0, stream>>>(sums1, bn1g, bn1b, scsh1, N);
  k_qkv<<<(N + 63)/64, 256, 0, stream>>>(h, scsh1, wtq, wtk, wtv, Q, K, V, N);

  k_deg<<<(E + 255)/256, 256, 0, stream>>>(dst, deg, E);
  k_scan_part<<<nb, 256, 0, stream>>>(deg, bsum, N);
  k_scan_top<<<1, 256, 0, stream>>>(bsum, nb, rowptr, N, E);
  k_scan_down<<<nb, 256, 0, stream>>>(deg, bsum, rowptr, N);
  hipMemcpyAsync(cursor, rowptr, (size_t)N * sizeof(int), hipMemcpyDeviceToDevice, stream);
  k_scatter<<<(E + 255)/256, 256, 0, stream>>>(src, dst, cursor, csr_src, csr_eid, E);

  k_score<<<(E*NHEAD + 255)/256, 256, 0, stream>>>(src, dst, Q, K, score, E*NHEAD);
  k_agg<<<N, 64, 0, stream>>>(rowptr, csr_src, csr_eid, score, V, wV);

  k_h2<<<(N + 63)/64, 256, 0, stream>>>(wV, wto, bo, h, h2, sums2, N);
  k_bn_final<<<1, 128, 0, stream>>>(sums2, bn2g, bn2b, scsh2, N);
  k_ffn<<<(N + 63)/64, 256, 0, stream>>>(h2, scsh2, wt1, b1, wt2, b2, out, N);
}

// Round 3
// 329.795 us; speedup vs baseline: 2.0296x; 1.2613x over previous
//
#include <hip/hip_runtime.h>
#include <hip/hip_bf16.h>

#define NDIM 128
#define NHEAD 8
#define EPSV 1e-5f

typedef unsigned short u16;
using bf16x8 = __attribute__((ext_vector_type(8))) short;
using f32x4  = __attribute__((ext_vector_type(4))) float;
using us8    = __attribute__((ext_vector_type(8))) unsigned short;
using us4    = __attribute__((ext_vector_type(4))) unsigned short;

__device__ __forceinline__ u16 f2b(float x){
  union { float f; unsigned u; } v; v.f = x;
  unsigned r = v.u + 0x7FFFu + ((v.u >> 16) & 1u);
  return (u16)(r >> 16);
}
__device__ __forceinline__ float b2f(u16 u){
  union { unsigned u; float f; } v; v.u = ((unsigned)u) << 16; return v.f;
}
__device__ __forceinline__ float blo(unsigned u){
  union { unsigned u; float f; } v; v.u = u << 16; return v.f;
}
__device__ __forceinline__ float bhi(unsigned u){
  union { unsigned u; float f; } v; v.u = u & 0xFFFF0000u; return v.f;
}

// A-frag: lane provides A[lane%16][(lane/16)*8 + j]; B-frag: B[(lane/16)*8+j][lane%16]
// C/D: col = lane&15, row = (lane>>4)*4 + reg   (measured m89)
template<int NT, int KS, int WTLD, int XSTR>
__device__ __forceinline__ void gemm_tiles(const u16* X, const u16* __restrict__ WT,
                                           int lr, int kg, int colbase, f32x4 (&acc)[NT][4]){
  #pragma unroll
  for (int ks = 0; ks < KS; ks++){
    bf16x8 a[4];
    #pragma unroll
    for (int m = 0; m < 4; m++)
      a[m] = *(const bf16x8*)(X + (size_t)(m*16 + lr)*XSTR + ks*32 + kg*8);
    #pragma unroll
    for (int n = 0; n < NT; n++){
      int col = colbase + n*16 + lr;
      bf16x8 b = *(const bf16x8*)(WT + (size_t)col*WTLD + ks*32 + kg*8);
      #pragma unroll
      for (int m = 0; m < 4; m++)
        acc[n][m] = __builtin_amdgcn_mfma_f32_16x16x32_bf16(a[m], b, acc[n][m], 0, 0, 0);
    }
  }
}

__device__ __forceinline__ void wconv_one(const float* __restrict__ W, u16* __restrict__ WT,
                                          int li, int rows, int cols){
  int r = li / cols, c = li % cols;
  WT[(size_t)c*rows + r] = f2b(W[li]);
}

// ============ prologue: weight convert (512 blocks) + BN1 stats (nBn) + deg count (nDeg) ============
__global__ __launch_bounds__(256) void k_prologue(
    const float* __restrict__ Wq, const float* __restrict__ Wk, const float* __restrict__ Wv,
    const float* __restrict__ Wo, const float* __restrict__ W1, const float* __restrict__ W2,
    u16* __restrict__ wtq, u16* __restrict__ wtk, u16* __restrict__ wtv,
    u16* __restrict__ wto, u16* __restrict__ wt1, u16* __restrict__ wt2,
    const float* __restrict__ h, float* __restrict__ sums,
    const int* __restrict__ dst, int* __restrict__ deg,
    int nBn, int nDeg, int N, int E){
  __shared__ float ls[256], ls2[256];
  int b = blockIdx.x, t = threadIdx.x;
  if (b < 512){
    int i = b*256 + t;
    if      (i <  16384) wconv_one(Wq, wtq, i,          128, 128);
    else if (i <  32768) wconv_one(Wk, wtk, i - 16384,  128, 128);
    else if (i <  49152) wconv_one(Wv, wtv, i - 32768,  128, 128);
    else if (i <  65536) wconv_one(Wo, wto, i - 49152,  128, 128);
    else if (i <  98304) wconv_one(W1, wt1, i - 65536,  128, 256);
    else                 wconv_one(W2, wt2, i - 98304,  256, 128);
    return;
  }
  b -= 512;
  if (b < nBn){
    int col = t & 127, half = t >> 7;
    int r0 = b * 128; int r1 = r0 + 128; if (r1 > N) r1 = N;
    float s = 0.f, s2 = 0.f;
    for (int r = r0 + half; r < r1; r += 2){ float v = h[(size_t)r*NDIM + col]; s += v; s2 += v*v; }
    ls[t] = s; ls2[t] = s2; __syncthreads();
    if (t < 128){ atomicAdd(&sums[col], ls[t] + ls[t+128]); atomicAdd(&sums[128+col], ls2[t] + ls2[t+128]); }
    return;
  }
  b -= nBn;
  int e = b*256 + t;
  if (e < E) atomicAdd(&deg[dst[e]], 1);
}

__global__ __launch_bounds__(128) void k_bn_final(const float* __restrict__ sums, const float* __restrict__ g,
                                                  const float* __restrict__ b, float* __restrict__ scsh, int N){
  int c = threadIdx.x;
  float mean = sums[c] / (float)N;
  float var  = sums[128+c] / (float)N - mean*mean;
  float rstd = rsqrtf(var + EPSV);
  float sc = g[c] * rstd;
  scsh[c] = sc; scsh[128+c] = b[c] - mean*sc;
}

// ============ BN1-apply + QKV projection (MFMA) ============
__global__ __launch_bounds__(256) void k_qkv(const float* __restrict__ h, const float* __restrict__ scsh,
                                             const u16* __restrict__ WTq, const u16* __restrict__ WTk, const u16* __restrict__ WTv,
                                             u16* __restrict__ Q, u16* __restrict__ K, u16* __restrict__ V, int N){
  __shared__ u16 hn[64][136];
  int t = threadIdx.x; int r0 = blockIdx.x * 64;
  {
    int row = t >> 2, c0 = (t & 3) * 32; int rr = r0 + row;
    #pragma unroll
    for (int j = 0; j < 8; j++){
      int c = c0 + 4*j;
      float4 v = make_float4(0.f,0.f,0.f,0.f);
      if (rr < N) v = *(const float4*)(h + (size_t)rr*NDIM + c);
      us4 o;
      o.x = f2b(v.x * scsh[c]   + scsh[128+c]);
      o.y = f2b(v.y * scsh[c+1] + scsh[129+c]);
      o.z = f2b(v.z * scsh[c+2] + scsh[130+c]);
      o.w = f2b(v.w * scsh[c+3] + scsh[131+c]);
      *(us4*)&hn[row][c] = o;
    }
  }
  __syncthreads();
  int lane = t & 63, w = t >> 6;
  int lr = lane & 15, kg = lane >> 4;
  f32x4 zero = {0.f,0.f,0.f,0.f};

  #define DO_PASS(WT, OUT) { \
    f32x4 acc[2][4]; \
    _Pragma("unroll") for (int n = 0; n < 2; n++) _Pragma("unroll") for (int m = 0; m < 4; m++) acc[n][m] = zero; \
    gemm_tiles<2,4,128,136>(&hn[0][0], WT, lr, kg, w*32, acc); \
    _Pragma("unroll") for (int n = 0; n < 2; n++){ \
      int col = w*32 + n*16 + lr; \
      _Pragma("unroll") for (int m = 0; m < 4; m++) \
        _Pragma("unroll") for (int r = 0; r < 4; r++){ \
          int rr = r0 + m*16 + kg*4 + r; \
          if (rr < N) OUT[(size_t)rr*NDIM + col] = f2b(acc[n][m][r]); \
        } \
    } }
  DO_PASS(WTq, Q)
  DO_PASS(WTk, K)
  DO_PASS(WTv, V)
  #undef DO_PASS
}

// ============ CSR build (scan) ============
__global__ __launch_bounds__(256) void k_scan_part(const int* __restrict__ deg, int* __restrict__ bsum, int N){
  __shared__ int ls[256];
  int t = threadIdx.x; int i = blockIdx.x*256 + t;
  ls[t] = (i < N) ? deg[i] : 0; __syncthreads();
  for (int off = 128; off > 0; off >>= 1){
    if (t < off) ls[t] += ls[t + off];
    __syncthreads();
  }
  if (t == 0) bsum[blockIdx.x] = ls[0];
}

__global__ __launch_bounds__(256) void k_scan_top(int* __restrict__ bsum, int nb, int* __restrict__ rowptr, int N, int E){
  __shared__ int ls[256];
  int t = threadIdx.x;
  int v = (t < nb) ? bsum[t] : 0; ls[t] = v; __syncthreads();
  for (int off = 1; off < 256; off <<= 1){
    int add = (t >= off) ? ls[t - off] : 0;
    __syncthreads();
    ls[t] += add;
    __syncthreads();
  }
  if (t < nb) bsum[t] = ls[t] - v;
  if (t == 0) rowptr[N] = E;
}

__global__ __launch_bounds__(256) void k_scan_down(const int* __restrict__ deg, const int* __restrict__ bsum,
                                                   int* __restrict__ rowptr, int* __restrict__ cursor, int N){
  __shared__ int ls[256];
  int t = threadIdx.x; int i = blockIdx.x*256 + t;
  int v = (i < N) ? deg[i] : 0; ls[t] = v; __syncthreads();
  for (int off = 1; off < 256; off <<= 1){
    int add = (t >= off) ? ls[t - off] : 0;
    __syncthreads();
    ls[t] += add;
    __syncthreads();
  }
  if (i < N){ int rp = ls[t] - v + bsum[blockIdx.x]; rowptr[i] = rp; cursor[i] = rp; }
}

__global__ __launch_bounds__(256) void k_scatter(const int* __restrict__ src, const int* __restrict__ dst,
                                                 int* __restrict__ cursor, int* __restrict__ csr_src, int E){
  int e = blockIdx.x*256 + threadIdx.x;
  if (e < E){
    int d = dst[e];
    int slot = atomicAdd(&cursor[d], 1);
    csr_src[slot] = src[e];
  }
}

// ============ fused edge phase: score + softmax + weighted V aggregation ============
// One wave per node. Scores clamped to [-5,5] -> exp(score) directly (no max pass).
__global__ __launch_bounds__(256) void k_sagg(const int* __restrict__ rowptr, const int* __restrict__ csr_src,
                                              const u16* __restrict__ Q, const u16* __restrict__ K,
                                              const u16* __restrict__ V, u16* __restrict__ wV, int N){
  int w = threadIdx.x >> 6, l = threadIdx.x & 63;
  int n = blockIdx.x*4 + w;
  if (n >= N) return;
  int d0 = l * 2;
  unsigned qq = *(const unsigned*)(Q + (size_t)n*NDIM + d0);
  float q0 = blo(qq) * 0.25f, q1 = bhi(qq) * 0.25f;   // fold 1/sqrt(16)
  int e0 = rowptr[n], e1 = rowptr[n+1];
  float ssum = 0.f, a0 = 0.f, a1 = 0.f;
  int i = e0;
  for (; i + 2 <= e1; i += 2){
    int s0 = csr_src[i], s1 = csr_src[i+1];
    unsigned kk0 = *(const unsigned*)(K + (size_t)s0*NDIM + d0);
    unsigned kk1 = *(const unsigned*)(K + (size_t)s1*NDIM + d0);
    unsigned vv0 = *(const unsigned*)(V + (size_t)s0*NDIM + d0);
    unsigned vv1 = *(const unsigned*)(V + (size_t)s1*NDIM + d0);
    float p0 = blo(kk0)*q0 + bhi(kk0)*q1;
    float p1 = blo(kk1)*q0 + bhi(kk1)*q1;
    p0 += __shfl_xor(p0, 1); p0 += __shfl_xor(p0, 2); p0 += __shfl_xor(p0, 4);
    p1 += __shfl_xor(p1, 1); p1 += __shfl_xor(p1, 2); p1 += __shfl_xor(p1, 4);
    float w0 = __expf(fminf(5.f, fmaxf(-5.f, p0)));
    float w1 = __expf(fminf(5.f, fmaxf(-5.f, p1)));
    ssum += w0 + w1;
    a0 += w0*blo(vv0) + w1*blo(vv1);
    a1 += w0*bhi(vv0) + w1*bhi(vv1);
  }
  if (i < e1){
    int s0 = csr_src[i];
    unsigned kk0 = *(const unsigned*)(K + (size_t)s0*NDIM + d0);
    unsigned vv0 = *(const unsigned*)(V + (size_t)s0*NDIM + d0);
    float p0 = blo(kk0)*q0 + bhi(kk0)*q1;
    p0 += __shfl_xor(p0, 1); p0 += __shfl_xor(p0, 2); p0 += __shfl_xor(p0, 4);
    float w0 = __expf(fminf(5.f, fmaxf(-5.f, p0)));
    ssum += w0;
    a0 += w0*blo(vv0);
    a1 += w0*bhi(vv0);
  }
  float inv = (e1 > e0) ? 1.f/ssum : 0.f;
  unsigned pk = (unsigned)f2b(a0*inv) | (((unsigned)f2b(a1*inv)) << 16);
  *(unsigned*)(wV + (size_t)n*NDIM + d0) = pk;
}

// ============ O-projection + residual + BN2 stats (MFMA) ============
__global__ __launch_bounds__(256) void k_h2(const u16* __restrict__ wV, const u16* __restrict__ WTo,
                                            const float* __restrict__ bo, const float* __restrict__ h,
                                            float* __restrict__ h2, float* __restrict__ sums2, int N){
  __shared__ u16 tw[64][136];
  int t = threadIdx.x; int r0 = blockIdx.x * 64;
  {
    int row = t >> 2, c0 = (t & 3) * 32; int rr = r0 + row;
    #pragma unroll
    for (int j = 0; j < 4; j++){
      int c = c0 + 8*j;
      us8 v = {0,0,0,0,0,0,0,0};
      if (rr < N) v = *(const us8*)(wV + (size_t)rr*NDIM + c);
      *(us8*)&tw[row][c] = v;
    }
  }
  __syncthreads();
  int lane = t & 63, w = t >> 6;
  int lr = lane & 15, kg = lane >> 4;
  f32x4 zero = {0.f,0.f,0.f,0.f};
  f32x4 acc[2][4];
  #pragma unroll
  for (int n = 0; n < 2; n++)
    #pragma unroll
    for (int m = 0; m < 4; m++) acc[n][m] = zero;
  gemm_tiles<2,4,128,136>(&tw[0][0], WTo, lr, kg, w*32, acc);

  float sv[2] = {0.f, 0.f}, qv[2] = {0.f, 0.f};
  #pragma unroll
  for (int n = 0; n < 2; n++){
    int col = w*32 + n*16 + lr;
    float bb = bo[col];
    #pragma unroll
    for (int m = 0; m < 4; m++)
      #pragma unroll
      for (int r = 0; r < 4; r++){
        int rr = r0 + m*16 + kg*4 + r;
        if (rr < N){
          size_t o = (size_t)rr*NDIM + col;
          float v = acc[n][m][r] + bb + h[o];
          h2[o] = v;
          sv[n] += v; qv[n] += v*v;
        }
      }
  }
  #pragma unroll
  for (int n = 0; n < 2; n++){
    float s = sv[n], q = qv[n];
    s += __shfl_xor(s, 16); s += __shfl_xor(s, 32);
    q += __shfl_xor(q, 16); q += __shfl_xor(q, 32);
    if (kg == 0){
      int col = w*32 + n*16 + lr;
      atomicAdd(&sums2[col], s);
      atomicAdd(&sums2[128+col], q);
    }
  }
}

// ============ BN2-apply + FFN + residual (MFMA) ============
__global__ __launch_bounds__(256) void k_ffn(const float* __restrict__ h2, const float* __restrict__ scsh,
                                             const u16* __restrict__ WT1, const float* __restrict__ b1,
                                             const u16* __restrict__ WT2, const float* __restrict__ b2,
                                             float* __restrict__ out, int N){
  __shared__ u16 x[64][136];
  __shared__ u16 tt[64][264];
  int t = threadIdx.x; int r0 = blockIdx.x * 64;
  {
    int row = t >> 2, c0 = (t & 3) * 32; int rr = r0 + row;
    #pragma unroll
    for (int j = 0; j < 8; j++){
      int c = c0 + 4*j;
      float4 v = make_float4(0.f,0.f,0.f,0.f);
      if (rr < N) v = *(const float4*)(h2 + (size_t)rr*NDIM + c);
      us4 o;
      o.x = f2b(v.x * scsh[c]   + scsh[128+c]);
      o.y = f2b(v.y * scsh[c+1] + scsh[129+c]);
      o.z = f2b(v.z * scsh[c+2] + scsh[130+c]);
      o.w = f2b(v.w * scsh[c+3] + scsh[131+c]);
      *(us4*)&x[row][c] = o;
    }
  }
  __syncthreads();
  int lane = t & 63, w = t >> 6;
  int lr = lane & 15, kg = lane >> 4;
  f32x4 zero = {0.f,0.f,0.f,0.f};
  {
    f32x4 a1[4][4];
    #pragma unroll
    for (int n = 0; n < 4; n++)
      #pragma unroll
      for (int m = 0; m < 4; m++) a1[n][m] = zero;
    gemm_tiles<4,4,128,136>(&x[0][0], WT1, lr, kg, w*64, a1);
    #pragma unroll
    for (int n = 0; n < 4; n++){
      int col = w*64 + n*16 + lr;
      float bb = b1[col];
      #pragma unroll
      for (int m = 0; m < 4; m++)
        #pragma unroll
        for (int r = 0; r < 4; r++)
          tt[m*16 + kg*4 + r][col] = f2b(fmaxf(a1[n][m][r] + bb, 0.f));
    }
  }
  __syncthreads();
  {
    f32x4 a2[2][4];
    #pragma unroll
    for (int n = 0; n < 2; n++)
      #pragma unroll
      for (int m = 0; m < 4; m++) a2[n][m] = zero;
    gemm_tiles<2,8,256,264>(&tt[0][0], WT2, lr, kg, w*32, a2);
    #pragma unroll
    for (int n = 0; n < 2; n++){
      int col = w*32 + n*16 + lr;
      float bb = b2[col];
      #pragma unroll
      for (int m = 0; m < 4; m++)
        #pragma unroll
        for (int r = 0; r < 4; r++){
          int rr = r0 + m*16 + kg*4 + r;
          if (rr < N){
            size_t o = (size_t)rr*NDIM + col;
            out[o] = h2[o] + a2[n][m][r] + bb;
          }
        }
    }
  }
}

extern "C" void kernel_launch(void* const* d_in, const int* in_sizes, int n_in,
                              void* d_out, int out_size, void* d_ws, size_t ws_size,
                              hipStream_t stream) {
  const float* h    = (const float*)d_in[0];
  const int*   src  = (const int*)d_in[1];
  const int*   dst  = (const int*)d_in[2];
  const float* Wq   = (const float*)d_in[3];
  const float* Wk   = (const float*)d_in[4];
  const float* Wv   = (const float*)d_in[5];
  const float* Wo   = (const float*)d_in[6];
  const float* bo   = (const float*)d_in[7];
  const float* bn1g = (const float*)d_in[8];
  const float* bn1b = (const float*)d_in[9];
  const float* bn2g = (const float*)d_in[10];
  const float* bn2b = (const float*)d_in[11];
  const float* W1   = (const float*)d_in[12];
  const float* b1   = (const float*)d_in[13];
  const float* W2   = (const float*)d_in[14];
  const float* b2   = (const float*)d_in[15];
  float* out = (float*)d_out;

  int N = in_sizes[0] / NDIM;
  int E = in_sizes[1];
  size_t fN = (size_t)N * NDIM;

  u16* Q  = (u16*)d_ws;
  u16* K  = Q + fN;
  u16* V  = K + fN;
  u16* wV = Q;                                  // reuse: each wave reads Q[n] before writing wV[n]
  float* h2    = (float*)(V + fN);              // fN floats
  int* deg     = (int*)(h2 + fN);
  int* rowptr  = deg + N;
  int* cursor  = rowptr + (N + 1);
  int* bsum    = cursor + N;
  int* csr_src = bsum + 256;
  float* sums1 = (float*)(csr_src + E);
  float* sums2 = sums1 + 256;
  float* scsh1 = sums2 + 256;
  float* scsh2 = scsh1 + 256;
  u16* wtq = (u16*)(scsh2 + 256);
  u16* wtk = wtq + NDIM*NDIM;
  u16* wtv = wtk + NDIM*NDIM;
  u16* wto = wtv + NDIM*NDIM;
  u16* wt1 = wto + NDIM*NDIM;
  u16* wt2 = wt1 + NDIM*2*NDIM;

  hipMemsetAsync(deg, 0, (size_t)N * sizeof(int), stream);
  hipMemsetAsync(sums1, 0, 512 * sizeof(float), stream);

  int nb  = (N + 255) / 256;
  int nBn  = (N + 127) / 128;
  int nDeg = (E + 255) / 256;

  k_prologue<<<512 + nBn + nDeg, 256, 0, stream>>>(Wq, Wk, Wv, Wo, W1, W2,
                                                   wtq, wtk, wtv, wto, wt1, wt2,
                                                   h, sums1, dst, deg, nBn, nDeg, N, E);
  k_bn_final<<<1, 128, 0, stream>>>(sums1, bn1g, bn1b, scsh1, N);
  k_qkv<<<(N + 63)/64, 256, 0, stream>>>(h, scsh1, wtq, wtk, wtv, Q, K, V, N);

  k_scan_part<<<nb, 256, 0, stream>>>(deg, bsum, N);
  k_scan_top<<<1, 256, 0, stream>>>(bsum, nb, rowptr, N, E);
  k_scan_down<<<nb, 256, 0, stream>>>(deg, bsum, rowptr, cursor, N);
  k_scatter<<<(E + 255)/256, 256, 0, stream>>>(src, dst, cursor, csr_src, E);

  k_sagg<<<(N + 3)/4, 256, 0, stream>>>(rowptr, csr_src, Q, K, V, wV, N);

  k_h2<<<(N + 63)/64, 256, 0, stream>>>(wV, wto, bo, h, h2, sums2, N);
  k_bn_final<<<1, 128, 0, stream>>>(sums2, bn2g, bn2b, scsh2, N);
  k_ffn<<<(N + 63)/64, 256, 0, stream>>>(h2, scsh2, wt1, b1, wt2, b2, out, N);
}

// Round 4
// 320.171 us; speedup vs baseline: 2.0906x; 1.0301x over previous
//
#include <hip/hip_runtime.h>
#include <hip/hip_bf16.h>

#define NDIM 128
#define NHEAD 8
#define EPSV 1e-5f

typedef unsigned short u16;
using bf16x8 = __attribute__((ext_vector_type(8))) short;
using f32x4  = __attribute__((ext_vector_type(4))) float;
using us8    = __attribute__((ext_vector_type(8))) unsigned short;
using us4    = __attribute__((ext_vector_type(4))) unsigned short;

__device__ __forceinline__ u16 f2b(float x){
  union { float f; unsigned u; } v; v.f = x;
  unsigned r = v.u + 0x7FFFu + ((v.u >> 16) & 1u);
  return (u16)(r >> 16);
}
__device__ __forceinline__ float b2f(u16 u){
  union { unsigned u; float f; } v; v.u = ((unsigned)u) << 16; return v.f;
}
__device__ __forceinline__ float blo(unsigned u){
  union { unsigned u; float f; } v; v.u = u << 16; return v.f;
}
__device__ __forceinline__ float bhi(unsigned u){
  union { unsigned u; float f; } v; v.u = u & 0xFFFF0000u; return v.f;
}

// A-frag: lane provides A[lane%16][(lane/16)*8 + j]; B-frag: B[(lane/16)*8+j][lane%16]
// C/D: col = lane&15, row = (lane>>4)*4 + reg   (measured m89)
template<int NT, int KS, int WTLD, int XSTR>
__device__ __forceinline__ void gemm_tiles(const u16* X, const u16* __restrict__ WT,
                                           int lr, int kg, int colbase, f32x4 (&acc)[NT][4]){
  #pragma unroll
  for (int ks = 0; ks < KS; ks++){
    bf16x8 a[4];
    #pragma unroll
    for (int m = 0; m < 4; m++)
      a[m] = *(const bf16x8*)(X + (size_t)(m*16 + lr)*XSTR + ks*32 + kg*8);
    #pragma unroll
    for (int n = 0; n < NT; n++){
      int col = colbase + n*16 + lr;
      bf16x8 b = *(const bf16x8*)(WT + (size_t)col*WTLD + ks*32 + kg*8);
      #pragma unroll
      for (int m = 0; m < 4; m++)
        acc[n][m] = __builtin_amdgcn_mfma_f32_16x16x32_bf16(a[m], b, acc[n][m], 0, 0, 0);
    }
  }
}

__device__ __forceinline__ void wconv_one(const float* __restrict__ W, u16* __restrict__ WT,
                                          int li, int rows, int cols){
  int r = li / cols, c = li % cols;
  WT[(size_t)c*rows + r] = f2b(W[li]);
}

// ============ prologue: weight convert (512 blocks) + BN1 stats (nBn) + deg count (nDeg) ============
__global__ __launch_bounds__(256) void k_prologue(
    const float* __restrict__ Wq, const float* __restrict__ Wk, const float* __restrict__ Wv,
    const float* __restrict__ Wo, const float* __restrict__ W1, const float* __restrict__ W2,
    u16* __restrict__ wtq, u16* __restrict__ wtk, u16* __restrict__ wtv,
    u16* __restrict__ wto, u16* __restrict__ wt1, u16* __restrict__ wt2,
    const float* __restrict__ h, float* __restrict__ sums,
    const int* __restrict__ dst, int* __restrict__ deg,
    int nBn, int nDeg, int N, int E){
  __shared__ float ls[256], ls2[256];
  int b = blockIdx.x, t = threadIdx.x;
  if (b < 512){
    int i = b*256 + t;
    if      (i <  16384) wconv_one(Wq, wtq, i,          128, 128);
    else if (i <  32768) wconv_one(Wk, wtk, i - 16384,  128, 128);
    else if (i <  49152) wconv_one(Wv, wtv, i - 32768,  128, 128);
    else if (i <  65536) wconv_one(Wo, wto, i - 49152,  128, 128);
    else if (i <  98304) wconv_one(W1, wt1, i - 65536,  128, 256);
    else                 wconv_one(W2, wt2, i - 98304,  256, 128);
    return;
  }
  b -= 512;
  if (b < nBn){
    int col = t & 127, half = t >> 7;
    int r0 = b * 128; int r1 = r0 + 128; if (r1 > N) r1 = N;
    float s = 0.f, s2 = 0.f;
    for (int r = r0 + half; r < r1; r += 2){ float v = h[(size_t)r*NDIM + col]; s += v; s2 += v*v; }
    ls[t] = s; ls2[t] = s2; __syncthreads();
    if (t < 128){ atomicAdd(&sums[col], ls[t] + ls[t+128]); atomicAdd(&sums[128+col], ls2[t] + ls2[t+128]); }
    return;
  }
  b -= nBn;
  int e = b*256 + t;
  if (e < E) atomicAdd(&deg[dst[e]], 1);
}

__global__ __launch_bounds__(128) void k_bn_final(const float* __restrict__ sums, const float* __restrict__ g,
                                                  const float* __restrict__ b, float* __restrict__ scsh, int N){
  int c = threadIdx.x;
  float mean = sums[c] / (float)N;
  float var  = sums[128+c] / (float)N - mean*mean;
  float rstd = rsqrtf(var + EPSV);
  float sc = g[c] * rstd;
  scsh[c] = sc; scsh[128+c] = b[c] - mean*sc;
}

// ============ BN1-apply + QKV projection (MFMA) ============
__global__ __launch_bounds__(256) void k_qkv(const float* __restrict__ h, const float* __restrict__ scsh,
                                             const u16* __restrict__ WTq, const u16* __restrict__ WTk, const u16* __restrict__ WTv,
                                             u16* __restrict__ Q, u16* __restrict__ K, u16* __restrict__ V, int N){
  __shared__ u16 hn[64][136];
  int t = threadIdx.x; int r0 = blockIdx.x * 64;
  {
    int row = t >> 2, c0 = (t & 3) * 32; int rr = r0 + row;
    #pragma unroll
    for (int j = 0; j < 8; j++){
      int c = c0 + 4*j;
      float4 v = make_float4(0.f,0.f,0.f,0.f);
      if (rr < N) v = *(const float4*)(h + (size_t)rr*NDIM + c);
      us4 o;
      o.x = f2b(v.x * scsh[c]   + scsh[128+c]);
      o.y = f2b(v.y * scsh[c+1] + scsh[129+c]);
      o.z = f2b(v.z * scsh[c+2] + scsh[130+c]);
      o.w = f2b(v.w * scsh[c+3] + scsh[131+c]);
      *(us4*)&hn[row][c] = o;
    }
  }
  __syncthreads();
  int lane = t & 63, w = t >> 6;
  int lr = lane & 15, kg = lane >> 4;
  f32x4 zero = {0.f,0.f,0.f,0.f};

  #define DO_PASS(WT, OUT) { \
    f32x4 acc[2][4]; \
    _Pragma("unroll") for (int n = 0; n < 2; n++) _Pragma("unroll") for (int m = 0; m < 4; m++) acc[n][m] = zero; \
    gemm_tiles<2,4,128,136>(&hn[0][0], WT, lr, kg, w*32, acc); \
    _Pragma("unroll") for (int n = 0; n < 2; n++){ \
      int col = w*32 + n*16 + lr; \
      _Pragma("unroll") for (int m = 0; m < 4; m++) \
        _Pragma("unroll") for (int r = 0; r < 4; r++){ \
          int rr = r0 + m*16 + kg*4 + r; \
          if (rr < N) OUT[(size_t)rr*NDIM + col] = f2b(acc[n][m][r]); \
        } \
    } }
  DO_PASS(WTq, Q)
  DO_PASS(WTk, K)
  DO_PASS(WTv, V)
  #undef DO_PASS
}

// ============ CSR build (scan) ============
__global__ __launch_bounds__(256) void k_scan_part(const int* __restrict__ deg, int* __restrict__ bsum, int N){
  __shared__ int ls[256];
  int t = threadIdx.x; int i = blockIdx.x*256 + t;
  ls[t] = (i < N) ? deg[i] : 0; __syncthreads();
  for (int off = 128; off > 0; off >>= 1){
    if (t < off) ls[t] += ls[t + off];
    __syncthreads();
  }
  if (t == 0) bsum[blockIdx.x] = ls[0];
}

__global__ __launch_bounds__(256) void k_scan_top(int* __restrict__ bsum, int nb, int* __restrict__ rowptr, int N, int E){
  __shared__ int ls[256];
  int t = threadIdx.x;
  int v = (t < nb) ? bsum[t] : 0; ls[t] = v; __syncthreads();
  for (int off = 1; off < 256; off <<= 1){
    int add = (t >= off) ? ls[t - off] : 0;
    __syncthreads();
    ls[t] += add;
    __syncthreads();
  }
  if (t < nb) bsum[t] = ls[t] - v;
  if (t == 0) rowptr[N] = E;
}

__global__ __launch_bounds__(256) void k_scan_down(const int* __restrict__ deg, const int* __restrict__ bsum,
                                                   int* __restrict__ rowptr, int* __restrict__ cursor, int N){
  __shared__ int ls[256];
  int t = threadIdx.x; int i = blockIdx.x*256 + t;
  int v = (i < N) ? deg[i] : 0; ls[t] = v; __syncthreads();
  for (int off = 1; off < 256; off <<= 1){
    int add = (t >= off) ? ls[t - off] : 0;
    __syncthreads();
    ls[t] += add;
    __syncthreads();
  }
  if (i < N){ int rp = ls[t] - v + bsum[blockIdx.x]; rowptr[i] = rp; cursor[i] = rp; }
}

__global__ __launch_bounds__(256) void k_scatter(const int* __restrict__ src, const int* __restrict__ dst,
                                                 int* __restrict__ cursor, int* __restrict__ csr_src, int E){
  int e = blockIdx.x*256 + threadIdx.x;
  if (e < E){
    int d = dst[e];
    int slot = atomicAdd(&cursor[d], 1);
    csr_src[slot] = src[e];
  }
}

// ============ fused edge phase: score + softmax + weighted V aggregation ============
// One wave per node; 8 edge-slots in flight. Score phase: lane = j*8+h computes the
// FULL 16-dim dot for edge-slot j, head h (no shuffles, exp once per lane).
// Agg phase: lane l owns dims 2l,2l+1; weight fetched with one ds_bpermute per edge.
// Scores clamped to [-5,5] -> exp(score) directly (identical to max-subtracted softmax).
__global__ __launch_bounds__(256) void k_sagg(const int* __restrict__ rowptr, const int* __restrict__ csr_src,
                                              const u16* __restrict__ Q, const u16* __restrict__ K,
                                              const u16* __restrict__ V, u16* __restrict__ wV, int N){
  int w = threadIdx.x >> 6, l = threadIdx.x & 63;
  int n = blockIdx.x*4 + w;
  if (n >= N) return;
  int j8 = l >> 3;     // edge slot (score phase)
  int hh = l & 7;      // head (score phase)
  int d0 = l * 2;      // dims (agg phase)

  float qf[16];
  {
    us8 q0 = *(const us8*)(Q + (size_t)n*NDIM + hh*16);
    us8 q1 = *(const us8*)(Q + (size_t)n*NDIM + hh*16 + 8);
    #pragma unroll
    for (int t = 0; t < 8; t++){ qf[t] = b2f(q0[t]) * 0.25f; qf[8+t] = b2f(q1[t]) * 0.25f; }
  }

  int e0 = rowptr[n], e1 = rowptr[n+1];
  float ssum_l = 0.f, a0 = 0.f, a1 = 0.f;

  for (int i = e0; i < e1; i += 8){
    int nedge = e1 - i; if (nedge > 8) nedge = 8;
    int myE = i + j8;
    int sidx = csr_src[(myE < e1) ? myE : i];

    // broadcast slot indices, issue all V gathers up-front (overlaps K latency)
    unsigned vv[8];
    #pragma unroll
    for (int j = 0; j < 8; j++){
      if (j >= nedge) break;
      int sj = __shfl(sidx, j*8);            // fixed-lane broadcast -> SGPR base
      vv[j] = *(const unsigned*)(V + (size_t)sj*NDIM + d0);
    }

    // K gather + in-lane full-head dot
    us8 k0 = *(const us8*)(K + (size_t)sidx*NDIM + hh*16);
    us8 k1 = *(const us8*)(K + (size_t)sidx*NDIM + hh*16 + 8);
    float p = 0.f;
    #pragma unroll
    for (int t = 0; t < 8; t++) p += qf[t]*b2f(k0[t]) + qf[8+t]*b2f(k1[t]);
    p = fminf(5.f, fmaxf(-5.f, p));
    float wgt = (myE < e1) ? __expf(p) : 0.f;
    ssum_l += wgt;

    // accumulate: weight for (edge j, head l>>3) lives in lane j*8 + (l>>3)
    #pragma unroll
    for (int j = 0; j < 8; j++){
      if (j >= nedge) break;
      float wj = __shfl(wgt, j*8 + j8);
      a0 += wj * blo(vv[j]);
      a1 += wj * bhi(vv[j]);
    }
  }

  // softmax denominator: sum over edge-slot bits (3,4,5), then route head sum to agg lane
  ssum_l += __shfl_xor(ssum_l, 8);
  ssum_l += __shfl_xor(ssum_l, 16);
  ssum_l += __shfl_xor(ssum_l, 32);
  float ssum = __shfl(ssum_l, j8);   // lane with (lane&7) == l>>3
  float inv = (e1 > e0) ? 1.f/ssum : 0.f;
  unsigned pk = (unsigned)f2b(a0*inv) | (((unsigned)f2b(a1*inv)) << 16);
  *(unsigned*)(wV + (size_t)n*NDIM + d0) = pk;
}

// ============ O-projection + residual + BN2 stats (MFMA) ============
__global__ __launch_bounds__(256) void k_h2(const u16* __restrict__ wV, const u16* __restrict__ WTo,
                                            const float* __restrict__ bo, const float* __restrict__ h,
                                            float* __restrict__ h2, float* __restrict__ sums2, int N){
  __shared__ u16 tw[64][136];
  int t = threadIdx.x; int r0 = blockIdx.x * 64;
  {
    int row = t >> 2, c0 = (t & 3) * 32; int rr = r0 + row;
    #pragma unroll
    for (int j = 0; j < 4; j++){
      int c = c0 + 8*j;
      us8 v = {0,0,0,0,0,0,0,0};
      if (rr < N) v = *(const us8*)(wV + (size_t)rr*NDIM + c);
      *(us8*)&tw[row][c] = v;
    }
  }
  __syncthreads();
  int lane = t & 63, w = t >> 6;
  int lr = lane & 15, kg = lane >> 4;
  f32x4 zero = {0.f,0.f,0.f,0.f};
  f32x4 acc[2][4];
  #pragma unroll
  for (int n = 0; n < 2; n++)
    #pragma unroll
    for (int m = 0; m < 4; m++) acc[n][m] = zero;
  gemm_tiles<2,4,128,136>(&tw[0][0], WTo, lr, kg, w*32, acc);

  float sv[2] = {0.f, 0.f}, qv[2] = {0.f, 0.f};
  #pragma unroll
  for (int n = 0; n < 2; n++){
    int col = w*32 + n*16 + lr;
    float bb = bo[col];
    #pragma unroll
    for (int m = 0; m < 4; m++)
      #pragma unroll
      for (int r = 0; r < 4; r++){
        int rr = r0 + m*16 + kg*4 + r;
        if (rr < N){
          size_t o = (size_t)rr*NDIM + col;
          float v = acc[n][m][r] + bb + h[o];
          h2[o] = v;
          sv[n] += v; qv[n] += v*v;
        }
      }
  }
  #pragma unroll
  for (int n = 0; n < 2; n++){
    float s = sv[n], q = qv[n];
    s += __shfl_xor(s, 16); s += __shfl_xor(s, 32);
    q += __shfl_xor(q, 16); q += __shfl_xor(q, 32);
    if (kg == 0){
      int col = w*32 + n*16 + lr;
      atomicAdd(&sums2[col], s);
      atomicAdd(&sums2[128+col], q);
    }
  }
}

// ============ BN2-apply + FFN + residual (MFMA) ============
__global__ __launch_bounds__(256) void k_ffn(const float* __restrict__ h2, const float* __restrict__ scsh,
                                             const u16* __restrict__ WT1, const float* __restrict__ b1,
                                             const u16* __restrict__ WT2, const float* __restrict__ b2,
                                             float* __restrict__ out, int N){
  __shared__ u16 x[64][136];
  __shared__ u16 tt[64][264];
  int t = threadIdx.x; int r0 = blockIdx.x * 64;
  {
    int row = t >> 2, c0 = (t & 3) * 32; int rr = r0 + row;
    #pragma unroll
    for (int j = 0; j < 8; j++){
      int c = c0 + 4*j;
      float4 v = make_float4(0.f,0.f,0.f,0.f);
      if (rr < N) v = *(const float4*)(h2 + (size_t)rr*NDIM + c);
      us4 o;
      o.x = f2b(v.x * scsh[c]   + scsh[128+c]);
      o.y = f2b(v.y * scsh[c+1] + scsh[129+c]);
      o.z = f2b(v.z * scsh[c+2] + scsh[130+c]);
      o.w = f2b(v.w * scsh[c+3] + scsh[131+c]);
      *(us4*)&x[row][c] = o;
    }
  }
  __syncthreads();
  int lane = t & 63, w = t >> 6;
  int lr = lane & 15, kg = lane >> 4;
  f32x4 zero = {0.f,0.f,0.f,0.f};
  {
    f32x4 a1[4][4];
    #pragma unroll
    for (int n = 0; n < 4; n++)
      #pragma unroll
      for (int m = 0; m < 4; m++) a1[n][m] = zero;
    gemm_tiles<4,4,128,136>(&x[0][0], WT1, lr, kg, w*64, a1);
    #pragma unroll
    for (int n = 0; n < 4; n++){
      int col = w*64 + n*16 + lr;
      float bb = b1[col];
      #pragma unroll
      for (int m = 0; m < 4; m++)
        #pragma unroll
        for (int r = 0; r < 4; r++)
          tt[m*16 + kg*4 + r][col] = f2b(fmaxf(a1[n][m][r] + bb, 0.f));
    }
  }
  __syncthreads();
  {
    f32x4 a2[2][4];
    #pragma unroll
    for (int n = 0; n < 2; n++)
      #pragma unroll
      for (int m = 0; m < 4; m++) a2[n][m] = zero;
    gemm_tiles<2,8,256,264>(&tt[0][0], WT2, lr, kg, w*32, a2);
    #pragma unroll
    for (int n = 0; n < 2; n++){
      int col = w*32 + n*16 + lr;
      float bb = b2[col];
      #pragma unroll
      for (int m = 0; m < 4; m++)
        #pragma unroll
        for (int r = 0; r < 4; r++){
          int rr = r0 + m*16 + kg*4 + r;
          if (rr < N){
            size_t o = (size_t)rr*NDIM + col;
            out[o] = h2[o] + a2[n][m][r] + bb;
          }
        }
    }
  }
}

extern "C" void kernel_launch(void* const* d_in, const int* in_sizes, int n_in,
                              void* d_out, int out_size, void* d_ws, size_t ws_size,
                              hipStream_t stream) {
  const float* h    = (const float*)d_in[0];
  const int*   src  = (const int*)d_in[1];
  const int*   dst  = (const int*)d_in[2];
  const float* Wq   = (const float*)d_in[3];
  const float* Wk   = (const float*)d_in[4];
  const float* Wv   = (const float*)d_in[5];
  const float* Wo   = (const float*)d_in[6];
  const float* bo   = (const float*)d_in[7];
  const float* bn1g = (const float*)d_in[8];
  const float* bn1b = (const float*)d_in[9];
  const float* bn2g = (const float*)d_in[10];
  const float* bn2b = (const float*)d_in[11];
  const float* W1   = (const float*)d_in[12];
  const float* b1   = (const float*)d_in[13];
  const float* W2   = (const float*)d_in[14];
  const float* b2   = (const float*)d_in[15];
  float* out = (float*)d_out;

  int N = in_sizes[0] / NDIM;
  int E = in_sizes[1];
  size_t fN = (size_t)N * NDIM;

  u16* Q  = (u16*)d_ws;
  u16* K  = Q + fN;
  u16* V  = K + fN;
  u16* wV = Q;                                  // reuse: each wave reads Q[n] before writing wV[n]
  float* h2    = (float*)(V + fN);              // fN floats
  int* deg     = (int*)(h2 + fN);
  int* rowptr  = deg + N;
  int* cursor  = rowptr + (N + 1);
  int* bsum    = cursor + N;
  int* csr_src = bsum + 256;
  float* sums1 = (float*)(csr_src + E);
  float* sums2 = sums1 + 256;
  float* scsh1 = sums2 + 256;
  float* scsh2 = scsh1 + 256;
  u16* wtq = (u16*)(scsh2 + 256);
  u16* wtk = wtq + NDIM*NDIM;
  u16* wtv = wtk + NDIM*NDIM;
  u16* wto = wtv + NDIM*NDIM;
  u16* wt1 = wto + NDIM*NDIM;
  u16* wt2 = wt1 + NDIM*2*NDIM;

  hipMemsetAsync(deg, 0, (size_t)N * sizeof(int), stream);
  hipMemsetAsync(sums1, 0, 512 * sizeof(float), stream);

  int nb  = (N + 255) / 256;
  int nBn  = (N + 127) / 128;
  int nDeg = (E + 255) / 256;

  k_prologue<<<512 + nBn + nDeg, 256, 0, stream>>>(Wq, Wk, Wv, Wo, W1, W2,
                                                   wtq, wtk, wtv, wto, wt1, wt2,
                                                   h, sums1, dst, deg, nBn, nDeg, N, E);
  k_bn_final<<<1, 128, 0, stream>>>(sums1, bn1g, bn1b, scsh1, N);
  k_qkv<<<(N + 63)/64, 256, 0, stream>>>(h, scsh1, wtq, wtk, wtv, Q, K, V, N);

  k_scan_part<<<nb, 256, 0, stream>>>(deg, bsum, N);
  k_scan_top<<<1, 256, 0, stream>>>(bsum, nb, rowptr, N, E);
  k_scan_down<<<nb, 256, 0, stream>>>(deg, bsum, rowptr, cursor, N);
  k_scatter<<<(E + 255)/256, 256, 0, stream>>>(src, dst, cursor, csr_src, E);

  k_sagg<<<(N + 3)/4, 256, 0, stream>>>(rowptr, csr_src, Q, K, V, wV, N);

  k_h2<<<(N + 63)/64, 256, 0, stream>>>(wV, wto, bo, h, h2, sums2, N);
  k_bn_final<<<1, 128, 0, stream>>>(sums2, bn2g, bn2b, scsh2, N);
  k_ffn<<<(N + 63)/64, 256, 0, stream>>>(h2, scsh2, wt1, b1, wt2, b2, out, N);
}

// Round 5
// 318.791 us; speedup vs baseline: 2.0996x; 1.0043x over previous
//
#include <hip/hip_runtime.h>
#include <hip/hip_bf16.h>

#define NDIM 128
#define NHEAD 8
#define EPSV 1e-5f

typedef unsigned short u16;
using bf16x8 = __attribute__((ext_vector_type(8))) short;
using f32x4  = __attribute__((ext_vector_type(4))) float;
using us8    = __attribute__((ext_vector_type(8))) unsigned short;
using us4    = __attribute__((ext_vector_type(4))) unsigned short;

__device__ __forceinline__ u16 f2b(float x){
  union { float f; unsigned u; } v; v.f = x;
  unsigned r = v.u + 0x7FFFu + ((v.u >> 16) & 1u);
  return (u16)(r >> 16);
}
__device__ __forceinline__ float b2f(u16 u){
  union { unsigned u; float f; } v; v.u = ((unsigned)u) << 16; return v.f;
}
__device__ __forceinline__ float blo(unsigned u){
  union { unsigned u; float f; } v; v.u = u << 16; return v.f;
}
__device__ __forceinline__ float bhi(unsigned u){
  union { unsigned u; float f; } v; v.u = u & 0xFFFF0000u; return v.f;
}

// A-frag: lane provides A[lane%16][(lane/16)*8 + j]; B-frag: B[(lane/16)*8+j][lane%16]
// C/D: col = lane&15, row = (lane>>4)*4 + reg   (measured m89)
template<int NT, int KS, int WTLD, int XSTR>
__device__ __forceinline__ void gemm_tiles(const u16* X, const u16* __restrict__ WT,
                                           int lr, int kg, int colbase, f32x4 (&acc)[NT][4]){
  #pragma unroll
  for (int ks = 0; ks < KS; ks++){
    bf16x8 a[4];
    #pragma unroll
    for (int m = 0; m < 4; m++)
      a[m] = *(const bf16x8*)(X + (size_t)(m*16 + lr)*XSTR + ks*32 + kg*8);
    #pragma unroll
    for (int n = 0; n < NT; n++){
      int col = colbase + n*16 + lr;
      bf16x8 b = *(const bf16x8*)(WT + (size_t)col*WTLD + ks*32 + kg*8);
      #pragma unroll
      for (int m = 0; m < 4; m++)
        acc[n][m] = __builtin_amdgcn_mfma_f32_16x16x32_bf16(a[m], b, acc[n][m], 0, 0, 0);
    }
  }
}

// transpose one 64x64 tile of W (rows x cols, f32) into WT (cols x rows, bf16), coalesced both ways
__device__ __forceinline__ void wconv_tile(const float* __restrict__ W, u16* __restrict__ WT,
                                           int rows, int cols, int tr, int tc, int t){
  __shared__ u16 T[64][66];
  int r0 = tr*64, c0 = tc*64;
  int r = t >> 2, cq = (t & 3) * 16;
  const float* src = W + (size_t)(r0 + r)*cols + c0 + cq;
  #pragma unroll
  for (int j = 0; j < 4; j++){
    float4 v = *(const float4*)(src + 4*j);
    us4 o; o.x = f2b(v.x); o.y = f2b(v.y); o.z = f2b(v.z); o.w = f2b(v.w);
    *(us4*)&T[r][cq + 4*j] = o;
  }
  __syncthreads();
  int c = t >> 2, rq = (t & 3) * 16;
  us8 o0, o1;
  #pragma unroll
  for (int j = 0; j < 8; j++){ o0[j] = T[rq + j][c]; o1[j] = T[rq + 8 + j][c]; }
  u16* dstp = WT + (size_t)(c0 + c)*rows + r0 + rq;
  *(us8*)dstp = o0;
  *(us8*)(dstp + 8) = o1;
}

// ============ prologue: deg count (vec4, first) + BN1 stats + weight transpose (32 tiles) ============
__global__ __launch_bounds__(256) void k_prologue(
    const float* __restrict__ Wq, const float* __restrict__ Wk, const float* __restrict__ Wv,
    const float* __restrict__ Wo, const float* __restrict__ W1, const float* __restrict__ W2,
    u16* __restrict__ wtq, u16* __restrict__ wtk, u16* __restrict__ wtv,
    u16* __restrict__ wto, u16* __restrict__ wt1, u16* __restrict__ wt2,
    const float* __restrict__ h, float* __restrict__ sums,
    const int* __restrict__ dst, int* __restrict__ deg,
    int nDeg, int nBn, int N, int E){
  __shared__ float ls[256], ls2[256];
  int b = blockIdx.x, t = threadIdx.x;
  if (b < nDeg){
    int e = (b*256 + t) * 4;
    if (e + 3 < E){
      int4 d = *(const int4*)(dst + e);
      atomicAdd(&deg[d.x], 1); atomicAdd(&deg[d.y], 1);
      atomicAdd(&deg[d.z], 1); atomicAdd(&deg[d.w], 1);
    } else {
      for (int k = e; k < E; k++) atomicAdd(&deg[dst[k]], 1);
    }
    return;
  }
  b -= nDeg;
  if (b < nBn){
    int col = t & 127, half = t >> 7;
    int r0 = b * 128; int r1 = r0 + 128; if (r1 > N) r1 = N;
    float s = 0.f, s2 = 0.f;
    for (int r = r0 + half; r < r1; r += 2){ float v = h[(size_t)r*NDIM + col]; s += v; s2 += v*v; }
    ls[t] = s; ls2[t] = s2; __syncthreads();
    if (t < 128){ atomicAdd(&sums[col], ls[t] + ls[t+128]); atomicAdd(&sums[128+col], ls2[t] + ls2[t+128]); }
    return;
  }
  b -= nBn;
  // 32 transpose tiles: [0,16)=Wq/Wk/Wv/Wo 2x2 each, [16,24)=W1 2x4, [24,32)=W2 4x2
  if (b < 16){
    const float* Ws[4] = {Wq, Wk, Wv, Wo};
    u16* Ts[4] = {wtq, wtk, wtv, wto};
    int wi = b >> 2, ti = b & 3;
    wconv_tile(Ws[wi], Ts[wi], 128, 128, ti >> 1, ti & 1, t);
  } else if (b < 24){
    int ti = b - 16;
    wconv_tile(W1, wt1, 128, 256, ti >> 2, ti & 3, t);
  } else {
    int ti = b - 24;
    wconv_tile(W2, wt2, 256, 128, ti & 3, ti >> 2, t);
  }
}

// ============ block 0: BN1 finalize; blocks 1..nb: scan partials ============
__global__ __launch_bounds__(256) void k_bnfinal_scanpart(
    const float* __restrict__ sums, const float* __restrict__ g, const float* __restrict__ b_,
    float* __restrict__ scsh, const int* __restrict__ deg, int* __restrict__ bsum, int N){
  __shared__ int ls[256];
  int t = threadIdx.x, b = blockIdx.x;
  if (b == 0){
    if (t < 128){
      float mean = sums[t] / (float)N;
      float var  = sums[128+t] / (float)N - mean*mean;
      float rstd = rsqrtf(var + EPSV);
      float sc = g[t] * rstd;
      scsh[t] = sc; scsh[128+t] = b_[t] - mean*sc;
    }
    return;
  }
  b -= 1;
  int i = b*256 + t;
  ls[t] = (i < N) ? deg[i] : 0; __syncthreads();
  for (int off = 128; off > 0; off >>= 1){
    if (t < off) ls[t] += ls[t + off];
    __syncthreads();
  }
  if (t == 0) bsum[b] = ls[0];
}

__global__ __launch_bounds__(256) void k_scan_top(int* __restrict__ bsum, int nb, int* __restrict__ rowptr, int N, int E){
  __shared__ int ls[256];
  int t = threadIdx.x;
  int v = (t < nb) ? bsum[t] : 0; ls[t] = v; __syncthreads();
  for (int off = 1; off < 256; off <<= 1){
    int add = (t >= off) ? ls[t - off] : 0;
    __syncthreads();
    ls[t] += add;
    __syncthreads();
  }
  if (t < nb) bsum[t] = ls[t] - v;
  if (t == 0) rowptr[N] = E;
}

__global__ __launch_bounds__(256) void k_scan_down(const int* __restrict__ deg, const int* __restrict__ bsum,
                                                   int* __restrict__ rowptr, int* __restrict__ cursor, int N){
  __shared__ int ls[256];
  int t = threadIdx.x; int i = blockIdx.x*256 + t;
  int v = (i < N) ? deg[i] : 0; ls[t] = v; __syncthreads();
  for (int off = 1; off < 256; off <<= 1){
    int add = (t >= off) ? ls[t - off] : 0;
    __syncthreads();
    ls[t] += add;
    __syncthreads();
  }
  if (i < N){ int rp = ls[t] - v + bsum[blockIdx.x]; rowptr[i] = rp; cursor[i] = rp; }
}

// ============ merged: scatter (first nS blocks) + BN1-apply + QKV projection (MFMA) ============
__global__ __launch_bounds__(256) void k_qkv_scatter(
    const float* __restrict__ h, const float* __restrict__ scsh,
    const u16* __restrict__ WTq, const u16* __restrict__ WTk, const u16* __restrict__ WTv,
    u16* __restrict__ Q, u16* __restrict__ K, u16* __restrict__ V, int N,
    const int* __restrict__ src, const int* __restrict__ dst,
    int* __restrict__ cursor, int* __restrict__ csr_src, int E, int nS){
  __shared__ u16 hn[64][136];
  int t = threadIdx.x;
  int b = blockIdx.x;
  if (b < nS){
    int e = (b*256 + t) * 4;
    if (e + 3 < E){
      int4 s4 = *(const int4*)(src + e);
      int4 d4 = *(const int4*)(dst + e);
      csr_src[atomicAdd(&cursor[d4.x], 1)] = s4.x;
      csr_src[atomicAdd(&cursor[d4.y], 1)] = s4.y;
      csr_src[atomicAdd(&cursor[d4.z], 1)] = s4.z;
      csr_src[atomicAdd(&cursor[d4.w], 1)] = s4.w;
    } else {
      for (int k = e; k < E; k++) csr_src[atomicAdd(&cursor[dst[k]], 1)] = src[k];
    }
    return;
  }
  int r0 = (b - nS) * 64;
  {
    int row = t >> 2, c0 = (t & 3) * 32; int rr = r0 + row;
    #pragma unroll
    for (int j = 0; j < 8; j++){
      int c = c0 + 4*j;
      float4 v = make_float4(0.f,0.f,0.f,0.f);
      if (rr < N) v = *(const float4*)(h + (size_t)rr*NDIM + c);
      us4 o;
      o.x = f2b(v.x * scsh[c]   + scsh[128+c]);
      o.y = f2b(v.y * scsh[c+1] + scsh[129+c]);
      o.z = f2b(v.z * scsh[c+2] + scsh[130+c]);
      o.w = f2b(v.w * scsh[c+3] + scsh[131+c]);
      *(us4*)&hn[row][c] = o;
    }
  }
  __syncthreads();
  int lane = t & 63, w = t >> 6;
  int lr = lane & 15, kg = lane >> 4;
  f32x4 zero = {0.f,0.f,0.f,0.f};

  #define DO_PASS(WT, OUT) { \
    f32x4 acc[2][4]; \
    _Pragma("unroll") for (int n = 0; n < 2; n++) _Pragma("unroll") for (int m = 0; m < 4; m++) acc[n][m] = zero; \
    gemm_tiles<2,4,128,136>(&hn[0][0], WT, lr, kg, w*32, acc); \
    _Pragma("unroll") for (int n = 0; n < 2; n++){ \
      int col = w*32 + n*16 + lr; \
      _Pragma("unroll") for (int m = 0; m < 4; m++) \
        _Pragma("unroll") for (int r = 0; r < 4; r++){ \
          int rr = r0 + m*16 + kg*4 + r; \
          if (rr < N) OUT[(size_t)rr*NDIM + col] = f2b(acc[n][m][r]); \
        } \
    } }
  DO_PASS(WTq, Q)
  DO_PASS(WTk, K)
  DO_PASS(WTv, V)
  #undef DO_PASS
}

// ============ fused edge phase: score + softmax + weighted V aggregation ============
__global__ __launch_bounds__(256) void k_sagg(const int* __restrict__ rowptr, const int* __restrict__ csr_src,
                                              const u16* __restrict__ Q, const u16* __restrict__ K,
                                              const u16* __restrict__ V, u16* __restrict__ wV, int N){
  int w = threadIdx.x >> 6, l = threadIdx.x & 63;
  int n = blockIdx.x*4 + w;
  if (n >= N) return;
  int j8 = l >> 3;     // edge slot (score phase)
  int hh = l & 7;      // head (score phase)
  int d0 = l * 2;      // dims (agg phase)

  float qf[16];
  {
    us8 q0 = *(const us8*)(Q + (size_t)n*NDIM + hh*16);
    us8 q1 = *(const us8*)(Q + (size_t)n*NDIM + hh*16 + 8);
    #pragma unroll
    for (int t = 0; t < 8; t++){ qf[t] = b2f(q0[t]) * 0.25f; qf[8+t] = b2f(q1[t]) * 0.25f; }
  }

  int e0 = rowptr[n], e1 = rowptr[n+1];
  float ssum_l = 0.f, a0 = 0.f, a1 = 0.f;

  for (int i = e0; i < e1; i += 8){
    int nedge = e1 - i; if (nedge > 8) nedge = 8;
    int myE = i + j8;
    int sidx = csr_src[(myE < e1) ? myE : i];

    unsigned vv[8];
    #pragma unroll
    for (int j = 0; j < 8; j++){
      if (j >= nedge) break;
      int sj = __shfl(sidx, j*8);
      vv[j] = *(const unsigned*)(V + (size_t)sj*NDIM + d0);
    }

    us8 k0 = *(const us8*)(K + (size_t)sidx*NDIM + hh*16);
    us8 k1 = *(const us8*)(K + (size_t)sidx*NDIM + hh*16 + 8);
    float p = 0.f;
    #pragma unroll
    for (int t = 0; t < 8; t++) p += qf[t]*b2f(k0[t]) + qf[8+t]*b2f(k1[t]);
    p = fminf(5.f, fmaxf(-5.f, p));
    float wgt = (myE < e1) ? __expf(p) : 0.f;
    ssum_l += wgt;

    #pragma unroll
    for (int j = 0; j < 8; j++){
      if (j >= nedge) break;
      float wj = __shfl(wgt, j*8 + j8);
      a0 += wj * blo(vv[j]);
      a1 += wj * bhi(vv[j]);
    }
  }

  ssum_l += __shfl_xor(ssum_l, 8);
  ssum_l += __shfl_xor(ssum_l, 16);
  ssum_l += __shfl_xor(ssum_l, 32);
  float ssum = __shfl(ssum_l, j8);
  float inv = (e1 > e0) ? 1.f/ssum : 0.f;
  unsigned pk = (unsigned)f2b(a0*inv) | (((unsigned)f2b(a1*inv)) << 16);
  *(unsigned*)(wV + (size_t)n*NDIM + d0) = pk;
}

// ============ O-projection + residual + BN2 stats (MFMA) ============
__global__ __launch_bounds__(256) void k_h2(const u16* __restrict__ wV, const u16* __restrict__ WTo,
                                            const float* __restrict__ bo, const float* __restrict__ h,
                                            float* __restrict__ h2, float* __restrict__ sums2, int N){
  __shared__ u16 tw[64][136];
  int t = threadIdx.x; int r0 = blockIdx.x * 64;
  {
    int row = t >> 2, c0 = (t & 3) * 32; int rr = r0 + row;
    #pragma unroll
    for (int j = 0; j < 4; j++){
      int c = c0 + 8*j;
      us8 v = {0,0,0,0,0,0,0,0};
      if (rr < N) v = *(const us8*)(wV + (size_t)rr*NDIM + c);
      *(us8*)&tw[row][c] = v;
    }
  }
  __syncthreads();
  int lane = t & 63, w = t >> 6;
  int lr = lane & 15, kg = lane >> 4;
  f32x4 zero = {0.f,0.f,0.f,0.f};
  f32x4 acc[2][4];
  #pragma unroll
  for (int n = 0; n < 2; n++)
    #pragma unroll
    for (int m = 0; m < 4; m++) acc[n][m] = zero;
  gemm_tiles<2,4,128,136>(&tw[0][0], WTo, lr, kg, w*32, acc);

  float sv[2] = {0.f, 0.f}, qv[2] = {0.f, 0.f};
  #pragma unroll
  for (int n = 0; n < 2; n++){
    int col = w*32 + n*16 + lr;
    float bb = bo[col];
    #pragma unroll
    for (int m = 0; m < 4; m++)
      #pragma unroll
      for (int r = 0; r < 4; r++){
        int rr = r0 + m*16 + kg*4 + r;
        if (rr < N){
          size_t o = (size_t)rr*NDIM + col;
          float v = acc[n][m][r] + bb + h[o];
          h2[o] = v;
          sv[n] += v; qv[n] += v*v;
        }
      }
  }
  #pragma unroll
  for (int n = 0; n < 2; n++){
    float s = sv[n], q = qv[n];
    s += __shfl_xor(s, 16); s += __shfl_xor(s, 32);
    q += __shfl_xor(q, 16); q += __shfl_xor(q, 32);
    if (kg == 0){
      int col = w*32 + n*16 + lr;
      atomicAdd(&sums2[col], s);
      atomicAdd(&sums2[128+col], q);
    }
  }
}

// ============ BN2-apply + FFN + residual (MFMA) ============
__global__ __launch_bounds__(256) void k_ffn(const float* __restrict__ h2, const float* __restrict__ scsh,
                                             const u16* __restrict__ WT1, const float* __restrict__ b1,
                                             const u16* __restrict__ WT2, const float* __restrict__ b2,
                                             float* __restrict__ out, int N){
  __shared__ u16 x[64][136];
  __shared__ u16 tt[64][264];
  int t = threadIdx.x; int r0 = blockIdx.x * 64;
  {
    int row = t >> 2, c0 = (t & 3) * 32; int rr = r0 + row;
    #pragma unroll
    for (int j = 0; j < 8; j++){
      int c = c0 + 4*j;
      float4 v = make_float4(0.f,0.f,0.f,0.f);
      if (rr < N) v = *(const float4*)(h2 + (size_t)rr*NDIM + c);
      us4 o;
      o.x = f2b(v.x * scsh[c]   + scsh[128+c]);
      o.y = f2b(v.y * scsh[c+1] + scsh[129+c]);
      o.z = f2b(v.z * scsh[c+2] + scsh[130+c]);
      o.w = f2b(v.w * scsh[c+3] + scsh[131+c]);
      *(us4*)&x[row][c] = o;
    }
  }
  __syncthreads();
  int lane = t & 63, w = t >> 6;
  int lr = lane & 15, kg = lane >> 4;
  f32x4 zero = {0.f,0.f,0.f,0.f};
  {
    f32x4 a1[4][4];
    #pragma unroll
    for (int n = 0; n < 4; n++)
      #pragma unroll
      for (int m = 0; m < 4; m++) a1[n][m] = zero;
    gemm_tiles<4,4,128,136>(&x[0][0], WT1, lr, kg, w*64, a1);
    #pragma unroll
    for (int n = 0; n < 4; n++){
      int col = w*64 + n*16 + lr;
      float bb = b1[col];
      #pragma unroll
      for (int m = 0; m < 4; m++)
        #pragma unroll
        for (int r = 0; r < 4; r++)
          tt[m*16 + kg*4 + r][col] = f2b(fmaxf(a1[n][m][r] + bb, 0.f));
    }
  }
  __syncthreads();
  {
    f32x4 a2[2][4];
    #pragma unroll
    for (int n = 0; n < 2; n++)
      #pragma unroll
      for (int m = 0; m < 4; m++) a2[n][m] = zero;
    gemm_tiles<2,8,256,264>(&tt[0][0], WT2, lr, kg, w*32, a2);
    #pragma unroll
    for (int n = 0; n < 2; n++){
      int col = w*32 + n*16 + lr;
      float bb = b2[col];
      #pragma unroll
      for (int m = 0; m < 4; m++)
        #pragma unroll
        for (int r = 0; r < 4; r++){
          int rr = r0 + m*16 + kg*4 + r;
          if (rr < N){
            size_t o = (size_t)rr*NDIM + col;
            out[o] = h2[o] + a2[n][m][r] + bb;
          }
        }
    }
  }
}

extern "C" void kernel_launch(void* const* d_in, const int* in_sizes, int n_in,
                              void* d_out, int out_size, void* d_ws, size_t ws_size,
                              hipStream_t stream) {
  const float* h    = (const float*)d_in[0];
  const int*   src  = (const int*)d_in[1];
  const int*   dst  = (const int*)d_in[2];
  const float* Wq   = (const float*)d_in[3];
  const float* Wk   = (const float*)d_in[4];
  const float* Wv   = (const float*)d_in[5];
  const float* Wo   = (const float*)d_in[6];
  const float* bo   = (const float*)d_in[7];
  const float* bn1g = (const float*)d_in[8];
  const float* bn1b = (const float*)d_in[9];
  const float* bn2g = (const float*)d_in[10];
  const float* bn2b = (const float*)d_in[11];
  const float* W1   = (const float*)d_in[12];
  const float* b1   = (const float*)d_in[13];
  const float* W2   = (const float*)d_in[14];
  const float* b2   = (const float*)d_in[15];
  float* out = (float*)d_out;

  int N = in_sizes[0] / NDIM;
  int E = in_sizes[1];
  size_t fN = (size_t)N * NDIM;

  u16* Q  = (u16*)d_ws;
  u16* K  = Q + fN;
  u16* V  = K + fN;
  u16* wV = Q;                                  // reuse: each wave reads Q[n] before writing wV[n]
  float* h2    = (float*)(V + fN);              // fN floats
  int* deg     = (int*)(h2 + fN);
  int* rowptr  = deg + N;
  int* cursor  = rowptr + (N + 1);
  int* bsum    = cursor + N;
  int* csr_src = bsum + 256;
  float* sums1 = (float*)(csr_src + E);
  float* sums2 = sums1 + 256;
  float* scsh1 = sums2 + 256;
  float* scsh2 = scsh1 + 256;
  u16* wtq = (u16*)(scsh2 + 256);
  u16* wtk = wtq + NDIM*NDIM;
  u16* wtv = wtk + NDIM*NDIM;
  u16* wto = wtv + NDIM*NDIM;
  u16* wt1 = wto + NDIM*NDIM;
  u16* wt2 = wt1 + NDIM*2*NDIM;

  hipMemsetAsync(deg, 0, (size_t)N * sizeof(int), stream);
  hipMemsetAsync(sums1, 0, 512 * sizeof(float), stream);

  int nb   = (N + 255) / 256;
  int nBn  = (N + 127) / 128;
  int nE4  = (E + 3) / 4;
  int nDeg = (nE4 + 255) / 256;
  int nQ   = (N + 63) / 64;

  k_prologue<<<nDeg + nBn + 32, 256, 0, stream>>>(Wq, Wk, Wv, Wo, W1, W2,
                                                  wtq, wtk, wtv, wto, wt1, wt2,
                                                  h, sums1, dst, deg, nDeg, nBn, N, E);
  k_bnfinal_scanpart<<<1 + nb, 256, 0, stream>>>(sums1, bn1g, bn1b, scsh1, deg, bsum, N);
  k_scan_top<<<1, 256, 0, stream>>>(bsum, nb, rowptr, N, E);
  k_scan_down<<<nb, 256, 0, stream>>>(deg, bsum, rowptr, cursor, N);

  k_qkv_scatter<<<nDeg + nQ, 256, 0, stream>>>(h, scsh1, wtq, wtk, wtv, Q, K, V, N,
                                               src, dst, cursor, csr_src, E, nDeg);

  k_sagg<<<(N + 3)/4, 256, 0, stream>>>(rowptr, csr_src, Q, K, V, wV, N);

  k_h2<<<(N + 63)/64, 256, 0, stream>>>(wV, wto, bo, h, h2, sums2, N);
  k_bnfinal_scanpart<<<1, 256, 0, stream>>>(sums2, bn2g, bn2b, scsh2, deg, bsum, N);
  k_ffn<<<(N + 63)/64, 256, 0, stream>>>(h2, scsh2, wt1, b1, wt2, b2, out, N);
}

// Round 6
// 285.765 us; speedup vs baseline: 2.3423x; 1.1156x over previous
//
#include <hip/hip_runtime.h>
#include <hip/hip_bf16.h>

#define NDIM 128
#define NHEAD 8
#define EPSV 1e-5f

typedef unsigned short u16;
using bf16x8 = __attribute__((ext_vector_type(8))) short;
using f32x4  = __attribute__((ext_vector_type(4))) float;
using us8    = __attribute__((ext_vector_type(8))) unsigned short;
using us4    = __attribute__((ext_vector_type(4))) unsigned short;

__device__ __forceinline__ u16 f2b(float x){
  union { float f; unsigned u; } v; v.f = x;
  unsigned r = v.u + 0x7FFFu + ((v.u >> 16) & 1u);
  return (u16)(r >> 16);
}
__device__ __forceinline__ float b2f(u16 u){
  union { unsigned u; float f; } v; v.u = ((unsigned)u) << 16; return v.f;
}
__device__ __forceinline__ float blo(unsigned u){
  union { unsigned u; float f; } v; v.u = u << 16; return v.f;
}
__device__ __forceinline__ float bhi(unsigned u){
  union { unsigned u; float f; } v; v.u = u & 0xFFFF0000u; return v.f;
}

// A-frag: lane provides A[lane%16][(lane/16)*8 + j]; B-frag: B[(lane/16)*8+j][lane%16]
// C/D: col = lane&15, row = (lane>>4)*4 + reg   (measured m89)
template<int NT, int KS, int WTLD, int XSTR>
__device__ __forceinline__ void gemm_tiles(const u16* X, const u16* __restrict__ WT,
                                           int lr, int kg, int colbase, f32x4 (&acc)[NT][4]){
  #pragma unroll
  for (int ks = 0; ks < KS; ks++){
    bf16x8 a[4];
    #pragma unroll
    for (int m = 0; m < 4; m++)
      a[m] = *(const bf16x8*)(X + (size_t)(m*16 + lr)*XSTR + ks*32 + kg*8);
    #pragma unroll
    for (int n = 0; n < NT; n++){
      int col = colbase + n*16 + lr;
      bf16x8 b = *(const bf16x8*)(WT + (size_t)col*WTLD + ks*32 + kg*8);
      #pragma unroll
      for (int m = 0; m < 4; m++)
        acc[n][m] = __builtin_amdgcn_mfma_f32_16x16x32_bf16(a[m], b, acc[n][m], 0, 0, 0);
    }
  }
}

// transpose one 64x64 tile of W (rows x cols, f32) into WT (cols x rows, bf16), coalesced both ways
__device__ __forceinline__ void wconv_tile(const float* __restrict__ W, u16* __restrict__ WT,
                                           int rows, int cols, int tr, int tc, int t){
  __shared__ u16 T[64][66];
  int r0 = tr*64, c0 = tc*64;
  int r = t >> 2, cq = (t & 3) * 16;
  const float* src = W + (size_t)(r0 + r)*cols + c0 + cq;
  #pragma unroll
  for (int j = 0; j < 4; j++){
    float4 v = *(const float4*)(src + 4*j);
    us4 o; o.x = f2b(v.x); o.y = f2b(v.y); o.z = f2b(v.z); o.w = f2b(v.w);
    *(us4*)&T[r][cq + 4*j] = o;
  }
  __syncthreads();
  int c = t >> 2, rq = (t & 3) * 16;
  us8 o0, o1;
  #pragma unroll
  for (int j = 0; j < 8; j++){ o0[j] = T[rq + j][c]; o1[j] = T[rq + 8 + j][c]; }
  u16* dstp = WT + (size_t)(c0 + c)*rows + r0 + rq;
  *(us8*)dstp = o0;
  *(us8*)(dstp + 8) = o1;
}

// ============ prologue: deg count + rank capture (vec4) + BN1 stats + weight transpose ============
__global__ __launch_bounds__(256) void k_prologue(
    const float* __restrict__ Wq, const float* __restrict__ Wk, const float* __restrict__ Wv,
    const float* __restrict__ Wo, const float* __restrict__ W1, const float* __restrict__ W2,
    u16* __restrict__ wtq, u16* __restrict__ wtk, u16* __restrict__ wtv,
    u16* __restrict__ wto, u16* __restrict__ wt1, u16* __restrict__ wt2,
    const float* __restrict__ h, float* __restrict__ sums,
    const int* __restrict__ dst, int* __restrict__ deg, int* __restrict__ rank,
    int nDeg, int nBn, int N, int E){
  __shared__ float ls[256], ls2[256];
  int b = blockIdx.x, t = threadIdx.x;
  if (b < nDeg){
    int e = (b*256 + t) * 4;
    if (e + 3 < E){
      int4 d = *(const int4*)(dst + e);
      int4 r;
      r.x = atomicAdd(&deg[d.x], 1);
      r.y = atomicAdd(&deg[d.y], 1);
      r.z = atomicAdd(&deg[d.z], 1);
      r.w = atomicAdd(&deg[d.w], 1);
      *(int4*)(rank + e) = r;
    } else {
      for (int k = e; k < E; k++) rank[k] = atomicAdd(&deg[dst[k]], 1);
    }
    return;
  }
  b -= nDeg;
  if (b < nBn){
    int col = t & 127, half = t >> 7;
    int r0 = b * 128; int r1 = r0 + 128; if (r1 > N) r1 = N;
    float s = 0.f, s2 = 0.f;
    for (int r = r0 + half; r < r1; r += 2){ float v = h[(size_t)r*NDIM + col]; s += v; s2 += v*v; }
    ls[t] = s; ls2[t] = s2; __syncthreads();
    if (t < 128){ atomicAdd(&sums[col], ls[t] + ls[t+128]); atomicAdd(&sums[128+col], ls2[t] + ls2[t+128]); }
    return;
  }
  b -= nBn;
  // 32 transpose tiles: [0,16)=Wq/Wk/Wv/Wo 2x2 each, [16,24)=W1 2x4, [24,32)=W2 4x2
  if (b < 16){
    const float* Ws[4] = {Wq, Wk, Wv, Wo};
    u16* Ts[4] = {wtq, wtk, wtv, wto};
    int wi = b >> 2, ti = b & 3;
    wconv_tile(Ws[wi], Ts[wi], 128, 128, ti >> 1, ti & 1, t);
  } else if (b < 24){
    int ti = b - 16;
    wconv_tile(W1, wt1, 128, 256, ti >> 2, ti & 3, t);
  } else {
    int ti = b - 24;
    wconv_tile(W2, wt2, 256, 128, ti & 3, ti >> 2, t);
  }
}

// ============ block 0: BN finalize; blocks 1..nb: scan partials ============
__global__ __launch_bounds__(256) void k_bnfinal_scanpart(
    const float* __restrict__ sums, const float* __restrict__ g, const float* __restrict__ b_,
    float* __restrict__ scsh, const int* __restrict__ deg, int* __restrict__ bsum, int N){
  __shared__ int ls[256];
  int t = threadIdx.x, b = blockIdx.x;
  if (b == 0){
    if (t < 128){
      float mean = sums[t] / (float)N;
      float var  = sums[128+t] / (float)N - mean*mean;
      float rstd = rsqrtf(var + EPSV);
      float sc = g[t] * rstd;
      scsh[t] = sc; scsh[128+t] = b_[t] - mean*sc;
    }
    return;
  }
  b -= 1;
  int i = b*256 + t;
  ls[t] = (i < N) ? deg[i] : 0; __syncthreads();
  for (int off = 128; off > 0; off >>= 1){
    if (t < off) ls[t] += ls[t + off];
    __syncthreads();
  }
  if (t == 0) bsum[b] = ls[0];
}

__global__ __launch_bounds__(256) void k_scan_top(int* __restrict__ bsum, int nb, int* __restrict__ rowptr, int N, int E){
  __shared__ int ls[256];
  int t = threadIdx.x;
  int v = (t < nb) ? bsum[t] : 0; ls[t] = v; __syncthreads();
  for (int off = 1; off < 256; off <<= 1){
    int add = (t >= off) ? ls[t - off] : 0;
    __syncthreads();
    ls[t] += add;
    __syncthreads();
  }
  if (t < nb) bsum[t] = ls[t] - v;
  if (t == 0) rowptr[N] = E;
}

__global__ __launch_bounds__(256) void k_scan_down(const int* __restrict__ deg, const int* __restrict__ bsum,
                                                   int* __restrict__ rowptr, int N){
  __shared__ int ls[256];
  int t = threadIdx.x; int i = blockIdx.x*256 + t;
  int v = (i < N) ? deg[i] : 0; ls[t] = v; __syncthreads();
  for (int off = 1; off < 256; off <<= 1){
    int add = (t >= off) ? ls[t - off] : 0;
    __syncthreads();
    ls[t] += add;
    __syncthreads();
  }
  if (i < N) rowptr[i] = ls[t] - v + bsum[blockIdx.x];
}

// ============ scatter: plain stores, no atomics (rank precomputed in prologue) ============
__global__ __launch_bounds__(256) void k_scatter(const int* __restrict__ src, const int* __restrict__ dst,
                                                 const int* __restrict__ rank, const int* __restrict__ rowptr,
                                                 int* __restrict__ csr_src, int E){
  int e = (blockIdx.x*256 + threadIdx.x) * 4;
  if (e + 3 < E){
    int4 s4 = *(const int4*)(src + e);
    int4 d4 = *(const int4*)(dst + e);
    int4 r4 = *(const int4*)(rank + e);
    csr_src[rowptr[d4.x] + r4.x] = s4.x;
    csr_src[rowptr[d4.y] + r4.y] = s4.y;
    csr_src[rowptr[d4.z] + r4.z] = s4.z;
    csr_src[rowptr[d4.w] + r4.w] = s4.w;
  } else {
    for (int k = e; k < E; k++) csr_src[rowptr[dst[k]] + rank[k]] = src[k];
  }
}

// ============ BN1-apply + QKV projection (MFMA, LDS-staged coalesced output) ============
__global__ __launch_bounds__(256) void k_qkv(const float* __restrict__ h, const float* __restrict__ scsh,
                                             const u16* __restrict__ WTq, const u16* __restrict__ WTk, const u16* __restrict__ WTv,
                                             u16* __restrict__ Q, u16* __restrict__ K, u16* __restrict__ V, int N){
  __shared__ u16 hn[64][136];
  __shared__ u16 ob[64][136];
  int t = threadIdx.x; int r0 = blockIdx.x * 64;
  {
    int row = t >> 2, c0 = (t & 3) * 32; int rr = r0 + row;
    #pragma unroll
    for (int j = 0; j < 8; j++){
      int c = c0 + 4*j;
      float4 v = make_float4(0.f,0.f,0.f,0.f);
      if (rr < N) v = *(const float4*)(h + (size_t)rr*NDIM + c);
      us4 o;
      o.x = f2b(v.x * scsh[c]   + scsh[128+c]);
      o.y = f2b(v.y * scsh[c+1] + scsh[129+c]);
      o.z = f2b(v.z * scsh[c+2] + scsh[130+c]);
      o.w = f2b(v.w * scsh[c+3] + scsh[131+c]);
      *(us4*)&hn[row][c] = o;
    }
  }
  __syncthreads();
  int lane = t & 63, w = t >> 6;
  int lr = lane & 15, kg = lane >> 4;
  int srow = t >> 2, sc0 = (t & 3) * 32;   // staging-store mapping
  f32x4 zero = {0.f,0.f,0.f,0.f};

  #define DO_PASS(WT, OUT, FIRST) { \
    f32x4 acc[2][4]; \
    _Pragma("unroll") for (int n = 0; n < 2; n++) _Pragma("unroll") for (int m = 0; m < 4; m++) acc[n][m] = zero; \
    gemm_tiles<2,4,128,136>(&hn[0][0], WT, lr, kg, w*32, acc); \
    if (!FIRST) __syncthreads(); \
    _Pragma("unroll") for (int n = 0; n < 2; n++){ \
      int col = w*32 + n*16 + lr; \
      _Pragma("unroll") for (int m = 0; m < 4; m++) \
        _Pragma("unroll") for (int r = 0; r < 4; r++) \
          ob[m*16 + kg*4 + r][col] = f2b(acc[n][m][r]); \
    } \
    __syncthreads(); \
    if (r0 + srow < N){ \
      u16* dp = OUT + (size_t)(r0 + srow)*NDIM + sc0; \
      _Pragma("unroll") for (int j = 0; j < 4; j++) \
        *(us8*)(dp + j*8) = *(const us8*)&ob[srow][sc0 + j*8]; \
    } }
  DO_PASS(WTq, Q, true)
  DO_PASS(WTk, K, false)
  DO_PASS(WTv, V, false)
  #undef DO_PASS
}

// ============ fused edge phase: score + softmax + weighted V aggregation ============
__global__ __launch_bounds__(256) void k_sagg(const int* __restrict__ rowptr, const int* __restrict__ csr_src,
                                              const u16* __restrict__ Q, const u16* __restrict__ K,
                                              const u16* __restrict__ V, u16* __restrict__ wV, int N){
  int w = threadIdx.x >> 6, l = threadIdx.x & 63;
  int n = blockIdx.x*4 + w;
  if (n >= N) return;
  int j8 = l >> 3;     // edge slot (score phase)
  int hh = l & 7;      // head (score phase)
  int d0 = l * 2;      // dims (agg phase)

  float qf[16];
  {
    us8 q0 = *(const us8*)(Q + (size_t)n*NDIM + hh*16);
    us8 q1 = *(const us8*)(Q + (size_t)n*NDIM + hh*16 + 8);
    #pragma unroll
    for (int t = 0; t < 8; t++){ qf[t] = b2f(q0[t]) * 0.25f; qf[8+t] = b2f(q1[t]) * 0.25f; }
  }

  int e0 = rowptr[n], e1 = rowptr[n+1];
  float ssum_l = 0.f, a0 = 0.f, a1 = 0.f;

  for (int i = e0; i < e1; i += 8){
    int nedge = e1 - i; if (nedge > 8) nedge = 8;
    int myE = i + j8;
    int sidx = csr_src[(myE < e1) ? myE : i];

    unsigned vv[8];
    #pragma unroll
    for (int j = 0; j < 8; j++){
      if (j >= nedge) break;
      int sj = __shfl(sidx, j*8);
      vv[j] = *(const unsigned*)(V + (size_t)sj*NDIM + d0);
    }

    us8 k0 = *(const us8*)(K + (size_t)sidx*NDIM + hh*16);
    us8 k1 = *(const us8*)(K + (size_t)sidx*NDIM + hh*16 + 8);
    float p = 0.f;
    #pragma unroll
    for (int t = 0; t < 8; t++) p += qf[t]*b2f(k0[t]) + qf[8+t]*b2f(k1[t]);
    p = fminf(5.f, fmaxf(-5.f, p));
    float wgt = (myE < e1) ? __expf(p) : 0.f;
    ssum_l += wgt;

    #pragma unroll
    for (int j = 0; j < 8; j++){
      if (j >= nedge) break;
      float wj = __shfl(wgt, j*8 + j8);
      a0 += wj * blo(vv[j]);
      a1 += wj * bhi(vv[j]);
    }
  }

  ssum_l += __shfl_xor(ssum_l, 8);
  ssum_l += __shfl_xor(ssum_l, 16);
  ssum_l += __shfl_xor(ssum_l, 32);
  float ssum = __shfl(ssum_l, j8);
  float inv = (e1 > e0) ? 1.f/ssum : 0.f;
  unsigned pk = (unsigned)f2b(a0*inv) | (((unsigned)f2b(a1*inv)) << 16);
  *(unsigned*)(wV + (size_t)n*NDIM + d0) = pk;
}

// ============ O-projection + residual + BN2 stats (MFMA) ============
__global__ __launch_bounds__(256) void k_h2(const u16* __restrict__ wV, const u16* __restrict__ WTo,
                                            const float* __restrict__ bo, const float* __restrict__ h,
                                            float* __restrict__ h2, float* __restrict__ sums2, int N){
  __shared__ u16 tw[64][136];
  int t = threadIdx.x; int r0 = blockIdx.x * 64;
  {
    int row = t >> 2, c0 = (t & 3) * 32; int rr = r0 + row;
    #pragma unroll
    for (int j = 0; j < 4; j++){
      int c = c0 + 8*j;
      us8 v = {0,0,0,0,0,0,0,0};
      if (rr < N) v = *(const us8*)(wV + (size_t)rr*NDIM + c);
      *(us8*)&tw[row][c] = v;
    }
  }
  __syncthreads();
  int lane = t & 63, w = t >> 6;
  int lr = lane & 15, kg = lane >> 4;
  f32x4 zero = {0.f,0.f,0.f,0.f};
  f32x4 acc[2][4];
  #pragma unroll
  for (int n = 0; n < 2; n++)
    #pragma unroll
    for (int m = 0; m < 4; m++) acc[n][m] = zero;
  gemm_tiles<2,4,128,136>(&tw[0][0], WTo, lr, kg, w*32, acc);

  float sv[2] = {0.f, 0.f}, qv[2] = {0.f, 0.f};
  #pragma unroll
  for (int n = 0; n < 2; n++){
    int col = w*32 + n*16 + lr;
    float bb = bo[col];
    #pragma unroll
    for (int m = 0; m < 4; m++)
      #pragma unroll
      for (int r = 0; r < 4; r++){
        int rr = r0 + m*16 + kg*4 + r;
        if (rr < N){
          size_t o = (size_t)rr*NDIM + col;
          float v = acc[n][m][r] + bb + h[o];
          h2[o] = v;
          sv[n] += v; qv[n] += v*v;
        }
      }
  }
  #pragma unroll
  for (int n = 0; n < 2; n++){
    float s = sv[n], q = qv[n];
    s += __shfl_xor(s, 16); s += __shfl_xor(s, 32);
    q += __shfl_xor(q, 16); q += __shfl_xor(q, 32);
    if (kg == 0){
      int col = w*32 + n*16 + lr;
      atomicAdd(&sums2[col], s);
      atomicAdd(&sums2[128+col], q);
    }
  }
}

// ============ BN2-apply + FFN + residual (MFMA) ============
__global__ __launch_bounds__(256) void k_ffn(const float* __restrict__ h2, const float* __restrict__ scsh,
                                             const u16* __restrict__ WT1, const float* __restrict__ b1,
                                             const u16* __restrict__ WT2, const float* __restrict__ b2,
                                             float* __restrict__ out, int N){
  __shared__ u16 x[64][136];
  __shared__ u16 tt[64][264];
  int t = threadIdx.x; int r0 = blockIdx.x * 64;
  {
    int row = t >> 2, c0 = (t & 3) * 32; int rr = r0 + row;
    #pragma unroll
    for (int j = 0; j < 8; j++){
      int c = c0 + 4*j;
      float4 v = make_float4(0.f,0.f,0.f,0.f);
      if (rr < N) v = *(const float4*)(h2 + (size_t)rr*NDIM + c);
      us4 o;
      o.x = f2b(v.x * scsh[c]   + scsh[128+c]);
      o.y = f2b(v.y * scsh[c+1] + scsh[129+c]);
      o.z = f2b(v.z * scsh[c+2] + scsh[130+c]);
      o.w = f2b(v.w * scsh[c+3] + scsh[131+c]);
      *(us4*)&x[row][c] = o;
    }
  }
  __syncthreads();
  int lane = t & 63, w = t >> 6;
  int lr = lane & 15, kg = lane >> 4;
  f32x4 zero = {0.f,0.f,0.f,0.f};
  {
    f32x4 a1[4][4];
    #pragma unroll
    for (int n = 0; n < 4; n++)
      #pragma unroll
      for (int m = 0; m < 4; m++) a1[n][m] = zero;
    gemm_tiles<4,4,128,136>(&x[0][0], WT1, lr, kg, w*64, a1);
    #pragma unroll
    for (int n = 0; n < 4; n++){
      int col = w*64 + n*16 + lr;
      float bb = b1[col];
      #pragma unroll
      for (int m = 0; m < 4; m++)
        #pragma unroll
        for (int r = 0; r < 4; r++)
          tt[m*16 + kg*4 + r][col] = f2b(fmaxf(a1[n][m][r] + bb, 0.f));
    }
  }
  __syncthreads();
  {
    f32x4 a2[2][4];
    #pragma unroll
    for (int n = 0; n < 2; n++)
      #pragma unroll
      for (int m = 0; m < 4; m++) a2[n][m] = zero;
    gemm_tiles<2,8,256,264>(&tt[0][0], WT2, lr, kg, w*32, a2);
    #pragma unroll
    for (int n = 0; n < 2; n++){
      int col = w*32 + n*16 + lr;
      float bb = b2[col];
      #pragma unroll
      for (int m = 0; m < 4; m++)
        #pragma unroll
        for (int r = 0; r < 4; r++){
          int rr = r0 + m*16 + kg*4 + r;
          if (rr < N){
            size_t o = (size_t)rr*NDIM + col;
            out[o] = h2[o] + a2[n][m][r] + bb;
          }
        }
    }
  }
}

extern "C" void kernel_launch(void* const* d_in, const int* in_sizes, int n_in,
                              void* d_out, int out_size, void* d_ws, size_t ws_size,
                              hipStream_t stream) {
  const float* h    = (const float*)d_in[0];
  const int*   src  = (const int*)d_in[1];
  const int*   dst  = (const int*)d_in[2];
  const float* Wq   = (const float*)d_in[3];
  const float* Wk   = (const float*)d_in[4];
  const float* Wv   = (const float*)d_in[5];
  const float* Wo   = (const float*)d_in[6];
  const float* bo   = (const float*)d_in[7];
  const float* bn1g = (const float*)d_in[8];
  const float* bn1b = (const float*)d_in[9];
  const float* bn2g = (const float*)d_in[10];
  const float* bn2b = (const float*)d_in[11];
  const float* W1   = (const float*)d_in[12];
  const float* b1   = (const float*)d_in[13];
  const float* W2   = (const float*)d_in[14];
  const float* b2   = (const float*)d_in[15];
  float* out = (float*)d_out;

  int N = in_sizes[0] / NDIM;
  int E = in_sizes[1];
  size_t fN = (size_t)N * NDIM;

  u16* Q  = (u16*)d_ws;
  u16* K  = Q + fN;
  u16* V  = K + fN;
  u16* wV = Q;                                  // reuse: each wave reads Q[n] before writing wV[n]
  float* h2    = (float*)(V + fN);              // fN floats
  int* deg     = (int*)(h2 + fN);
  int* rowptr  = deg + N;                       // N+1
  int* bsum    = rowptr + (N + 1);              // 256
  int* rank    = bsum + 256;                    // E
  int* csr_src = rank + E;                      // E
  float* sums1 = (float*)(csr_src + E);
  float* sums2 = sums1 + 256;
  float* scsh1 = sums2 + 256;
  float* scsh2 = scsh1 + 256;
  u16* wtq = (u16*)(scsh2 + 256);
  u16* wtk = wtq + NDIM*NDIM;
  u16* wtv = wtk + NDIM*NDIM;
  u16* wto = wtv + NDIM*NDIM;
  u16* wt1 = wto + NDIM*NDIM;
  u16* wt2 = wt1 + NDIM*2*NDIM;

  hipMemsetAsync(deg, 0, (size_t)N * sizeof(int), stream);
  hipMemsetAsync(sums1, 0, 512 * sizeof(float), stream);

  int nb   = (N + 255) / 256;
  int nBn  = (N + 127) / 128;
  int nE4  = (E + 3) / 4;
  int nDeg = (nE4 + 255) / 256;
  int nQ   = (N + 63) / 64;

  k_prologue<<<nDeg + nBn + 32, 256, 0, stream>>>(Wq, Wk, Wv, Wo, W1, W2,
                                                  wtq, wtk, wtv, wto, wt1, wt2,
                                                  h, sums1, dst, deg, rank, nDeg, nBn, N, E);
  k_bnfinal_scanpart<<<1 + nb, 256, 0, stream>>>(sums1, bn1g, bn1b, scsh1, deg, bsum, N);
  k_scan_top<<<1, 256, 0, stream>>>(bsum, nb, rowptr, N, E);
  k_scan_down<<<nb, 256, 0, stream>>>(deg, bsum, rowptr, N);
  k_scatter<<<nDeg, 256, 0, stream>>>(src, dst, rank, rowptr, csr_src, E);

  k_qkv<<<nQ, 256, 0, stream>>>(h, scsh1, wtq, wtk, wtv, Q, K, V, N);

  k_sagg<<<(N + 3)/4, 256, 0, stream>>>(rowptr, csr_src, Q, K, V, wV, N);

  k_h2<<<(N + 63)/64, 256, 0, stream>>>(wV, wto, bo, h, h2, sums2, N);
  k_bnfinal_scanpart<<<1, 256, 0, stream>>>(sums2, bn2g, bn2b, scsh2, deg, bsum, N);
  k_ffn<<<(N + 63)/64, 256, 0, stream>>>(h2, scsh2, wt1, b1, wt2, b2, out, N);
}

// Round 7
// 284.368 us; speedup vs baseline: 2.3538x; 1.0049x over previous
//
#include <hip/hip_runtime.h>
#include <hip/hip_bf16.h>

#define NDIM 128
#define NHEAD 8
#define EPSV 1e-5f

typedef unsigned short u16;
using bf16x8 = __attribute__((ext_vector_type(8))) short;
using f32x4  = __attribute__((ext_vector_type(4))) float;
using us8    = __attribute__((ext_vector_type(8))) unsigned short;
using us4    = __attribute__((ext_vector_type(4))) unsigned short;

__device__ __forceinline__ u16 f2b(float x){
  union { float f; unsigned u; } v; v.f = x;
  unsigned r = v.u + 0x7FFFu + ((v.u >> 16) & 1u);
  return (u16)(r >> 16);
}
__device__ __forceinline__ float b2f(u16 u){
  union { unsigned u; float f; } v; v.u = ((unsigned)u) << 16; return v.f;
}
__device__ __forceinline__ float blo(unsigned u){
  union { unsigned u; float f; } v; v.u = u << 16; return v.f;
}
__device__ __forceinline__ float bhi(unsigned u){
  union { unsigned u; float f; } v; v.u = u & 0xFFFF0000u; return v.f;
}

// A-frag: lane provides A[lane%16][(lane/16)*8 + j]; B-frag: B[(lane/16)*8+j][lane%16]
// C/D: col = lane&15, row = (lane>>4)*4 + reg   (measured m89)
template<int NT, int KS, int WTLD, int XSTR>
__device__ __forceinline__ void gemm_tiles(const u16* X, const u16* __restrict__ WT,
                                           int lr, int kg, int colbase, f32x4 (&acc)[NT][4]){
  #pragma unroll
  for (int ks = 0; ks < KS; ks++){
    bf16x8 a[4];
    #pragma unroll
    for (int m = 0; m < 4; m++)
      a[m] = *(const bf16x8*)(X + (size_t)(m*16 + lr)*XSTR + ks*32 + kg*8);
    #pragma unroll
    for (int n = 0; n < NT; n++){
      int col = colbase + n*16 + lr;
      bf16x8 b = *(const bf16x8*)(WT + (size_t)col*WTLD + ks*32 + kg*8);
      #pragma unroll
      for (int m = 0; m < 4; m++)
        acc[n][m] = __builtin_amdgcn_mfma_f32_16x16x32_bf16(a[m], b, acc[n][m], 0, 0, 0);
    }
  }
}

// transpose one 64x64 tile of W (rows x cols, f32) into WT (cols x rows, bf16), coalesced both ways
__device__ __forceinline__ void wconv_tile(const float* __restrict__ W, u16* __restrict__ WT,
                                           int rows, int cols, int tr, int tc, int t){
  __shared__ u16 T[64][66];
  int r0 = tr*64, c0 = tc*64;
  int r = t >> 2, cq = (t & 3) * 16;
  const float* src = W + (size_t)(r0 + r)*cols + c0 + cq;
  #pragma unroll
  for (int j = 0; j < 4; j++){
    float4 v = *(const float4*)(src + 4*j);
    us4 o; o.x = f2b(v.x); o.y = f2b(v.y); o.z = f2b(v.z); o.w = f2b(v.w);
    *(us4*)&T[r][cq + 4*j] = o;
  }
  __syncthreads();
  int c = t >> 2, rq = (t & 3) * 16;
  us8 o0, o1;
  #pragma unroll
  for (int j = 0; j < 8; j++){ o0[j] = T[rq + j][c]; o1[j] = T[rq + 8 + j][c]; }
  u16* dstp = WT + (size_t)(c0 + c)*rows + r0 + rq;
  *(us8*)dstp = o0;
  *(us8*)(dstp + 8) = o1;
}

// ============ pro: BN1 stats (nBn blocks) + weight transpose (32 blocks) ============
__global__ __launch_bounds__(256) void k_pro(
    const float* __restrict__ Wq, const float* __restrict__ Wk, const float* __restrict__ Wv,
    const float* __restrict__ Wo, const float* __restrict__ W1, const float* __restrict__ W2,
    u16* __restrict__ wtq, u16* __restrict__ wtk, u16* __restrict__ wtv,
    u16* __restrict__ wto, u16* __restrict__ wt1, u16* __restrict__ wt2,
    const float* __restrict__ h, float* __restrict__ sums,
    int nBn, int N){
  __shared__ float ls[256], ls2[256];
  int b = blockIdx.x, t = threadIdx.x;
  if (b < nBn){
    int col = t & 127, half = t >> 7;
    int r0 = b * 128; int r1 = r0 + 128; if (r1 > N) r1 = N;
    float s = 0.f, s2 = 0.f;
    for (int r = r0 + half; r < r1; r += 2){ float v = h[(size_t)r*NDIM + col]; s += v; s2 += v*v; }
    ls[t] = s; ls2[t] = s2; __syncthreads();
    if (t < 128){ atomicAdd(&sums[col], ls[t] + ls[t+128]); atomicAdd(&sums[128+col], ls2[t] + ls2[t+128]); }
    return;
  }
  b -= nBn;
  if (b < 16){
    const float* Ws[4] = {Wq, Wk, Wv, Wo};
    u16* Ts[4] = {wtq, wtk, wtv, wto};
    int wi = b >> 2, ti = b & 3;
    wconv_tile(Ws[wi], Ts[wi], 128, 128, ti >> 1, ti & 1, t);
  } else if (b < 24){
    int ti = b - 16;
    wconv_tile(W1, wt1, 128, 256, ti >> 2, ti & 3, t);
  } else {
    int ti = b - 24;
    wconv_tile(W2, wt2, 256, 128, ti & 3, ti >> 2, t);
  }
}

__global__ __launch_bounds__(128) void k_bn_final(const float* __restrict__ sums, const float* __restrict__ g,
                                                  const float* __restrict__ b, float* __restrict__ scsh, int N){
  int c = threadIdx.x;
  float mean = sums[c] / (float)N;
  float var  = sums[128+c] / (float)N - mean*mean;
  float rstd = rsqrtf(var + EPSV);
  float sc = g[c] * rstd;
  scsh[c] = sc; scsh[128+c] = b[c] - mean*sc;
}

// ============ merged: deg+rank atomics (even blocks) ∥ BN1-apply + QKV MFMA (odd blocks) ============
__global__ __launch_bounds__(256) void k_qkv_deg(
    const float* __restrict__ h, const float* __restrict__ scsh,
    const u16* __restrict__ WTq, const u16* __restrict__ WTk, const u16* __restrict__ WTv,
    u16* __restrict__ Q, u16* __restrict__ K, u16* __restrict__ V, int N,
    const int* __restrict__ dst, int* __restrict__ deg, int* __restrict__ rank,
    int E, int nDeg, int nQ){
  __shared__ u16 hn[64][136];
  __shared__ u16 ob[64][136];
  int t = threadIdx.x;
  int b = blockIdx.x;
  if (!(b & 1)){
    int di = b >> 1;
    if (di >= nDeg) return;
    int e = (di*256 + t) * 4;
    if (e + 3 < E){
      int4 d = *(const int4*)(dst + e);
      int4 r;
      r.x = atomicAdd(&deg[d.x], 1);
      r.y = atomicAdd(&deg[d.y], 1);
      r.z = atomicAdd(&deg[d.z], 1);
      r.w = atomicAdd(&deg[d.w], 1);
      *(int4*)(rank + e) = r;
    } else {
      for (int k = e; k < E; k++) rank[k] = atomicAdd(&deg[dst[k]], 1);
    }
    return;
  }
  int qi = b >> 1;
  if (qi >= nQ) return;
  int r0 = qi * 64;
  {
    int row = t >> 2, c0 = (t & 3) * 32; int rr = r0 + row;
    #pragma unroll
    for (int j = 0; j < 8; j++){
      int c = c0 + 4*j;
      float4 v = make_float4(0.f,0.f,0.f,0.f);
      if (rr < N) v = *(const float4*)(h + (size_t)rr*NDIM + c);
      us4 o;
      o.x = f2b(v.x * scsh[c]   + scsh[128+c]);
      o.y = f2b(v.y * scsh[c+1] + scsh[129+c]);
      o.z = f2b(v.z * scsh[c+2] + scsh[130+c]);
      o.w = f2b(v.w * scsh[c+3] + scsh[131+c]);
      *(us4*)&hn[row][c] = o;
    }
  }
  __syncthreads();
  int lane = t & 63, w = t >> 6;
  int lr = lane & 15, kg = lane >> 4;
  int srow = t >> 2, sc0 = (t & 3) * 32;   // staging-store mapping
  f32x4 zero = {0.f,0.f,0.f,0.f};

  #define DO_PASS(WT, OUT, FIRST) { \
    f32x4 acc[2][4]; \
    _Pragma("unroll") for (int n = 0; n < 2; n++) _Pragma("unroll") for (int m = 0; m < 4; m++) acc[n][m] = zero; \
    gemm_tiles<2,4,128,136>(&hn[0][0], WT, lr, kg, w*32, acc); \
    if (!FIRST) __syncthreads(); \
    _Pragma("unroll") for (int n = 0; n < 2; n++){ \
      int col = w*32 + n*16 + lr; \
      _Pragma("unroll") for (int m = 0; m < 4; m++) \
        _Pragma("unroll") for (int r = 0; r < 4; r++) \
          ob[m*16 + kg*4 + r][col] = f2b(acc[n][m][r]); \
    } \
    __syncthreads(); \
    if (r0 + srow < N){ \
      u16* dp = OUT + (size_t)(r0 + srow)*NDIM + sc0; \
      _Pragma("unroll") for (int j = 0; j < 4; j++) \
        *(us8*)(dp + j*8) = *(const us8*)&ob[srow][sc0 + j*8]; \
    } }
  DO_PASS(WTq, Q, true)
  DO_PASS(WTk, K, false)
  DO_PASS(WTv, V, false)
  #undef DO_PASS
}

// ============ scan kernels ============
__global__ __launch_bounds__(256) void k_scan_part(const int* __restrict__ deg, int* __restrict__ bsum, int N){
  __shared__ int ls[256];
  int t = threadIdx.x; int i = blockIdx.x*256 + t;
  ls[t] = (i < N) ? deg[i] : 0; __syncthreads();
  for (int off = 128; off > 0; off >>= 1){
    if (t < off) ls[t] += ls[t + off];
    __syncthreads();
  }
  if (t == 0) bsum[blockIdx.x] = ls[0];
}

__global__ __launch_bounds__(256) void k_scan_top(int* __restrict__ bsum, int nb, int* __restrict__ rowptr, int N, int E){
  __shared__ int ls[256];
  int t = threadIdx.x;
  int v = (t < nb) ? bsum[t] : 0; ls[t] = v; __syncthreads();
  for (int off = 1; off < 256; off <<= 1){
    int add = (t >= off) ? ls[t - off] : 0;
    __syncthreads();
    ls[t] += add;
    __syncthreads();
  }
  if (t < nb) bsum[t] = ls[t] - v;
  if (t == 0) rowptr[N] = E;
}

__global__ __launch_bounds__(256) void k_scan_down(const int* __restrict__ deg, const int* __restrict__ bsum,
                                                   int* __restrict__ rowptr, int N){
  __shared__ int ls[256];
  int t = threadIdx.x; int i = blockIdx.x*256 + t;
  int v = (i < N) ? deg[i] : 0; ls[t] = v; __syncthreads();
  for (int off = 1; off < 256; off <<= 1){
    int add = (t >= off) ? ls[t - off] : 0;
    __syncthreads();
    ls[t] += add;
    __syncthreads();
  }
  if (i < N) rowptr[i] = ls[t] - v + bsum[blockIdx.x];
}

// ============ scatter: plain stores, no atomics (rank precomputed) ============
__global__ __launch_bounds__(256) void k_scatter(const int* __restrict__ src, const int* __restrict__ dst,
                                                 const int* __restrict__ rank, const int* __restrict__ rowptr,
                                                 int* __restrict__ csr_src, int E){
  int e = (blockIdx.x*256 + threadIdx.x) * 4;
  if (e + 3 < E){
    int4 s4 = *(const int4*)(src + e);
    int4 d4 = *(const int4*)(dst + e);
    int4 r4 = *(const int4*)(rank + e);
    csr_src[rowptr[d4.x] + r4.x] = s4.x;
    csr_src[rowptr[d4.y] + r4.y] = s4.y;
    csr_src[rowptr[d4.z] + r4.z] = s4.z;
    csr_src[rowptr[d4.w] + r4.w] = s4.w;
  } else {
    for (int k = e; k < E; k++) csr_src[rowptr[dst[k]] + rank[k]] = src[k];
  }
}

// ============ fused edge phase: score + softmax + weighted V aggregation ============
__global__ __launch_bounds__(256) void k_sagg(const int* __restrict__ rowptr, const int* __restrict__ csr_src,
                                              const u16* __restrict__ Q, const u16* __restrict__ K,
                                              const u16* __restrict__ V, u16* __restrict__ wV, int N){
  int w = threadIdx.x >> 6, l = threadIdx.x & 63;
  int n = blockIdx.x*4 + w;
  if (n >= N) return;
  int j8 = l >> 3;     // edge slot (score phase)
  int hh = l & 7;      // head (score phase)
  int d0 = l * 2;      // dims (agg phase)

  float qf[16];
  {
    us8 q0 = *(const us8*)(Q + (size_t)n*NDIM + hh*16);
    us8 q1 = *(const us8*)(Q + (size_t)n*NDIM + hh*16 + 8);
    #pragma unroll
    for (int t = 0; t < 8; t++){ qf[t] = b2f(q0[t]) * 0.25f; qf[8+t] = b2f(q1[t]) * 0.25f; }
  }

  int e0 = rowptr[n], e1 = rowptr[n+1];
  float ssum_l = 0.f, a0 = 0.f, a1 = 0.f;

  for (int i = e0; i < e1; i += 8){
    int nedge = e1 - i; if (nedge > 8) nedge = 8;
    int myE = i + j8;
    int sidx = csr_src[(myE < e1) ? myE : i];

    unsigned vv[8];
    #pragma unroll
    for (int j = 0; j < 8; j++){
      if (j >= nedge) break;
      int sj = __shfl(sidx, j*8);
      vv[j] = *(const unsigned*)(V + (size_t)sj*NDIM + d0);
    }

    us8 k0 = *(const us8*)(K + (size_t)sidx*NDIM + hh*16);
    us8 k1 = *(const us8*)(K + (size_t)sidx*NDIM + hh*16 + 8);
    float p = 0.f;
    #pragma unroll
    for (int t = 0; t < 8; t++) p += qf[t]*b2f(k0[t]) + qf[8+t]*b2f(k1[t]);
    p = fminf(5.f, fmaxf(-5.f, p));
    float wgt = (myE < e1) ? __expf(p) : 0.f;
    ssum_l += wgt;

    #pragma unroll
    for (int j = 0; j < 8; j++){
      if (j >= nedge) break;
      float wj = __shfl(wgt, j*8 + j8);
      a0 += wj * blo(vv[j]);
      a1 += wj * bhi(vv[j]);
    }
  }

  ssum_l += __shfl_xor(ssum_l, 8);
  ssum_l += __shfl_xor(ssum_l, 16);
  ssum_l += __shfl_xor(ssum_l, 32);
  float ssum = __shfl(ssum_l, j8);
  float inv = (e1 > e0) ? 1.f/ssum : 0.f;
  unsigned pk = (unsigned)f2b(a0*inv) | (((unsigned)f2b(a1*inv)) << 16);
  *(unsigned*)(wV + (size_t)n*NDIM + d0) = pk;
}

// ============ O-projection + residual + BN2 stats (MFMA) ============
__global__ __launch_bounds__(256) void k_h2(const u16* __restrict__ wV, const u16* __restrict__ WTo,
                                            const float* __restrict__ bo, const float* __restrict__ h,
                                            float* __restrict__ h2, float* __restrict__ sums2, int N){
  __shared__ u16 tw[64][136];
  int t = threadIdx.x; int r0 = blockIdx.x * 64;
  {
    int row = t >> 2, c0 = (t & 3) * 32; int rr = r0 + row;
    #pragma unroll
    for (int j = 0; j < 4; j++){
      int c = c0 + 8*j;
      us8 v = {0,0,0,0,0,0,0,0};
      if (rr < N) v = *(const us8*)(wV + (size_t)rr*NDIM + c);
      *(us8*)&tw[row][c] = v;
    }
  }
  __syncthreads();
  int lane = t & 63, w = t >> 6;
  int lr = lane & 15, kg = lane >> 4;
  f32x4 zero = {0.f,0.f,0.f,0.f};
  f32x4 acc[2][4];
  #pragma unroll
  for (int n = 0; n < 2; n++)
    #pragma unroll
    for (int m = 0; m < 4; m++) acc[n][m] = zero;
  gemm_tiles<2,4,128,136>(&tw[0][0], WTo, lr, kg, w*32, acc);

  float sv[2] = {0.f, 0.f}, qv[2] = {0.f, 0.f};
  #pragma unroll
  for (int n = 0; n < 2; n++){
    int col = w*32 + n*16 + lr;
    float bb = bo[col];
    #pragma unroll
    for (int m = 0; m < 4; m++)
      #pragma unroll
      for (int r = 0; r < 4; r++){
        int rr = r0 + m*16 + kg*4 + r;
        if (rr < N){
          size_t o = (size_t)rr*NDIM + col;
          float v = acc[n][m][r] + bb + h[o];
          h2[o] = v;
          sv[n] += v; qv[n] += v*v;
        }
      }
  }
  #pragma unroll
  for (int n = 0; n < 2; n++){
    float s = sv[n], q = qv[n];
    s += __shfl_xor(s, 16); s += __shfl_xor(s, 32);
    q += __shfl_xor(q, 16); q += __shfl_xor(q, 32);
    if (kg == 0){
      int col = w*32 + n*16 + lr;
      atomicAdd(&sums2[col], s);
      atomicAdd(&sums2[128+col], q);
    }
  }
}

// ============ BN2-apply + FFN + residual (MFMA) ============
__global__ __launch_bounds__(256) void k_ffn(const float* __restrict__ h2, const float* __restrict__ scsh,
                                             const u16* __restrict__ WT1, const float* __restrict__ b1,
                                             const u16* __restrict__ WT2, const float* __restrict__ b2,
                                             float* __restrict__ out, int N){
  __shared__ u16 x[64][136];
  __shared__ u16 tt[64][264];
  int t = threadIdx.x; int r0 = blockIdx.x * 64;
  {
    int row = t >> 2, c0 = (t & 3) * 32; int rr = r0 + row;
    #pragma unroll
    for (int j = 0; j < 8; j++){
      int c = c0 + 4*j;
      float4 v = make_float4(0.f,0.f,0.f,0.f);
      if (rr < N) v = *(const float4*)(h2 + (size_t)rr*NDIM + c);
      us4 o;
      o.x = f2b(v.x * scsh[c]   + scsh[128+c]);
      o.y = f2b(v.y * scsh[c+1] + scsh[129+c]);
      o.z = f2b(v.z * scsh[c+2] + scsh[130+c]);
      o.w = f2b(v.w * scsh[c+3] + scsh[131+c]);
      *(us4*)&x[row][c] = o;
    }
  }
  __syncthreads();
  int lane = t & 63, w = t >> 6;
  int lr = lane & 15, kg = lane >> 4;
  f32x4 zero = {0.f,0.f,0.f,0.f};
  {
    f32x4 a1[4][4];
    #pragma unroll
    for (int n = 0; n < 4; n++)
      #pragma unroll
      for (int m = 0; m < 4; m++) a1[n][m] = zero;
    gemm_tiles<4,4,128,136>(&x[0][0], WT1, lr, kg, w*64, a1);
    #pragma unroll
    for (int n = 0; n < 4; n++){
      int col = w*64 + n*16 + lr;
      float bb = b1[col];
      #pragma unroll
      for (int m = 0; m < 4; m++)
        #pragma unroll
        for (int r = 0; r < 4; r++)
          tt[m*16 + kg*4 + r][col] = f2b(fmaxf(a1[n][m][r] + bb, 0.f));
    }
  }
  __syncthreads();
  {
    f32x4 a2[2][4];
    #pragma unroll
    for (int n = 0; n < 2; n++)
      #pragma unroll
      for (int m = 0; m < 4; m++) a2[n][m] = zero;
    gemm_tiles<2,8,256,264>(&tt[0][0], WT2, lr, kg, w*32, a2);
    #pragma unroll
    for (int n = 0; n < 2; n++){
      int col = w*32 + n*16 + lr;
      float bb = b2[col];
      #pragma unroll
      for (int m = 0; m < 4; m++)
        #pragma unroll
        for (int r = 0; r < 4; r++){
          int rr = r0 + m*16 + kg*4 + r;
          if (rr < N){
            size_t o = (size_t)rr*NDIM + col;
            out[o] = h2[o] + a2[n][m][r] + bb;
          }
        }
    }
  }
}

extern "C" void kernel_launch(void* const* d_in, const int* in_sizes, int n_in,
                              void* d_out, int out_size, void* d_ws, size_t ws_size,
                              hipStream_t stream) {
  const float* h    = (const float*)d_in[0];
  const int*   src  = (const int*)d_in[1];
  const int*   dst  = (const int*)d_in[2];
  const float* Wq   = (const float*)d_in[3];
  const float* Wk   = (const float*)d_in[4];
  const float* Wv   = (const float*)d_in[5];
  const float* Wo   = (const float*)d_in[6];
  const float* bo   = (const float*)d_in[7];
  const float* bn1g = (const float*)d_in[8];
  const float* bn1b = (const float*)d_in[9];
  const float* bn2g = (const float*)d_in[10];
  const float* bn2b = (const float*)d_in[11];
  const float* W1   = (const float*)d_in[12];
  const float* b1   = (const float*)d_in[13];
  const float* W2   = (const float*)d_in[14];
  const float* b2   = (const float*)d_in[15];
  float* out = (float*)d_out;

  int N = in_sizes[0] / NDIM;
  int E = in_sizes[1];
  size_t fN = (size_t)N * NDIM;

  u16* Q  = (u16*)d_ws;
  u16* K  = Q + fN;
  u16* V  = K + fN;
  u16* wV = Q;                                  // reuse: each wave reads Q[n] before writing wV[n]
  float* h2    = (float*)(V + fN);              // fN floats
  int* deg     = (int*)(h2 + fN);
  int* rowptr  = deg + N;                       // N+1
  int* bsum    = rowptr + (N + 1);              // 256
  int* rank    = bsum + 256;                    // E
  int* csr_src = rank + E;                      // E
  float* sums1 = (float*)(csr_src + E);
  float* sums2 = sums1 + 256;
  float* scsh1 = sums2 + 256;
  float* scsh2 = scsh1 + 256;
  u16* wtq = (u16*)(scsh2 + 256);
  u16* wtk = wtq + NDIM*NDIM;
  u16* wtv = wtk + NDIM*NDIM;
  u16* wto = wtv + NDIM*NDIM;
  u16* wt1 = wto + NDIM*NDIM;
  u16* wt2 = wt1 + NDIM*2*NDIM;

  hipMemsetAsync(deg, 0, (size_t)N * sizeof(int), stream);
  hipMemsetAsync(sums1, 0, 512 * sizeof(float), stream);

  int nb   = (N + 255) / 256;
  int nBn  = (N + 127) / 128;
  int nE4  = (E + 3) / 4;
  int nDeg = (nE4 + 255) / 256;
  int nQ   = (N + 63) / 64;
  int nMix = 2 * (nDeg > nQ ? nDeg : nQ);

  k_pro<<<nBn + 32, 256, 0, stream>>>(Wq, Wk, Wv, Wo, W1, W2,
                                      wtq, wtk, wtv, wto, wt1, wt2,
                                      h, sums1, nBn, N);
  k_bn_final<<<1, 128, 0, stream>>>(sums1, bn1g, bn1b, scsh1, N);

  k_qkv_deg<<<nMix, 256, 0, stream>>>(h, scsh1, wtq, wtk, wtv, Q, K, V, N,
                                      dst, deg, rank, E, nDeg, nQ);

  k_scan_part<<<nb, 256, 0, stream>>>(deg, bsum, N);
  k_scan_top<<<1, 256, 0, stream>>>(bsum, nb, rowptr, N, E);
  k_scan_down<<<nb, 256, 0, stream>>>(deg, bsum, rowptr, N);
  k_scatter<<<nDeg, 256, 0, stream>>>(src, dst, rank, rowptr, csr_src, E);

  k_sagg<<<(N + 3)/4, 256, 0, stream>>>(rowptr, csr_src, Q, K, V, wV, N);

  k_h2<<<(N + 63)/64, 256, 0, stream>>>(wV, wto, bo, h, h2, sums2, N);
  k_bn_final<<<1, 128, 0, stream>>>(sums2, bn2g, bn2b, scsh2, N);
  k_ffn<<<(N + 63)/64, 256, 0, stream>>>(h2, scsh2, wt1, b1, wt2, b2, out, N);
}

// Round 8
// 267.683 us; speedup vs baseline: 2.5005x; 1.0623x over previous
//
#include <hip/hip_runtime.h>
#include <hip/hip_bf16.h>

#define NDIM 128
#define NHEAD 8
#define EPSV 1e-5f

typedef unsigned short u16;
using bf16x8 = __attribute__((ext_vector_type(8))) short;
using f32x4  = __attribute__((ext_vector_type(4))) float;
using us8    = __attribute__((ext_vector_type(8))) unsigned short;
using us4    = __attribute__((ext_vector_type(4))) unsigned short;

__device__ __forceinline__ u16 f2b(float x){
  union { float f; unsigned u; } v; v.f = x;
  unsigned r = v.u + 0x7FFFu + ((v.u >> 16) & 1u);
  return (u16)(r >> 16);
}
__device__ __forceinline__ float b2f(u16 u){
  union { unsigned u; float f; } v; v.u = ((unsigned)u) << 16; return v.f;
}
__device__ __forceinline__ float blo(unsigned u){
  union { unsigned u; float f; } v; v.u = u << 16; return v.f;
}
__device__ __forceinline__ float bhi(unsigned u){
  union { unsigned u; float f; } v; v.u = u & 0xFFFF0000u; return v.f;
}

// A-frag: lane provides A[lane%16][(lane/16)*8 + j]; B-frag: B[(lane/16)*8+j][lane%16]
// C/D: col = lane&15, row = (lane>>4)*4 + reg   (measured m89)
template<int NT, int KS, int WTLD, int XSTR>
__device__ __forceinline__ void gemm_tiles(const u16* X, const u16* __restrict__ WT,
                                           int lr, int kg, int colbase, f32x4 (&acc)[NT][4]){
  #pragma unroll
  for (int ks = 0; ks < KS; ks++){
    bf16x8 a[4];
    #pragma unroll
    for (int m = 0; m < 4; m++)
      a[m] = *(const bf16x8*)(X + (size_t)(m*16 + lr)*XSTR + ks*32 + kg*8);
    #pragma unroll
    for (int n = 0; n < NT; n++){
      int col = colbase + n*16 + lr;
      bf16x8 b = *(const bf16x8*)(WT + (size_t)col*WTLD + ks*32 + kg*8);
      #pragma unroll
      for (int m = 0; m < 4; m++)
        acc[n][m] = __builtin_amdgcn_mfma_f32_16x16x32_bf16(a[m], b, acc[n][m], 0, 0, 0);
    }
  }
}

// transpose one 64x64 tile of W (rows x cols, f32) into WT (cols x rows, bf16), coalesced both ways
__device__ __forceinline__ void wconv_tile(const float* __restrict__ W, u16* __restrict__ WT,
                                           int rows, int cols, int tr, int tc, int t){
  __shared__ u16 T[64][66];
  int r0 = tr*64, c0 = tc*64;
  int r = t >> 2, cq = (t & 3) * 16;
  const float* src = W + (size_t)(r0 + r)*cols + c0 + cq;
  #pragma unroll
  for (int j = 0; j < 4; j++){
    float4 v = *(const float4*)(src + 4*j);
    us4 o; o.x = f2b(v.x); o.y = f2b(v.y); o.z = f2b(v.z); o.w = f2b(v.w);
    *(us4*)&T[r][cq + 4*j] = o;
  }
  __syncthreads();
  int c = t >> 2, rq = (t & 3) * 16;
  us8 o0, o1;
  #pragma unroll
  for (int j = 0; j < 8; j++){ o0[j] = T[rq + j][c]; o1[j] = T[rq + 8 + j][c]; }
  u16* dstp = WT + (size_t)(c0 + c)*rows + r0 + rq;
  *(us8*)dstp = o0;
  *(us8*)(dstp + 8) = o1;
}

// ============ pro: BN1 stats (nBn) + weight transpose (32) + coarse edge histogram (C chunks) ============
__global__ __launch_bounds__(256) void k_pro(
    const float* __restrict__ Wq, const float* __restrict__ Wk, const float* __restrict__ Wv,
    const float* __restrict__ Wo, const float* __restrict__ W1, const float* __restrict__ W2,
    u16* __restrict__ wtq, u16* __restrict__ wtk, u16* __restrict__ wtv,
    u16* __restrict__ wto, u16* __restrict__ wt1, u16* __restrict__ wt2,
    const float* __restrict__ h, float* __restrict__ sums,
    const int* __restrict__ dst, int* __restrict__ cntT,
    int nBn, int N, int E, int B, int C){
  __shared__ float ls[256], ls2[256];
  __shared__ int hist[256];
  int b = blockIdx.x, t = threadIdx.x;
  if (b < nBn){
    int col = t & 127, half = t >> 7;
    int r0 = b * 128; int r1 = r0 + 128; if (r1 > N) r1 = N;
    float s = 0.f, s2 = 0.f;
    for (int r = r0 + half; r < r1; r += 2){ float v = h[(size_t)r*NDIM + col]; s += v; s2 += v*v; }
    ls[t] = s; ls2[t] = s2; __syncthreads();
    if (t < 128){ atomicAdd(&sums[col], ls[t] + ls[t+128]); atomicAdd(&sums[128+col], ls2[t] + ls2[t+128]); }
    return;
  }
  b -= nBn;
  if (b < 16){
    const float* Ws[4] = {Wq, Wk, Wv, Wo};
    u16* Ts[4] = {wtq, wtk, wtv, wto};
    int wi = b >> 2, ti = b & 3;
    wconv_tile(Ws[wi], Ts[wi], 128, 128, ti >> 1, ti & 1, t);
    return;
  }
  if (b < 24){
    int ti = b - 16;
    wconv_tile(W1, wt1, 128, 256, ti >> 2, ti & 3, t);
    return;
  }
  if (b < 32){
    int ti = b - 24;
    wconv_tile(W2, wt2, 256, 128, ti & 3, ti >> 2, t);
    return;
  }
  int ci = b - 32;           // coarse histogram chunk
  if (ci >= C) return;
  hist[t] = 0; __syncthreads();
  int e0 = ci * 4096;
  #pragma unroll
  for (int j = 0; j < 16; j++){
    int e = e0 + t + j*256;
    if (e < E) atomicAdd(&hist[dst[e] >> 8], 1);
  }
  __syncthreads();
  if (t < B) cntT[t*C + ci] = hist[t];
}

__global__ __launch_bounds__(128) void k_bn_final(const float* __restrict__ sums, const float* __restrict__ g,
                                                  const float* __restrict__ b, float* __restrict__ scsh, int N){
  int c = threadIdx.x;
  float mean = sums[c] / (float)N;
  float var  = sums[128+c] / (float)N - mean*mean;
  float rstd = rsqrtf(var + EPSV);
  float sc = g[c] * rstd;
  scsh[c] = sc; scsh[128+c] = b[c] - mean*sc;
}

// ============ generic scan kernels (exclusive scan of in[0..len)) ============
__global__ __launch_bounds__(256) void k_scan_part(const int* __restrict__ in, int* __restrict__ bsum, int len){
  __shared__ int ls[256];
  int t = threadIdx.x; int i = blockIdx.x*256 + t;
  ls[t] = (i < len) ? in[i] : 0; __syncthreads();
  for (int off = 128; off > 0; off >>= 1){
    if (t < off) ls[t] += ls[t + off];
    __syncthreads();
  }
  if (t == 0) bsum[blockIdx.x] = ls[0];
}

__global__ __launch_bounds__(256) void k_scan_top(int* __restrict__ bsum, int nb, int* __restrict__ rowptr, int N, int E){
  __shared__ int ls[256];
  int t = threadIdx.x;
  int v = (t < nb) ? bsum[t] : 0; ls[t] = v; __syncthreads();
  for (int off = 1; off < 256; off <<= 1){
    int add = (t >= off) ? ls[t - off] : 0;
    __syncthreads();
    ls[t] += add;
    __syncthreads();
  }
  if (t < nb) bsum[t] = ls[t] - v;
  if (t == 0) rowptr[N] = E;
}

__global__ __launch_bounds__(256) void k_scan_down(const int* __restrict__ in, const int* __restrict__ bsum,
                                                   int* __restrict__ outp, int len){
  __shared__ int ls[256];
  int t = threadIdx.x; int i = blockIdx.x*256 + t;
  int v = (i < len) ? in[i] : 0; ls[t] = v; __syncthreads();
  for (int off = 1; off < 256; off <<= 1){
    int add = (t >= off) ? ls[t - off] : 0;
    __syncthreads();
    ls[t] += add;
    __syncthreads();
  }
  if (i < len) outp[i] = ls[t] - v + bsum[blockIdx.x];
}

// ============ bucket pass: write (dst,src) into coarse-bucket slots (LDS cursors only) ============
__global__ __launch_bounds__(256) void k_bucket(const int* __restrict__ src, const int* __restrict__ dst,
                                                const int* __restrict__ scn, int2* __restrict__ ebuf,
                                                int B, int C, int E){
  __shared__ int off[256];
  int ci = blockIdx.x, t = threadIdx.x;
  off[t] = (t < B) ? scn[t*C + ci] : 0;
  __syncthreads();
  int e0 = ci * 4096;
  #pragma unroll
  for (int j = 0; j < 16; j++){
    int e = e0 + t + j*256;
    if (e < E){
      int d = dst[e], s = src[e];
      int slot = atomicAdd(&off[d >> 8], 1);
      ebuf[slot] = make_int2(d, s);
    }
  }
}

// ============ fine sort within bucket: rowptr + csr_src (LDS atomics only) ============
__global__ __launch_bounds__(256) void k_finesort(const int2* __restrict__ ebuf, const int* __restrict__ scn,
                                                  int* __restrict__ rowptr, int* __restrict__ csr_src,
                                                  int B, int C, int N, int E){
  __shared__ int ls[256], cur[256];
  int b = blockIdx.x, t = threadIdx.x;
  int base = scn[b*C];
  int end  = (b == B-1) ? E : scn[(b+1)*C];
  int lo = b << 8;
  cur[t] = 0; __syncthreads();
  for (int e = base + t; e < end; e += 256) atomicAdd(&cur[ebuf[e].x - lo], 1);
  __syncthreads();
  int v = cur[t]; ls[t] = v; __syncthreads();
  for (int off = 1; off < 256; off <<= 1){
    int add = (t >= off) ? ls[t - off] : 0;
    __syncthreads();
    ls[t] += add;
    __syncthreads();
  }
  int excl = ls[t] - v;
  __syncthreads();
  cur[t] = excl;
  if (lo + t < N) rowptr[lo + t] = base + excl;
  __syncthreads();
  for (int e = base + t; e < end; e += 256){
    int2 p = ebuf[e];
    int slot = base + atomicAdd(&cur[p.x - lo], 1);
    csr_src[slot] = p.y;
  }
}

// ============ BN1-apply + QKV projection (MFMA, LDS-staged coalesced output) ============
__global__ __launch_bounds__(256) void k_qkv(const float* __restrict__ h, const float* __restrict__ scsh,
                                             const u16* __restrict__ WTq, const u16* __restrict__ WTk, const u16* __restrict__ WTv,
                                             u16* __restrict__ Q, u16* __restrict__ K, u16* __restrict__ V, int N){
  __shared__ u16 hn[64][136];
  __shared__ u16 ob[64][136];
  int t = threadIdx.x; int r0 = blockIdx.x * 64;
  {
    int row = t >> 2, c0 = (t & 3) * 32; int rr = r0 + row;
    #pragma unroll
    for (int j = 0; j < 8; j++){
      int c = c0 + 4*j;
      float4 v = make_float4(0.f,0.f,0.f,0.f);
      if (rr < N) v = *(const float4*)(h + (size_t)rr*NDIM + c);
      us4 o;
      o.x = f2b(v.x * scsh[c]   + scsh[128+c]);
      o.y = f2b(v.y * scsh[c+1] + scsh[129+c]);
      o.z = f2b(v.z * scsh[c+2] + scsh[130+c]);
      o.w = f2b(v.w * scsh[c+3] + scsh[131+c]);
      *(us4*)&hn[row][c] = o;
    }
  }
  __syncthreads();
  int lane = t & 63, w = t >> 6;
  int lr = lane & 15, kg = lane >> 4;
  int srow = t >> 2, sc0 = (t & 3) * 32;   // staging-store mapping
  f32x4 zero = {0.f,0.f,0.f,0.f};

  #define DO_PASS(WT, OUT, FIRST) { \
    f32x4 acc[2][4]; \
    _Pragma("unroll") for (int n = 0; n < 2; n++) _Pragma("unroll") for (int m = 0; m < 4; m++) acc[n][m] = zero; \
    gemm_tiles<2,4,128,136>(&hn[0][0], WT, lr, kg, w*32, acc); \
    if (!FIRST) __syncthreads(); \
    _Pragma("unroll") for (int n = 0; n < 2; n++){ \
      int col = w*32 + n*16 + lr; \
      _Pragma("unroll") for (int m = 0; m < 4; m++) \
        _Pragma("unroll") for (int r = 0; r < 4; r++) \
          ob[m*16 + kg*4 + r][col] = f2b(acc[n][m][r]); \
    } \
    __syncthreads(); \
    if (r0 + srow < N){ \
      u16* dp = OUT + (size_t)(r0 + srow)*NDIM + sc0; \
      _Pragma("unroll") for (int j = 0; j < 4; j++) \
        *(us8*)(dp + j*8) = *(const us8*)&ob[srow][sc0 + j*8]; \
    } }
  DO_PASS(WTq, Q, true)
  DO_PASS(WTk, K, false)
  DO_PASS(WTv, V, false)
  #undef DO_PASS
}

// ============ fused edge phase: score + softmax + weighted V aggregation ============
__global__ __launch_bounds__(256) void k_sagg(const int* __restrict__ rowptr, const int* __restrict__ csr_src,
                                              const u16* __restrict__ Q, const u16* __restrict__ K,
                                              const u16* __restrict__ V, u16* __restrict__ wV, int N){
  int w = threadIdx.x >> 6, l = threadIdx.x & 63;
  int n = blockIdx.x*4 + w;
  if (n >= N) return;
  int j8 = l >> 3;     // edge slot (score phase)
  int hh = l & 7;      // head (score phase)
  int d0 = l * 2;      // dims (agg phase)

  float qf[16];
  {
    us8 q0 = *(const us8*)(Q + (size_t)n*NDIM + hh*16);
    us8 q1 = *(const us8*)(Q + (size_t)n*NDIM + hh*16 + 8);
    #pragma unroll
    for (int t = 0; t < 8; t++){ qf[t] = b2f(q0[t]) * 0.25f; qf[8+t] = b2f(q1[t]) * 0.25f; }
  }

  int e0 = rowptr[n], e1 = rowptr[n+1];
  float ssum_l = 0.f, a0 = 0.f, a1 = 0.f;

  for (int i = e0; i < e1; i += 8){
    int nedge = e1 - i; if (nedge > 8) nedge = 8;
    int myE = i + j8;
    int sidx = csr_src[(myE < e1) ? myE : i];

    unsigned vv[8];
    #pragma unroll
    for (int j = 0; j < 8; j++){
      if (j >= nedge) break;
      int sj = __shfl(sidx, j*8);
      vv[j] = *(const unsigned*)(V + (size_t)sj*NDIM + d0);
    }

    us8 k0 = *(const us8*)(K + (size_t)sidx*NDIM + hh*16);
    us8 k1 = *(const us8*)(K + (size_t)sidx*NDIM + hh*16 + 8);
    float p = 0.f;
    #pragma unroll
    for (int t = 0; t < 8; t++) p += qf[t]*b2f(k0[t]) + qf[8+t]*b2f(k1[t]);
    p = fminf(5.f, fmaxf(-5.f, p));
    float wgt = (myE < e1) ? __expf(p) : 0.f;
    ssum_l += wgt;

    #pragma unroll
    for (int j = 0; j < 8; j++){
      if (j >= nedge) break;
      float wj = __shfl(wgt, j*8 + j8);
      a0 += wj * blo(vv[j]);
      a1 += wj * bhi(vv[j]);
    }
  }

  ssum_l += __shfl_xor(ssum_l, 8);
  ssum_l += __shfl_xor(ssum_l, 16);
  ssum_l += __shfl_xor(ssum_l, 32);
  float ssum = __shfl(ssum_l, j8);
  float inv = (e1 > e0) ? 1.f/ssum : 0.f;
  unsigned pk = (unsigned)f2b(a0*inv) | (((unsigned)f2b(a1*inv)) << 16);
  *(unsigned*)(wV + (size_t)n*NDIM + d0) = pk;
}

// ============ O-projection + residual + BN2 stats (MFMA) ============
__global__ __launch_bounds__(256) void k_h2(const u16* __restrict__ wV, const u16* __restrict__ WTo,
                                            const float* __restrict__ bo, const float* __restrict__ h,
                                            float* __restrict__ h2, float* __restrict__ sums2, int N){
  __shared__ u16 tw[64][136];
  int t = threadIdx.x; int r0 = blockIdx.x * 64;
  {
    int row = t >> 2, c0 = (t & 3) * 32; int rr = r0 + row;
    #pragma unroll
    for (int j = 0; j < 4; j++){
      int c = c0 + 8*j;
      us8 v = {0,0,0,0,0,0,0,0};
      if (rr < N) v = *(const us8*)(wV + (size_t)rr*NDIM + c);
      *(us8*)&tw[row][c] = v;
    }
  }
  __syncthreads();
  int lane = t & 63, w = t >> 6;
  int lr = lane & 15, kg = lane >> 4;
  f32x4 zero = {0.f,0.f,0.f,0.f};
  f32x4 acc[2][4];
  #pragma unroll
  for (int n = 0; n < 2; n++)
    #pragma unroll
    for (int m = 0; m < 4; m++) acc[n][m] = zero;
  gemm_tiles<2,4,128,136>(&tw[0][0], WTo, lr, kg, w*32, acc);

  float sv[2] = {0.f, 0.f}, qv[2] = {0.f, 0.f};
  #pragma unroll
  for (int n = 0; n < 2; n++){
    int col = w*32 + n*16 + lr;
    float bb = bo[col];
    #pragma unroll
    for (int m = 0; m < 4; m++)
      #pragma unroll
      for (int r = 0; r < 4; r++){
        int rr = r0 + m*16 + kg*4 + r;
        if (rr < N){
          size_t o = (size_t)rr*NDIM + col;
          float v = acc[n][m][r] + bb + h[o];
          h2[o] = v;
          sv[n] += v; qv[n] += v*v;
        }
      }
  }
  #pragma unroll
  for (int n = 0; n < 2; n++){
    float s = sv[n], q = qv[n];
    s += __shfl_xor(s, 16); s += __shfl_xor(s, 32);
    q += __shfl_xor(q, 16); q += __shfl_xor(q, 32);
    if (kg == 0){
      int col = w*32 + n*16 + lr;
      atomicAdd(&sums2[col], s);
      atomicAdd(&sums2[128+col], q);
    }
  }
}

// ============ BN2-apply + FFN + residual (MFMA) ============
__global__ __launch_bounds__(256) void k_ffn(const float* __restrict__ h2, const float* __restrict__ scsh,
                                             const u16* __restrict__ WT1, const float* __restrict__ b1,
                                             const u16* __restrict__ WT2, const float* __restrict__ b2,
                                             float* __restrict__ out, int N){
  __shared__ u16 x[64][136];
  __shared__ u16 tt[64][264];
  int t = threadIdx.x; int r0 = blockIdx.x * 64;
  {
    int row = t >> 2, c0 = (t & 3) * 32; int rr = r0 + row;
    #pragma unroll
    for (int j = 0; j < 8; j++){
      int c = c0 + 4*j;
      float4 v = make_float4(0.f,0.f,0.f,0.f);
      if (rr < N) v = *(const float4*)(h2 + (size_t)rr*NDIM + c);
      us4 o;
      o.x = f2b(v.x * scsh[c]   + scsh[128+c]);
      o.y = f2b(v.y * scsh[c+1] + scsh[129+c]);
      o.z = f2b(v.z * scsh[c+2] + scsh[130+c]);
      o.w = f2b(v.w * scsh[c+3] + scsh[131+c]);
      *(us4*)&x[row][c] = o;
    }
  }
  __syncthreads();
  int lane = t & 63, w = t >> 6;
  int lr = lane & 15, kg = lane >> 4;
  f32x4 zero = {0.f,0.f,0.f,0.f};
  {
    f32x4 a1[4][4];
    #pragma unroll
    for (int n = 0; n < 4; n++)
      #pragma unroll
      for (int m = 0; m < 4; m++) a1[n][m] = zero;
    gemm_tiles<4,4,128,136>(&x[0][0], WT1, lr, kg, w*64, a1);
    #pragma unroll
    for (int n = 0; n < 4; n++){
      int col = w*64 + n*16 + lr;
      float bb = b1[col];
      #pragma unroll
      for (int m = 0; m < 4; m++)
        #pragma unroll
        for (int r = 0; r < 4; r++)
          tt[m*16 + kg*4 + r][col] = f2b(fmaxf(a1[n][m][r] + bb, 0.f));
    }
  }
  __syncthreads();
  {
    f32x4 a2[2][4];
    #pragma unroll
    for (int n = 0; n < 2; n++)
      #pragma unroll
      for (int m = 0; m < 4; m++) a2[n][m] = zero;
    gemm_tiles<2,8,256,264>(&tt[0][0], WT2, lr, kg, w*32, a2);
    #pragma unroll
    for (int n = 0; n < 2; n++){
      int col = w*32 + n*16 + lr;
      float bb = b2[col];
      #pragma unroll
      for (int m = 0; m < 4; m++)
        #pragma unroll
        for (int r = 0; r < 4; r++){
          int rr = r0 + m*16 + kg*4 + r;
          if (rr < N){
            size_t o = (size_t)rr*NDIM + col;
            out[o] = h2[o] + a2[n][m][r] + bb;
          }
        }
    }
  }
}

extern "C" void kernel_launch(void* const* d_in, const int* in_sizes, int n_in,
                              void* d_out, int out_size, void* d_ws, size_t ws_size,
                              hipStream_t stream) {
  const float* h    = (const float*)d_in[0];
  const int*   src  = (const int*)d_in[1];
  const int*   dst  = (const int*)d_in[2];
  const float* Wq   = (const float*)d_in[3];
  const float* Wk   = (const float*)d_in[4];
  const float* Wv   = (const float*)d_in[5];
  const float* Wo   = (const float*)d_in[6];
  const float* bo   = (const float*)d_in[7];
  const float* bn1g = (const float*)d_in[8];
  const float* bn1b = (const float*)d_in[9];
  const float* bn2g = (const float*)d_in[10];
  const float* bn2b = (const float*)d_in[11];
  const float* W1   = (const float*)d_in[12];
  const float* b1   = (const float*)d_in[13];
  const float* W2   = (const float*)d_in[14];
  const float* b2   = (const float*)d_in[15];
  float* out = (float*)d_out;

  int N = in_sizes[0] / NDIM;
  int E = in_sizes[1];
  size_t fN = (size_t)N * NDIM;

  int B   = (N + 255) >> 8;       // coarse buckets (256 nodes each), must be <= 256
  int C   = (E + 4095) >> 12;     // edge chunks (4096 edges each)
  int NB2 = B * C;
  int nb2 = (NB2 + 255) / 256;    // must be <= 256

  u16* Q  = (u16*)d_ws;
  u16* K  = Q + fN;
  u16* V  = K + fN;
  u16* wV = Q;                                  // reuse: each wave reads Q[n] before writing wV[n]
  float* h2   = (float*)(V + fN);               // fN floats
  int2* ebuf  = (int2*)(h2 + fN);               // E int2 (8B aligned here)
  int* rowptr = (int*)(ebuf + E);               // N+1
  int* bsum   = rowptr + (N + 1);               // 256
  int* cntT   = bsum + 256;                     // NB2
  int* scn    = cntT + NB2;                     // NB2
  int* csr_src= scn + NB2;                      // E
  float* sums1 = (float*)(csr_src + E);
  float* sums2 = sums1 + 256;
  float* scsh1 = sums2 + 256;
  float* scsh2 = scsh1 + 256;
  u16* wtq = (u16*)(scsh2 + 256);
  u16* wtk = wtq + NDIM*NDIM;
  u16* wtv = wtk + NDIM*NDIM;
  u16* wto = wtv + NDIM*NDIM;
  u16* wt1 = wto + NDIM*NDIM;
  u16* wt2 = wt1 + NDIM*2*NDIM;

  hipMemsetAsync(sums1, 0, 512 * sizeof(float), stream);

  int nBn = (N + 127) / 128;
  int nQ  = (N + 63) / 64;

  k_pro<<<nBn + 32 + C, 256, 0, stream>>>(Wq, Wk, Wv, Wo, W1, W2,
                                          wtq, wtk, wtv, wto, wt1, wt2,
                                          h, sums1, dst, cntT, nBn, N, E, B, C);
  k_bn_final<<<1, 128, 0, stream>>>(sums1, bn1g, bn1b, scsh1, N);

  k_scan_part<<<nb2, 256, 0, stream>>>(cntT, bsum, NB2);
  k_scan_top<<<1, 256, 0, stream>>>(bsum, nb2, rowptr, N, E);
  k_scan_down<<<nb2, 256, 0, stream>>>(cntT, bsum, scn, NB2);
  k_bucket<<<C, 256, 0, stream>>>(src, dst, scn, ebuf, B, C, E);
  k_finesort<<<B, 256, 0, stream>>>(ebuf, scn, rowptr, csr_src, B, C, N, E);

  k_qkv<<<nQ, 256, 0, stream>>>(h, scsh1, wtq, wtk, wtv, Q, K, V, N);

  k_sagg<<<(N + 3)/4, 256, 0, stream>>>(rowptr, csr_src, Q, K, V, wV, N);

  k_h2<<<(N + 63)/64, 256, 0, stream>>>(wV, wto, bo, h, h2, sums2, N);
  k_bn_final<<<1, 128, 0, stream>>>(sums2, bn2g, bn2b, scsh2, N);
  k_ffn<<<(N + 63)/64, 256, 0, stream>>>(h2, scsh2, wt1, b1, wt2, b2, out, N);
}

// Round 9
// 254.253 us; speedup vs baseline: 2.6326x; 1.0528x over previous
//
#include <hip/hip_runtime.h>
#include <hip/hip_bf16.h>

#define NDIM 128
#define NHEAD 8
#define EPSV 1e-5f

typedef unsigned short u16;
using bf16x8 = __attribute__((ext_vector_type(8))) short;
using f32x4  = __attribute__((ext_vector_type(4))) float;
using us8    = __attribute__((ext_vector_type(8))) unsigned short;
using us4    = __attribute__((ext_vector_type(4))) unsigned short;

__device__ __forceinline__ u16 f2b(float x){
  union { float f; unsigned u; } v; v.f = x;
  unsigned r = v.u + 0x7FFFu + ((v.u >> 16) & 1u);
  return (u16)(r >> 16);
}
__device__ __forceinline__ float b2f(u16 u){
  union { unsigned u; float f; } v; v.u = ((unsigned)u) << 16; return v.f;
}
__device__ __forceinline__ float blo(unsigned u){
  union { unsigned u; float f; } v; v.u = u << 16; return v.f;
}
__device__ __forceinline__ float bhi(unsigned u){
  union { unsigned u; float f; } v; v.u = u & 0xFFFF0000u; return v.f;
}

// A-frag: lane provides A[lane%16][(lane/16)*8 + j]; B-frag: B[(lane/16)*8+j][lane%16]
// C/D: col = lane&15, row = (lane>>4)*4 + reg   (measured m89)
template<int NT, int KS, int WTLD, int XSTR>
__device__ __forceinline__ void gemm_tiles(const u16* X, const u16* __restrict__ WT,
                                           int lr, int kg, int colbase, f32x4 (&acc)[NT][4]){
  #pragma unroll
  for (int ks = 0; ks < KS; ks++){
    bf16x8 a[4];
    #pragma unroll
    for (int m = 0; m < 4; m++)
      a[m] = *(const bf16x8*)(X + (size_t)(m*16 + lr)*XSTR + ks*32 + kg*8);
    #pragma unroll
    for (int n = 0; n < NT; n++){
      int col = colbase + n*16 + lr;
      bf16x8 b = *(const bf16x8*)(WT + (size_t)col*WTLD + ks*32 + kg*8);
      #pragma unroll
      for (int m = 0; m < 4; m++)
        acc[n][m] = __builtin_amdgcn_mfma_f32_16x16x32_bf16(a[m], b, acc[n][m], 0, 0, 0);
    }
  }
}

// transpose one 64x64 tile of W (rows x cols, f32) into WT (cols x rows, bf16), coalesced both ways
__device__ __forceinline__ void wconv_tile(const float* __restrict__ W, u16* __restrict__ WT,
                                           int rows, int cols, int tr, int tc, int t){
  __shared__ u16 T[64][66];
  int r0 = tr*64, c0 = tc*64;
  int r = t >> 2, cq = (t & 3) * 16;
  const float* src = W + (size_t)(r0 + r)*cols + c0 + cq;
  #pragma unroll
  for (int j = 0; j < 4; j++){
    float4 v = *(const float4*)(src + 4*j);
    us4 o; o.x = f2b(v.x); o.y = f2b(v.y); o.z = f2b(v.z); o.w = f2b(v.w);
    *(us4*)&T[r][cq + 4*j] = o;
  }
  __syncthreads();
  int c = t >> 2, rq = (t & 3) * 16;
  us8 o0, o1;
  #pragma unroll
  for (int j = 0; j < 8; j++){ o0[j] = T[rq + j][c]; o1[j] = T[rq + 8 + j][c]; }
  u16* dstp = WT + (size_t)(c0 + c)*rows + r0 + rq;
  *(us8*)dstp = o0;
  *(us8*)(dstp + 8) = o1;
}

// ============ pro: BN1 stats (nBn) + weight transpose (32) + coarse edge histogram (C chunks) ============
__global__ __launch_bounds__(256) void k_pro(
    const float* __restrict__ Wq, const float* __restrict__ Wk, const float* __restrict__ Wv,
    const float* __restrict__ Wo, const float* __restrict__ W1, const float* __restrict__ W2,
    u16* __restrict__ wtq, u16* __restrict__ wtk, u16* __restrict__ wtv,
    u16* __restrict__ wto, u16* __restrict__ wt1, u16* __restrict__ wt2,
    const float* __restrict__ h, float* __restrict__ sums,
    const int* __restrict__ dst, int* __restrict__ cntT,
    int nBn, int N, int E, int B, int C){
  __shared__ float ls[256], ls2[256];
  __shared__ int hist[256];
  int b = blockIdx.x, t = threadIdx.x;
  if (b < nBn){
    int col = t & 127, half = t >> 7;
    int r0 = b * 128; int r1 = r0 + 128; if (r1 > N) r1 = N;
    float s = 0.f, s2 = 0.f;
    for (int r = r0 + half; r < r1; r += 2){ float v = h[(size_t)r*NDIM + col]; s += v; s2 += v*v; }
    ls[t] = s; ls2[t] = s2; __syncthreads();
    if (t < 128){ atomicAdd(&sums[col], ls[t] + ls[t+128]); atomicAdd(&sums[128+col], ls2[t] + ls2[t+128]); }
    return;
  }
  b -= nBn;
  if (b < 16){
    const float* Ws[4] = {Wq, Wk, Wv, Wo};
    u16* Ts[4] = {wtq, wtk, wtv, wto};
    int wi = b >> 2, ti = b & 3;
    wconv_tile(Ws[wi], Ts[wi], 128, 128, ti >> 1, ti & 1, t);
    return;
  }
  if (b < 24){
    int ti = b - 16;
    wconv_tile(W1, wt1, 128, 256, ti >> 2, ti & 3, t);
    return;
  }
  if (b < 32){
    int ti = b - 24;
    wconv_tile(W2, wt2, 256, 128, ti & 3, ti >> 2, t);
    return;
  }
  int ci = b - 32;           // coarse histogram chunk
  if (ci >= C) return;
  hist[t] = 0; __syncthreads();
  int e0 = ci * 4096;
  #pragma unroll
  for (int j = 0; j < 16; j++){
    int e = e0 + t + j*256;
    if (e < E) atomicAdd(&hist[dst[e] >> 8], 1);
  }
  __syncthreads();
  if (t < B) cntT[t*C + ci] = hist[t];
}

__global__ __launch_bounds__(128) void k_bn_final(const float* __restrict__ sums, const float* __restrict__ g,
                                                  const float* __restrict__ b, float* __restrict__ scsh, int N){
  int c = threadIdx.x;
  float mean = sums[c] / (float)N;
  float var  = sums[128+c] / (float)N - mean*mean;
  float rstd = rsqrtf(var + EPSV);
  float sc = g[c] * rstd;
  scsh[c] = sc; scsh[128+c] = b[c] - mean*sc;
}

// ============ generic scan kernels (exclusive scan of in[0..len)) ============
__global__ __launch_bounds__(256) void k_scan_part(const int* __restrict__ in, int* __restrict__ bsum, int len){
  __shared__ int ls[256];
  int t = threadIdx.x; int i = blockIdx.x*256 + t;
  ls[t] = (i < len) ? in[i] : 0; __syncthreads();
  for (int off = 128; off > 0; off >>= 1){
    if (t < off) ls[t] += ls[t + off];
    __syncthreads();
  }
  if (t == 0) bsum[blockIdx.x] = ls[0];
}

__global__ __launch_bounds__(256) void k_scan_top(int* __restrict__ bsum, int nb, int* __restrict__ rowptr, int N, int E){
  __shared__ int ls[256];
  int t = threadIdx.x;
  int v = (t < nb) ? bsum[t] : 0; ls[t] = v; __syncthreads();
  for (int off = 1; off < 256; off <<= 1){
    int add = (t >= off) ? ls[t - off] : 0;
    __syncthreads();
    ls[t] += add;
    __syncthreads();
  }
  if (t < nb) bsum[t] = ls[t] - v;
  if (t == 0) rowptr[N] = E;
}

__global__ __launch_bounds__(256) void k_scan_down(const int* __restrict__ in, const int* __restrict__ bsum,
                                                   int* __restrict__ outp, int len){
  __shared__ int ls[256];
  int t = threadIdx.x; int i = blockIdx.x*256 + t;
  int v = (i < len) ? in[i] : 0; ls[t] = v; __syncthreads();
  for (int off = 1; off < 256; off <<= 1){
    int add = (t >= off) ? ls[t - off] : 0;
    __syncthreads();
    ls[t] += add;
    __syncthreads();
  }
  if (i < len) outp[i] = ls[t] - v + bsum[blockIdx.x];
}

// ============ fine sort within bucket: rowptr + csr_src (LDS atomics only) ============
__global__ __launch_bounds__(256) void k_finesort(const int2* __restrict__ ebuf, const int* __restrict__ scn,
                                                  int* __restrict__ rowptr, int* __restrict__ csr_src,
                                                  int B, int C, int N, int E){
  __shared__ int ls[256], cur[256];
  int b = blockIdx.x, t = threadIdx.x;
  int base = scn[b*C];
  int end  = (b == B-1) ? E : scn[(b+1)*C];
  int lo = b << 8;
  cur[t] = 0; __syncthreads();
  for (int e = base + t; e < end; e += 256) atomicAdd(&cur[ebuf[e].x - lo], 1);
  __syncthreads();
  int v = cur[t]; ls[t] = v; __syncthreads();
  for (int off = 1; off < 256; off <<= 1){
    int add = (t >= off) ? ls[t - off] : 0;
    __syncthreads();
    ls[t] += add;
    __syncthreads();
  }
  int excl = ls[t] - v;
  __syncthreads();
  cur[t] = excl;
  if (lo + t < N) rowptr[lo + t] = base + excl;
  __syncthreads();
  for (int e = base + t; e < end; e += 256){
    int2 p = ebuf[e];
    int slot = base + atomicAdd(&cur[p.x - lo], 1);
    csr_src[slot] = p.y;
  }
}

// ============ merged: bucket pass (first C blocks) + BN1-apply + QKV projection (MFMA) ============
__global__ __launch_bounds__(256) void k_qkv_bucket(
    const float* __restrict__ h, const float* __restrict__ scsh,
    const u16* __restrict__ WTq, const u16* __restrict__ WTk, const u16* __restrict__ WTv,
    u16* __restrict__ Q, u16* __restrict__ K, u16* __restrict__ V, int N,
    const int* __restrict__ src, const int* __restrict__ dst,
    const int* __restrict__ scn, int2* __restrict__ ebuf, int B, int C, int E){
  __shared__ u16 hn[64][136];
  __shared__ u16 ob[64][136];
  __shared__ int off[256];
  int b = blockIdx.x, t = threadIdx.x;
  if (b < C){
    off[t] = (t < B) ? scn[t*C + b] : 0;
    __syncthreads();
    int e0 = b * 4096;
    #pragma unroll
    for (int j = 0; j < 16; j++){
      int e = e0 + t + j*256;
      if (e < E){
        int d = dst[e], s = src[e];
        int slot = atomicAdd(&off[d >> 8], 1);
        ebuf[slot] = make_int2(d, s);
      }
    }
    return;
  }
  int r0 = (b - C) * 64;
  {
    int row = t >> 2, c0 = (t & 3) * 32; int rr = r0 + row;
    #pragma unroll
    for (int j = 0; j < 8; j++){
      int c = c0 + 4*j;
      float4 v = make_float4(0.f,0.f,0.f,0.f);
      if (rr < N) v = *(const float4*)(h + (size_t)rr*NDIM + c);
      us4 o;
      o.x = f2b(v.x * scsh[c]   + scsh[128+c]);
      o.y = f2b(v.y * scsh[c+1] + scsh[129+c]);
      o.z = f2b(v.z * scsh[c+2] + scsh[130+c]);
      o.w = f2b(v.w * scsh[c+3] + scsh[131+c]);
      *(us4*)&hn[row][c] = o;
    }
  }
  __syncthreads();
  int lane = t & 63, w = t >> 6;
  int lr = lane & 15, kg = lane >> 4;
  int srow = t >> 2, sc0 = (t & 3) * 32;   // staging-store mapping
  f32x4 zero = {0.f,0.f,0.f,0.f};

  #define DO_PASS(WT, OUT, FIRST) { \
    f32x4 acc[2][4]; \
    _Pragma("unroll") for (int n = 0; n < 2; n++) _Pragma("unroll") for (int m = 0; m < 4; m++) acc[n][m] = zero; \
    gemm_tiles<2,4,128,136>(&hn[0][0], WT, lr, kg, w*32, acc); \
    if (!FIRST) __syncthreads(); \
    _Pragma("unroll") for (int n = 0; n < 2; n++){ \
      int col = w*32 + n*16 + lr; \
      _Pragma("unroll") for (int m = 0; m < 4; m++) \
        _Pragma("unroll") for (int r = 0; r < 4; r++) \
          ob[m*16 + kg*4 + r][col] = f2b(acc[n][m][r]); \
    } \
    __syncthreads(); \
    if (r0 + srow < N){ \
      u16* dp = OUT + (size_t)(r0 + srow)*NDIM + sc0; \
      _Pragma("unroll") for (int j = 0; j < 4; j++) \
        *(us8*)(dp + j*8) = *(const us8*)&ob[srow][sc0 + j*8]; \
    } }
  DO_PASS(WTq, Q, true)
  DO_PASS(WTk, K, false)
  DO_PASS(WTv, V, false)
  #undef DO_PASS
}

// ============ fused edge phase: score + softmax + weighted V aggregation (shuffle-free) ============
// One wave/node, 8 edge slots in flight. Score lane = j*8+h does the full 16-dim dot
// for (edge j, head h). Edge indices come from SCALAR loads (wave-uniform window base);
// V rows load early via SGPR base. Weight redistribution via a 64-float per-wave LDS
// transpose (1 ds_write + 2 ds_read_b128) instead of 8 bpermutes.
__global__ __launch_bounds__(256) void k_sagg(const int* __restrict__ rowptr, const int* __restrict__ csr_src,
                                              const u16* __restrict__ Q, const u16* __restrict__ K,
                                              const u16* __restrict__ V, u16* __restrict__ wV, int N){
  __shared__ float wx[4][64];
  int w = threadIdx.x >> 6, l = threadIdx.x & 63;
  int n = blockIdx.x*4 + w;
  if (n >= N) return;
  int j8 = l >> 3, hh = l & 7, d0 = l * 2;

  float2 qf[8];
  {
    const unsigned* qp = (const unsigned*)(Q + (size_t)n*NDIM + hh*16);
    #pragma unroll
    for (int t = 0; t < 8; t++){
      unsigned u = qp[t];
      qf[t].x = blo(u) * 0.25f;
      qf[t].y = bhi(u) * 0.25f;
    }
  }

  int e0 = rowptr[n], e1 = rowptr[n+1];
  float ssum_l = 0.f;
  float a0 = 0.f, a1 = 0.f;
  int i = e0;

  for (; i + 8 <= e1; i += 8){
    int i0 = __builtin_amdgcn_readfirstlane(i);
    int s0 = csr_src[i0+0], s1 = csr_src[i0+1], s2 = csr_src[i0+2], s3 = csr_src[i0+3];
    int s4 = csr_src[i0+4], s5 = csr_src[i0+5], s6 = csr_src[i0+6], s7 = csr_src[i0+7];
    // V rows: SGPR base + lane offset, issued before the score chain
    unsigned vv0 = *(const unsigned*)(V + (size_t)s0*NDIM + d0);
    unsigned vv1 = *(const unsigned*)(V + (size_t)s1*NDIM + d0);
    unsigned vv2 = *(const unsigned*)(V + (size_t)s2*NDIM + d0);
    unsigned vv3 = *(const unsigned*)(V + (size_t)s3*NDIM + d0);
    unsigned vv4 = *(const unsigned*)(V + (size_t)s4*NDIM + d0);
    unsigned vv5 = *(const unsigned*)(V + (size_t)s5*NDIM + d0);
    unsigned vv6 = *(const unsigned*)(V + (size_t)s6*NDIM + d0);
    unsigned vv7 = *(const unsigned*)(V + (size_t)s7*NDIM + d0);
    // K gather + in-lane dot for (edge j8, head hh)
    int sidx = csr_src[i + j8];
    const unsigned* kp = (const unsigned*)(K + (size_t)sidx*NDIM + hh*16);
    float px = 0.f, py = 0.f;
    #pragma unroll
    for (int t = 0; t < 8; t++){
      unsigned u = kp[t];
      px += qf[t].x * blo(u);
      py += qf[t].y * bhi(u);
    }
    float p = px + py;
    p = fminf(5.f, fmaxf(-5.f, p));
    float wgt = __expf(p);
    ssum_l += wgt;
    wx[w][hh*8 + j8] = wgt;
    float4 wa = *(const float4*)&wx[w][j8*8];
    float4 wb = *(const float4*)&wx[w][j8*8 + 4];
    a0 += wa.x*blo(vv0) + wa.y*blo(vv1) + wa.z*blo(vv2) + wa.w*blo(vv3)
        + wb.x*blo(vv4) + wb.y*blo(vv5) + wb.z*blo(vv6) + wb.w*blo(vv7);
    a1 += wa.x*bhi(vv0) + wa.y*bhi(vv1) + wa.z*bhi(vv2) + wa.w*bhi(vv3)
        + wb.x*bhi(vv4) + wb.y*bhi(vv5) + wb.z*bhi(vv6) + wb.w*bhi(vv7);
  }

  int rem = e1 - i;
  if (rem > 0){
    int i0 = __builtin_amdgcn_readfirstlane(i);
    int s[8];
    #pragma unroll
    for (int j = 0; j < 8; j++) s[j] = csr_src[i0 + (j < rem ? j : 0)];
    unsigned vv[8];
    #pragma unroll
    for (int j = 0; j < 8; j++) vv[j] = *(const unsigned*)(V + (size_t)s[j]*NDIM + d0);
    int sidx = csr_src[i0 + (j8 < rem ? j8 : 0)];
    const unsigned* kp = (const unsigned*)(K + (size_t)sidx*NDIM + hh*16);
    float px = 0.f, py = 0.f;
    #pragma unroll
    for (int t = 0; t < 8; t++){
      unsigned u = kp[t];
      px += qf[t].x * blo(u);
      py += qf[t].y * bhi(u);
    }
    float p = px + py;
    p = fminf(5.f, fmaxf(-5.f, p));
    float wgt = (j8 < rem) ? __expf(p) : 0.f;
    ssum_l += wgt;
    wx[w][hh*8 + j8] = wgt;
    float4 wa = *(const float4*)&wx[w][j8*8];
    float4 wb = *(const float4*)&wx[w][j8*8 + 4];
    a0 += wa.x*blo(vv[0]) + wa.y*blo(vv[1]) + wa.z*blo(vv[2]) + wa.w*blo(vv[3])
        + wb.x*blo(vv[4]) + wb.y*blo(vv[5]) + wb.z*blo(vv[6]) + wb.w*blo(vv[7]);
    a1 += wa.x*bhi(vv[0]) + wa.y*bhi(vv[1]) + wa.z*bhi(vv[2]) + wa.w*bhi(vv[3])
        + wb.x*bhi(vv[4]) + wb.y*bhi(vv[5]) + wb.z*bhi(vv[6]) + wb.w*bhi(vv[7]);
  }

  ssum_l += __shfl_xor(ssum_l, 8);
  ssum_l += __shfl_xor(ssum_l, 16);
  ssum_l += __shfl_xor(ssum_l, 32);
  float ssum = __shfl(ssum_l, j8);       // lane j8 holds head (j8&7)==l>>3 total
  float inv = (e1 > e0) ? 1.f/ssum : 0.f;
  unsigned pk = (unsigned)f2b(a0*inv) | (((unsigned)f2b(a1*inv)) << 16);
  *(unsigned*)(wV + (size_t)n*NDIM + d0) = pk;
}

// ============ O-projection + residual + BN2 stats (MFMA) ============
__global__ __launch_bounds__(256) void k_h2(const u16* __restrict__ wV, const u16* __restrict__ WTo,
                                            const float* __restrict__ bo, const float* __restrict__ h,
                                            float* __restrict__ h2, float* __restrict__ sums2, int N){
  __shared__ u16 tw[64][136];
  int t = threadIdx.x; int r0 = blockIdx.x * 64;
  {
    int row = t >> 2, c0 = (t & 3) * 32; int rr = r0 + row;
    #pragma unroll
    for (int j = 0; j < 4; j++){
      int c = c0 + 8*j;
      us8 v = {0,0,0,0,0,0,0,0};
      if (rr < N) v = *(const us8*)(wV + (size_t)rr*NDIM + c);
      *(us8*)&tw[row][c] = v;
    }
  }
  __syncthreads();
  int lane = t & 63, w = t >> 6;
  int lr = lane & 15, kg = lane >> 4;
  f32x4 zero = {0.f,0.f,0.f,0.f};
  f32x4 acc[2][4];
  #pragma unroll
  for (int n = 0; n < 2; n++)
    #pragma unroll
    for (int m = 0; m < 4; m++) acc[n][m] = zero;
  gemm_tiles<2,4,128,136>(&tw[0][0], WTo, lr, kg, w*32, acc);

  float sv[2] = {0.f, 0.f}, qv[2] = {0.f, 0.f};
  #pragma unroll
  for (int n = 0; n < 2; n++){
    int col = w*32 + n*16 + lr;
    float bb = bo[col];
    #pragma unroll
    for (int m = 0; m < 4; m++)
      #pragma unroll
      for (int r = 0; r < 4; r++){
        int rr = r0 + m*16 + kg*4 + r;
        if (rr < N){
          size_t o = (size_t)rr*NDIM + col;
          float v = acc[n][m][r] + bb + h[o];
          h2[o] = v;
          sv[n] += v; qv[n] += v*v;
        }
      }
  }
  #pragma unroll
  for (int n = 0; n < 2; n++){
    float s = sv[n], q = qv[n];
    s += __shfl_xor(s, 16); s += __shfl_xor(s, 32);
    q += __shfl_xor(q, 16); q += __shfl_xor(q, 32);
    if (kg == 0){
      int col = w*32 + n*16 + lr;
      atomicAdd(&sums2[col], s);
      atomicAdd(&sums2[128+col], q);
    }
  }
}

// ============ BN2-apply + FFN + residual (MFMA) ============
__global__ __launch_bounds__(256) void k_ffn(const float* __restrict__ h2, const float* __restrict__ scsh,
                                             const u16* __restrict__ WT1, const float* __restrict__ b1,
                                             const u16* __restrict__ WT2, const float* __restrict__ b2,
                                             float* __restrict__ out, int N){
  __shared__ u16 x[64][136];
  __shared__ u16 tt[64][264];
  int t = threadIdx.x; int r0 = blockIdx.x * 64;
  {
    int row = t >> 2, c0 = (t & 3) * 32; int rr = r0 + row;
    #pragma unroll
    for (int j = 0; j < 8; j++){
      int c = c0 + 4*j;
      float4 v = make_float4(0.f,0.f,0.f,0.f);
      if (rr < N) v = *(const float4*)(h2 + (size_t)rr*NDIM + c);
      us4 o;
      o.x = f2b(v.x * scsh[c]   + scsh[128+c]);
      o.y = f2b(v.y * scsh[c+1] + scsh[129+c]);
      o.z = f2b(v.z * scsh[c+2] + scsh[130+c]);
      o.w = f2b(v.w * scsh[c+3] + scsh[131+c]);
      *(us4*)&x[row][c] = o;
    }
  }
  __syncthreads();
  int lane = t & 63, w = t >> 6;
  int lr = lane & 15, kg = lane >> 4;
  f32x4 zero = {0.f,0.f,0.f,0.f};
  {
    f32x4 a1[4][4];
    #pragma unroll
    for (int n = 0; n < 4; n++)
      #pragma unroll
      for (int m = 0; m < 4; m++) a1[n][m] = zero;
    gemm_tiles<4,4,128,136>(&x[0][0], WT1, lr, kg, w*64, a1);
    #pragma unroll
    for (int n = 0; n < 4; n++){
      int col = w*64 + n*16 + lr;
      float bb = b1[col];
      #pragma unroll
      for (int m = 0; m < 4; m++)
        #pragma unroll
        for (int r = 0; r < 4; r++)
          tt[m*16 + kg*4 + r][col] = f2b(fmaxf(a1[n][m][r] + bb, 0.f));
    }
  }
  __syncthreads();
  {
    f32x4 a2[2][4];
    #pragma unroll
    for (int n = 0; n < 2; n++)
      #pragma unroll
      for (int m = 0; m < 4; m++) a2[n][m] = zero;
    gemm_tiles<2,8,256,264>(&tt[0][0], WT2, lr, kg, w*32, a2);
    #pragma unroll
    for (int n = 0; n < 2; n++){
      int col = w*32 + n*16 + lr;
      float bb = b2[col];
      #pragma unroll
      for (int m = 0; m < 4; m++)
        #pragma unroll
        for (int r = 0; r < 4; r++){
          int rr = r0 + m*16 + kg*4 + r;
          if (rr < N){
            size_t o = (size_t)rr*NDIM + col;
            out[o] = h2[o] + a2[n][m][r] + bb;
          }
        }
    }
  }
}

extern "C" void kernel_launch(void* const* d_in, const int* in_sizes, int n_in,
                              void* d_out, int out_size, void* d_ws, size_t ws_size,
                              hipStream_t stream) {
  const float* h    = (const float*)d_in[0];
  const int*   src  = (const int*)d_in[1];
  const int*   dst  = (const int*)d_in[2];
  const float* Wq   = (const float*)d_in[3];
  const float* Wk   = (const float*)d_in[4];
  const float* Wv   = (const float*)d_in[5];
  const float* Wo   = (const float*)d_in[6];
  const float* bo   = (const float*)d_in[7];
  const float* bn1g = (const float*)d_in[8];
  const float* bn1b = (const float*)d_in[9];
  const float* bn2g = (const float*)d_in[10];
  const float* bn2b = (const float*)d_in[11];
  const float* W1   = (const float*)d_in[12];
  const float* b1   = (const float*)d_in[13];
  const float* W2   = (const float*)d_in[14];
  const float* b2   = (const float*)d_in[15];
  float* out = (float*)d_out;

  int N = in_sizes[0] / NDIM;
  int E = in_sizes[1];
  size_t fN = (size_t)N * NDIM;

  int B   = (N + 255) >> 8;       // coarse buckets (256 nodes each), must be <= 256
  int C   = (E + 4095) >> 12;     // edge chunks (4096 edges each)
  int NB2 = B * C;
  int nb2 = (NB2 + 255) / 256;    // must be <= 256

  u16* Q  = (u16*)d_ws;
  u16* K  = Q + fN;
  u16* V  = K + fN;
  u16* wV = Q;                                  // reuse: each wave reads Q[n] before writing wV[n]
  float* h2   = (float*)(V + fN);               // fN floats
  int2* ebuf  = (int2*)(h2 + fN);               // E int2 (8B aligned here)
  int* rowptr = (int*)(ebuf + E);               // N+1
  int* bsum   = rowptr + (N + 1);               // 256
  int* cntT   = bsum + 256;                     // NB2
  int* scn    = cntT + NB2;                     // NB2
  int* csr_src= scn + NB2;                      // E
  float* sums1 = (float*)(csr_src + E);
  float* sums2 = sums1 + 256;
  float* scsh1 = sums2 + 256;
  float* scsh2 = scsh1 + 256;
  u16* wtq = (u16*)(scsh2 + 256);
  u16* wtk = wtq + NDIM*NDIM;
  u16* wtv = wtk + NDIM*NDIM;
  u16* wto = wtv + NDIM*NDIM;
  u16* wt1 = wto + NDIM*NDIM;
  u16* wt2 = wt1 + NDIM*2*NDIM;

  hipMemsetAsync(sums1, 0, 512 * sizeof(float), stream);

  int nBn = (N + 127) / 128;
  int nQ  = (N + 63) / 64;

  k_pro<<<nBn + 32 + C, 256, 0, stream>>>(Wq, Wk, Wv, Wo, W1, W2,
                                          wtq, wtk, wtv, wto, wt1, wt2,
                                          h, sums1, dst, cntT, nBn, N, E, B, C);
  k_bn_final<<<1, 128, 0, stream>>>(sums1, bn1g, bn1b, scsh1, N);

  k_scan_part<<<nb2, 256, 0, stream>>>(cntT, bsum, NB2);
  k_scan_top<<<1, 256, 0, stream>>>(bsum, nb2, rowptr, N, E);
  k_scan_down<<<nb2, 256, 0, stream>>>(cntT, bsum, scn, NB2);

  k_qkv_bucket<<<C + nQ, 256, 0, stream>>>(h, scsh1, wtq, wtk, wtv, Q, K, V, N,
                                           src, dst, scn, ebuf, B, C, E);
  k_finesort<<<B, 256, 0, stream>>>(ebuf, scn, rowptr, csr_src, B, C, N, E);

  k_sagg<<<(N + 3)/4, 256, 0, stream>>>(rowptr, csr_src, Q, K, V, wV, N);

  k_h2<<<(N + 63)/64, 256, 0, stream>>>(wV, wto, bo, h, h2, sums2, N);
  k_bn_final<<<1, 128, 0, stream>>>(sums2, bn2g, bn2b, scsh2, N);
  k_ffn<<<(N + 63)/64, 256, 0, stream>>>(h2, scsh2, wt1, b1, wt2, b2, out, N);
}

// Round 10
// 245.095 us; speedup vs baseline: 2.7309x; 1.0374x over previous
//
#include <hip/hip_runtime.h>
#include <hip/hip_bf16.h>

#define NDIM 128
#define NHEAD 8
#define EPSV 1e-5f

typedef unsigned short u16;
using bf16x8 = __attribute__((ext_vector_type(8))) short;
using f32x4  = __attribute__((ext_vector_type(4))) float;
using us8    = __attribute__((ext_vector_type(8))) unsigned short;
using us4    = __attribute__((ext_vector_type(4))) unsigned short;

__device__ __forceinline__ u16 f2b(float x){
  union { float f; unsigned u; } v; v.f = x;
  unsigned r = v.u + 0x7FFFu + ((v.u >> 16) & 1u);
  return (u16)(r >> 16);
}
__device__ __forceinline__ float b2f(u16 u){
  union { unsigned u; float f; } v; v.u = ((unsigned)u) << 16; return v.f;
}
__device__ __forceinline__ float blo(unsigned u){
  union { unsigned u; float f; } v; v.u = u << 16; return v.f;
}
__device__ __forceinline__ float bhi(unsigned u){
  union { unsigned u; float f; } v; v.u = u & 0xFFFF0000u; return v.f;
}

// A-frag: lane provides A[lane%16][(lane/16)*8 + j]; B-frag: B[(lane/16)*8+j][lane%16]
// C/D: col = lane&15, row = (lane>>4)*4 + reg   (measured m89)
template<int NT, int MT, int KS, int WTLD, int XSTR>
__device__ __forceinline__ void gemm_tiles(const u16* X, const u16* __restrict__ WT,
                                           int lr, int kg, int colbase, f32x4 (&acc)[NT][MT]){
  #pragma unroll
  for (int ks = 0; ks < KS; ks++){
    bf16x8 a[MT];
    #pragma unroll
    for (int m = 0; m < MT; m++)
      a[m] = *(const bf16x8*)(X + (size_t)(m*16 + lr)*XSTR + ks*32 + kg*8);
    #pragma unroll
    for (int n = 0; n < NT; n++){
      int col = colbase + n*16 + lr;
      bf16x8 b = *(const bf16x8*)(WT + (size_t)col*WTLD + ks*32 + kg*8);
      #pragma unroll
      for (int m = 0; m < MT; m++)
        acc[n][m] = __builtin_amdgcn_mfma_f32_16x16x32_bf16(a[m], b, acc[n][m], 0, 0, 0);
    }
  }
}

// transpose one 64x64 tile of W (rows x cols, f32) into WT (cols x rows, bf16), coalesced both ways
__device__ __forceinline__ void wconv_tile(const float* __restrict__ W, u16* __restrict__ WT,
                                           int rows, int cols, int tr, int tc, int t){
  __shared__ u16 T[64][66];
  int r0 = tr*64, c0 = tc*64;
  int r = t >> 2, cq = (t & 3) * 16;
  const float* src = W + (size_t)(r0 + r)*cols + c0 + cq;
  #pragma unroll
  for (int j = 0; j < 4; j++){
    float4 v = *(const float4*)(src + 4*j);
    us4 o; o.x = f2b(v.x); o.y = f2b(v.y); o.z = f2b(v.z); o.w = f2b(v.w);
    *(us4*)&T[r][cq + 4*j] = o;
  }
  __syncthreads();
  int c = t >> 2, rq = (t & 3) * 16;
  us8 o0, o1;
  #pragma unroll
  for (int j = 0; j < 8; j++){ o0[j] = T[rq + j][c]; o1[j] = T[rq + 8 + j][c]; }
  u16* dstp = WT + (size_t)(c0 + c)*rows + r0 + rq;
  *(us8*)dstp = o0;
  *(us8*)(dstp + 8) = o1;
}

// ============ pro: BN1 stats (nBn) + weight transpose (32) + coarse edge histogram (C chunks) ============
__global__ __launch_bounds__(256) void k_pro(
    const float* __restrict__ Wq, const float* __restrict__ Wk, const float* __restrict__ Wv,
    const float* __restrict__ Wo, const float* __restrict__ W1, const float* __restrict__ W2,
    u16* __restrict__ wtq, u16* __restrict__ wtk, u16* __restrict__ wtv,
    u16* __restrict__ wto, u16* __restrict__ wt1, u16* __restrict__ wt2,
    const float* __restrict__ h, float* __restrict__ sums,
    const int* __restrict__ dst, int* __restrict__ cntT,
    int nBn, int N, int E, int B, int C){
  __shared__ float ls[256], ls2[256];
  __shared__ int hist[256];
  int b = blockIdx.x, t = threadIdx.x;
  if (b < nBn){
    int col = t & 127, half = t >> 7;
    int r0 = b * 128; int r1 = r0 + 128; if (r1 > N) r1 = N;
    float s = 0.f, s2 = 0.f;
    for (int r = r0 + half; r < r1; r += 2){ float v = h[(size_t)r*NDIM + col]; s += v; s2 += v*v; }
    ls[t] = s; ls2[t] = s2; __syncthreads();
    if (t < 128){ atomicAdd(&sums[col], ls[t] + ls[t+128]); atomicAdd(&sums[128+col], ls2[t] + ls2[t+128]); }
    return;
  }
  b -= nBn;
  if (b < 16){
    const float* Ws[4] = {Wq, Wk, Wv, Wo};
    u16* Ts[4] = {wtq, wtk, wtv, wto};
    int wi = b >> 2, ti = b & 3;
    wconv_tile(Ws[wi], Ts[wi], 128, 128, ti >> 1, ti & 1, t);
    return;
  }
  if (b < 24){
    int ti = b - 16;
    wconv_tile(W1, wt1, 128, 256, ti >> 2, ti & 3, t);
    return;
  }
  if (b < 32){
    int ti = b - 24;
    wconv_tile(W2, wt2, 256, 128, ti & 3, ti >> 2, t);
    return;
  }
  int ci = b - 32;           // coarse histogram chunk
  if (ci >= C) return;
  hist[t] = 0; __syncthreads();
  int e0 = ci * 4096;
  #pragma unroll
  for (int j = 0; j < 16; j++){
    int e = e0 + t + j*256;
    if (e < E) atomicAdd(&hist[dst[e] >> 8], 1);
  }
  __syncthreads();
  if (t < B) cntT[t*C + ci] = hist[t];
}

// ============ standalone BN stats over an fp32 matrix ============
__global__ __launch_bounds__(256) void k_bnstats(const float* __restrict__ x, float* __restrict__ sums, int N){
  __shared__ float ls[256], ls2[256];
  int b = blockIdx.x, t = threadIdx.x;
  int col = t & 127, half = t >> 7;
  int r0 = b * 128; int r1 = r0 + 128; if (r1 > N) r1 = N;
  float s = 0.f, s2 = 0.f;
  for (int r = r0 + half; r < r1; r += 2){ float v = x[(size_t)r*NDIM + col]; s += v; s2 += v*v; }
  ls[t] = s; ls2[t] = s2; __syncthreads();
  if (t < 128){ atomicAdd(&sums[col], ls[t] + ls[t+128]); atomicAdd(&sums[128+col], ls2[t] + ls2[t+128]); }
}

__global__ __launch_bounds__(128) void k_bn_final(const float* __restrict__ sums, const float* __restrict__ g,
                                                  const float* __restrict__ b, float* __restrict__ scsh, int N){
  int c = threadIdx.x;
  float mean = sums[c] / (float)N;
  float var  = sums[128+c] / (float)N - mean*mean;
  float rstd = rsqrtf(var + EPSV);
  float sc = g[c] * rstd;
  scsh[c] = sc; scsh[128+c] = b[c] - mean*sc;
}

// ============ generic scan kernels (exclusive scan of in[0..len)) ============
__global__ __launch_bounds__(256) void k_scan_part(const int* __restrict__ in, int* __restrict__ bsum, int len){
  __shared__ int ls[256];
  int t = threadIdx.x; int i = blockIdx.x*256 + t;
  ls[t] = (i < len) ? in[i] : 0; __syncthreads();
  for (int off = 128; off > 0; off >>= 1){
    if (t < off) ls[t] += ls[t + off];
    __syncthreads();
  }
  if (t == 0) bsum[blockIdx.x] = ls[0];
}

__global__ __launch_bounds__(256) void k_scan_top(int* __restrict__ bsum, int nb, int* __restrict__ rowptr, int N, int E){
  __shared__ int ls[256];
  int t = threadIdx.x;
  int v = (t < nb) ? bsum[t] : 0; ls[t] = v; __syncthreads();
  for (int off = 1; off < 256; off <<= 1){
    int add = (t >= off) ? ls[t - off] : 0;
    __syncthreads();
    ls[t] += add;
    __syncthreads();
  }
  if (t < nb) bsum[t] = ls[t] - v;
  if (t == 0) rowptr[N] = E;
}

__global__ __launch_bounds__(256) void k_scan_down(const int* __restrict__ in, const int* __restrict__ bsum,
                                                   int* __restrict__ outp, int len){
  __shared__ int ls[256];
  int t = threadIdx.x; int i = blockIdx.x*256 + t;
  int v = (i < len) ? in[i] : 0; ls[t] = v; __syncthreads();
  for (int off = 1; off < 256; off <<= 1){
    int add = (t >= off) ? ls[t - off] : 0;
    __syncthreads();
    ls[t] += add;
    __syncthreads();
  }
  if (i < len) outp[i] = ls[t] - v + bsum[blockIdx.x];
}

// ============ fine sort within bucket: rowptr + csr_src (LDS atomics only) ============
__global__ __launch_bounds__(256) void k_finesort(const int2* __restrict__ ebuf, const int* __restrict__ scn,
                                                  int* __restrict__ rowptr, int* __restrict__ csr_src,
                                                  int B, int C, int N, int E){
  __shared__ int ls[256], cur[256];
  int b = blockIdx.x, t = threadIdx.x;
  int base = scn[b*C];
  int end  = (b == B-1) ? E : scn[(b+1)*C];
  int lo = b << 8;
  cur[t] = 0; __syncthreads();
  for (int e = base + t; e < end; e += 256) atomicAdd(&cur[ebuf[e].x - lo], 1);
  __syncthreads();
  int v = cur[t]; ls[t] = v; __syncthreads();
  for (int off = 1; off < 256; off <<= 1){
    int add = (t >= off) ? ls[t - off] : 0;
    __syncthreads();
    ls[t] += add;
    __syncthreads();
  }
  int excl = ls[t] - v;
  __syncthreads();
  cur[t] = excl;
  if (lo + t < N) rowptr[lo + t] = base + excl;
  __syncthreads();
  for (int e = base + t; e < end; e += 256){
    int2 p = ebuf[e];
    int slot = base + atomicAdd(&cur[p.x - lo], 1);
    csr_src[slot] = p.y;
  }
}

// ============ merged: bucket pass (first C blocks) + BN1-apply + QKV projection (MFMA) ============
__global__ __launch_bounds__(256) void k_qkv_bucket(
    const float* __restrict__ h, const float* __restrict__ scsh,
    const u16* __restrict__ WTq, const u16* __restrict__ WTk, const u16* __restrict__ WTv,
    u16* __restrict__ Q, u16* __restrict__ K, u16* __restrict__ V, int N,
    const int* __restrict__ src, const int* __restrict__ dst,
    const int* __restrict__ scn, int2* __restrict__ ebuf, int B, int C, int E){
  __shared__ u16 hn[64][136];
  __shared__ u16 ob[64][136];
  __shared__ int off[256];
  int b = blockIdx.x, t = threadIdx.x;
  if (b < C){
    off[t] = (t < B) ? scn[t*C + b] : 0;
    __syncthreads();
    int e0 = b * 4096;
    #pragma unroll
    for (int j = 0; j < 16; j++){
      int e = e0 + t + j*256;
      if (e < E){
        int d = dst[e], s = src[e];
        int slot = atomicAdd(&off[d >> 8], 1);
        ebuf[slot] = make_int2(d, s);
      }
    }
    return;
  }
  int r0 = (b - C) * 64;
  {
    int row = t >> 2, c0 = (t & 3) * 32; int rr = r0 + row;
    #pragma unroll
    for (int j = 0; j < 8; j++){
      int c = c0 + 4*j;
      float4 v = make_float4(0.f,0.f,0.f,0.f);
      if (rr < N) v = *(const float4*)(h + (size_t)rr*NDIM + c);
      us4 o;
      o.x = f2b(v.x * scsh[c]   + scsh[128+c]);
      o.y = f2b(v.y * scsh[c+1] + scsh[129+c]);
      o.z = f2b(v.z * scsh[c+2] + scsh[130+c]);
      o.w = f2b(v.w * scsh[c+3] + scsh[131+c]);
      *(us4*)&hn[row][c] = o;
    }
  }
  __syncthreads();
  int lane = t & 63, w = t >> 6;
  int lr = lane & 15, kg = lane >> 4;
  int srow = t >> 2, sc0 = (t & 3) * 32;   // staging-store mapping
  f32x4 zero = {0.f,0.f,0.f,0.f};

  #define DO_PASS(WT, OUT, FIRST) { \
    f32x4 acc[2][4]; \
    _Pragma("unroll") for (int n = 0; n < 2; n++) _Pragma("unroll") for (int m = 0; m < 4; m++) acc[n][m] = zero; \
    gemm_tiles<2,4,4,128,136>(&hn[0][0], WT, lr, kg, w*32, acc); \
    if (!FIRST) __syncthreads(); \
    _Pragma("unroll") for (int n = 0; n < 2; n++){ \
      int col = w*32 + n*16 + lr; \
      _Pragma("unroll") for (int m = 0; m < 4; m++) \
        _Pragma("unroll") for (int r = 0; r < 4; r++) \
          ob[m*16 + kg*4 + r][col] = f2b(acc[n][m][r]); \
    } \
    __syncthreads(); \
    if (r0 + srow < N){ \
      u16* dp = OUT + (size_t)(r0 + srow)*NDIM + sc0; \
      _Pragma("unroll") for (int j = 0; j < 4; j++) \
        *(us8*)(dp + j*8) = *(const us8*)&ob[srow][sc0 + j*8]; \
    } }
  DO_PASS(WTq, Q, true)
  DO_PASS(WTk, K, false)
  DO_PASS(WTv, V, false)
  #undef DO_PASS
}

// ============ fused edge phase: score + softmax + weighted V aggregation (shuffle-free) ============
__global__ __launch_bounds__(256) void k_sagg(const int* __restrict__ rowptr, const int* __restrict__ csr_src,
                                              const u16* __restrict__ Q, const u16* __restrict__ K,
                                              const u16* __restrict__ V, u16* __restrict__ wV, int N){
  __shared__ float wx[4][64];
  int w = threadIdx.x >> 6, l = threadIdx.x & 63;
  int n = blockIdx.x*4 + w;
  if (n >= N) return;
  int j8 = l >> 3, hh = l & 7, d0 = l * 2;

  float2 qf[8];
  {
    const unsigned* qp = (const unsigned*)(Q + (size_t)n*NDIM + hh*16);
    #pragma unroll
    for (int t = 0; t < 8; t++){
      unsigned u = qp[t];
      qf[t].x = blo(u) * 0.25f;
      qf[t].y = bhi(u) * 0.25f;
    }
  }

  int e0 = rowptr[n], e1 = rowptr[n+1];
  float ssum_l = 0.f;
  float a0 = 0.f, a1 = 0.f;
  int i = e0;

  for (; i + 8 <= e1; i += 8){
    int i0 = __builtin_amdgcn_readfirstlane(i);
    int s0 = csr_src[i0+0], s1 = csr_src[i0+1], s2 = csr_src[i0+2], s3 = csr_src[i0+3];
    int s4 = csr_src[i0+4], s5 = csr_src[i0+5], s6 = csr_src[i0+6], s7 = csr_src[i0+7];
    unsigned vv0 = *(const unsigned*)(V + (size_t)s0*NDIM + d0);
    unsigned vv1 = *(const unsigned*)(V + (size_t)s1*NDIM + d0);
    unsigned vv2 = *(const unsigned*)(V + (size_t)s2*NDIM + d0);
    unsigned vv3 = *(const unsigned*)(V + (size_t)s3*NDIM + d0);
    unsigned vv4 = *(const unsigned*)(V + (size_t)s4*NDIM + d0);
    unsigned vv5 = *(const unsigned*)(V + (size_t)s5*NDIM + d0);
    unsigned vv6 = *(const unsigned*)(V + (size_t)s6*NDIM + d0);
    unsigned vv7 = *(const unsigned*)(V + (size_t)s7*NDIM + d0);
    int sidx = csr_src[i + j8];
    const unsigned* kp = (const unsigned*)(K + (size_t)sidx*NDIM + hh*16);
    float px = 0.f, py = 0.f;
    #pragma unroll
    for (int t = 0; t < 8; t++){
      unsigned u = kp[t];
      px += qf[t].x * blo(u);
      py += qf[t].y * bhi(u);
    }
    float p = px + py;
    p = fminf(5.f, fmaxf(-5.f, p));
    float wgt = __expf(p);
    ssum_l += wgt;
    wx[w][hh*8 + j8] = wgt;
    float4 wa = *(const float4*)&wx[w][j8*8];
    float4 wb = *(const float4*)&wx[w][j8*8 + 4];
    a0 += wa.x*blo(vv0) + wa.y*blo(vv1) + wa.z*blo(vv2) + wa.w*blo(vv3)
        + wb.x*blo(vv4) + wb.y*blo(vv5) + wb.z*blo(vv6) + wb.w*blo(vv7);
    a1 += wa.x*bhi(vv0) + wa.y*bhi(vv1) + wa.z*bhi(vv2) + wa.w*bhi(vv3)
        + wb.x*bhi(vv4) + wb.y*bhi(vv5) + wb.z*bhi(vv6) + wb.w*bhi(vv7);
  }

  int rem = e1 - i;
  if (rem > 0){
    int i0 = __builtin_amdgcn_readfirstlane(i);
    int s[8];
    #pragma unroll
    for (int j = 0; j < 8; j++) s[j] = csr_src[i0 + (j < rem ? j : 0)];
    unsigned vv[8];
    #pragma unroll
    for (int j = 0; j < 8; j++) vv[j] = *(const unsigned*)(V + (size_t)s[j]*NDIM + d0);
    int sidx = csr_src[i0 + (j8 < rem ? j8 : 0)];
    const unsigned* kp = (const unsigned*)(K + (size_t)sidx*NDIM + hh*16);
    float px = 0.f, py = 0.f;
    #pragma unroll
    for (int t = 0; t < 8; t++){
      unsigned u = kp[t];
      px += qf[t].x * blo(u);
      py += qf[t].y * bhi(u);
    }
    float p = px + py;
    p = fminf(5.f, fmaxf(-5.f, p));
    float wgt = (j8 < rem) ? __expf(p) : 0.f;
    ssum_l += wgt;
    wx[w][hh*8 + j8] = wgt;
    float4 wa = *(const float4*)&wx[w][j8*8];
    float4 wb = *(const float4*)&wx[w][j8*8 + 4];
    a0 += wa.x*blo(vv[0]) + wa.y*blo(vv[1]) + wa.z*blo(vv[2]) + wa.w*blo(vv[3])
        + wb.x*blo(vv[4]) + wb.y*blo(vv[5]) + wb.z*blo(vv[6]) + wb.w*blo(vv[7]);
    a1 += wa.x*bhi(vv[0]) + wa.y*bhi(vv[1]) + wa.z*bhi(vv[2]) + wa.w*bhi(vv[3])
        + wb.x*bhi(vv[4]) + wb.y*bhi(vv[5]) + wb.z*bhi(vv[6]) + wb.w*bhi(vv[7]);
  }

  ssum_l += __shfl_xor(ssum_l, 8);
  ssum_l += __shfl_xor(ssum_l, 16);
  ssum_l += __shfl_xor(ssum_l, 32);
  float ssum = __shfl(ssum_l, j8);
  float inv = (e1 > e0) ? 1.f/ssum : 0.f;
  unsigned pk = (unsigned)f2b(a0*inv) | (((unsigned)f2b(a1*inv)) << 16);
  *(unsigned*)(wV + (size_t)n*NDIM + d0) = pk;
}

// ============ O-projection + residual (MFMA, 32-row tiles, coalesced epilogue) ============
__global__ __launch_bounds__(256) void k_h2(const u16* __restrict__ wV, const u16* __restrict__ WTo,
                                            const float* __restrict__ bo, const float* __restrict__ h,
                                            float* __restrict__ h2, int N){
  __shared__ u16 tw[32][136];
  __shared__ float ob[32][132];
  int t = threadIdx.x; int r0 = blockIdx.x * 32;
  int row = t >> 3, c0 = (t & 7) * 16;
  {
    int rr = r0 + row;
    us8 z = {0,0,0,0,0,0,0,0};
    const u16* sp = wV + (size_t)rr*NDIM + c0;
    *(us8*)&tw[row][c0]     = (rr < N) ? *(const us8*)sp       : z;
    *(us8*)&tw[row][c0 + 8] = (rr < N) ? *(const us8*)(sp + 8) : z;
  }
  __syncthreads();
  int lane = t & 63, w = t >> 6;
  int lr = lane & 15, kg = lane >> 4;
  f32x4 zero = {0.f,0.f,0.f,0.f};
  f32x4 acc[2][2];
  #pragma unroll
  for (int n = 0; n < 2; n++)
    #pragma unroll
    for (int m = 0; m < 2; m++) acc[n][m] = zero;
  gemm_tiles<2,2,4,128,136>(&tw[0][0], WTo, lr, kg, w*32, acc);
  #pragma unroll
  for (int n = 0; n < 2; n++){
    int col = w*32 + n*16 + lr;
    float bb = bo[col];
    #pragma unroll
    for (int m = 0; m < 2; m++)
      #pragma unroll
      for (int r = 0; r < 4; r++)
        ob[m*16 + kg*4 + r][col] = acc[n][m][r] + bb;
  }
  __syncthreads();
  if (r0 + row < N){
    const float* hp = h  + (size_t)(r0 + row)*NDIM + c0;
    float*       op = h2 + (size_t)(r0 + row)*NDIM + c0;
    #pragma unroll
    for (int j = 0; j < 4; j++){
      float4 hv = *(const float4*)(hp + 4*j);
      float4 o;
      o.x = ob[row][c0 + 4*j]     + hv.x;
      o.y = ob[row][c0 + 4*j + 1] + hv.y;
      o.z = ob[row][c0 + 4*j + 2] + hv.z;
      o.w = ob[row][c0 + 4*j + 3] + hv.w;
      *(float4*)(op + 4*j) = o;
    }
  }
}

// ============ BN2-apply + FFN + residual (MFMA, 32-row tiles, coalesced epilogue) ============
__global__ __launch_bounds__(256) void k_ffn(const float* __restrict__ h2, const float* __restrict__ scsh,
                                             const u16* __restrict__ WT1, const float* __restrict__ b1,
                                             const u16* __restrict__ WT2, const float* __restrict__ b2,
                                             float* __restrict__ out, int N){
  __shared__ u16 x[32][136];
  __shared__ u16 tt[32][264];          // reused as float [32][132] after GEMM2
  int t = threadIdx.x; int r0 = blockIdx.x * 32;
  int row = t >> 3, c0 = (t & 7) * 16;
  {
    int rr = r0 + row;
    #pragma unroll
    for (int j = 0; j < 4; j++){
      int c = c0 + 4*j;
      float4 v = make_float4(0.f,0.f,0.f,0.f);
      if (rr < N) v = *(const float4*)(h2 + (size_t)rr*NDIM + c);
      us4 o;
      o.x = f2b(v.x * scsh[c]   + scsh[128+c]);
      o.y = f2b(v.y * scsh[c+1] + scsh[129+c]);
      o.z = f2b(v.z * scsh[c+2] + scsh[130+c]);
      o.w = f2b(v.w * scsh[c+3] + scsh[131+c]);
      *(us4*)&x[row][c] = o;
    }
  }
  __syncthreads();
  int lane = t & 63, w = t >> 6;
  int lr = lane & 15, kg = lane >> 4;
  f32x4 zero = {0.f,0.f,0.f,0.f};
  {
    f32x4 a1[4][2];
    #pragma unroll
    for (int n = 0; n < 4; n++)
      #pragma unroll
      for (int m = 0; m < 2; m++) a1[n][m] = zero;
    gemm_tiles<4,2,4,128,136>(&x[0][0], WT1, lr, kg, w*64, a1);
    #pragma unroll
    for (int n = 0; n < 4; n++){
      int col = w*64 + n*16 + lr;
      float bb = b1[col];
      #pragma unroll
      for (int m = 0; m < 2; m++)
        #pragma unroll
        for (int r = 0; r < 4; r++)
          tt[m*16 + kg*4 + r][col] = f2b(fmaxf(a1[n][m][r] + bb, 0.f));
    }
  }
  __syncthreads();
  f32x4 a2[2][2];
  #pragma unroll
  for (int n = 0; n < 2; n++)
    #pragma unroll
    for (int m = 0; m < 2; m++) a2[n][m] = zero;
  gemm_tiles<2,2,8,256,264>(&tt[0][0], WT2, lr, kg, w*32, a2);
  __syncthreads();                      // all tt reads done before overlay
  float* ob2 = (float*)&tt[0][0];       // [32][132], 16896 B — exact overlay
  #pragma unroll
  for (int n = 0; n < 2; n++){
    int col = w*32 + n*16 + lr;
    float bb = b2[col];
    #pragma unroll
    for (int m = 0; m < 2; m++)
      #pragma unroll
      for (int r = 0; r < 4; r++)
        ob2[(m*16 + kg*4 + r)*132 + col] = a2[n][m][r] + bb;
  }
  __syncthreads();
  if (r0 + row < N){
    const float* hp = h2  + (size_t)(r0 + row)*NDIM + c0;
    float*       op = out + (size_t)(r0 + row)*NDIM + c0;
    #pragma unroll
    for (int j = 0; j < 4; j++){
      float4 hv = *(const float4*)(hp + 4*j);
      float4 o;
      o.x = ob2[row*132 + c0 + 4*j]     + hv.x;
      o.y = ob2[row*132 + c0 + 4*j + 1] + hv.y;
      o.z = ob2[row*132 + c0 + 4*j + 2] + hv.z;
      o.w = ob2[row*132 + c0 + 4*j + 3] + hv.w;
      *(float4*)(op + 4*j) = o;
    }
  }
}

extern "C" void kernel_launch(void* const* d_in, const int* in_sizes, int n_in,
                              void* d_out, int out_size, void* d_ws, size_t ws_size,
                              hipStream_t stream) {
  const float* h    = (const float*)d_in[0];
  const int*   src  = (const int*)d_in[1];
  const int*   dst  = (const int*)d_in[2];
  const float* Wq   = (const float*)d_in[3];
  const float* Wk   = (const float*)d_in[4];
  const float* Wv   = (const float*)d_in[5];
  const float* Wo   = (const float*)d_in[6];
  const float* bo   = (const float*)d_in[7];
  const float* bn1g = (const float*)d_in[8];
  const float* bn1b = (const float*)d_in[9];
  const float* bn2g = (const float*)d_in[10];
  const float* bn2b = (const float*)d_in[11];
  const float* W1   = (const float*)d_in[12];
  const float* b1   = (const float*)d_in[13];
  const float* W2   = (const float*)d_in[14];
  const float* b2   = (const float*)d_in[15];
  float* out = (float*)d_out;

  int N = in_sizes[0] / NDIM;
  int E = in_sizes[1];
  size_t fN = (size_t)N * NDIM;

  int B   = (N + 255) >> 8;       // coarse buckets (256 nodes each), must be <= 256
  int C   = (E + 4095) >> 12;     // edge chunks (4096 edges each)
  int NB2 = B * C;
  int nb2 = (NB2 + 255) / 256;    // must be <= 256

  u16* Q  = (u16*)d_ws;
  u16* K  = Q + fN;
  u16* V  = K + fN;
  u16* wV = Q;                                  // reuse: each wave reads Q[n] before writing wV[n]
  float* h2   = (float*)(V + fN);               // fN floats
  int2* ebuf  = (int2*)(h2 + fN);               // E int2 (8B aligned here)
  int* rowptr = (int*)(ebuf + E);               // N+1
  int* bsum   = rowptr + (N + 1);               // 256
  int* cntT   = bsum + 256;                     // NB2
  int* scn    = cntT + NB2;                     // NB2
  int* csr_src= scn + NB2;                      // E
  float* sums1 = (float*)(csr_src + E);
  float* sums2 = sums1 + 256;
  float* scsh1 = sums2 + 256;
  float* scsh2 = scsh1 + 256;
  u16* wtq = (u16*)(scsh2 + 256);
  u16* wtk = wtq + NDIM*NDIM;
  u16* wtv = wtk + NDIM*NDIM;
  u16* wto = wtv + NDIM*NDIM;
  u16* wt1 = wto + NDIM*NDIM;
  u16* wt2 = wt1 + NDIM*2*NDIM;

  hipMemsetAsync(sums1, 0, 512 * sizeof(float), stream);

  int nBn = (N + 127) / 128;
  int nQ  = (N + 63) / 64;
  int n32 = (N + 31) / 32;

  k_pro<<<nBn + 32 + C, 256, 0, stream>>>(Wq, Wk, Wv, Wo, W1, W2,
                                          wtq, wtk, wtv, wto, wt1, wt2,
                                          h, sums1, dst, cntT, nBn, N, E, B, C);
  k_bn_final<<<1, 128, 0, stream>>>(sums1, bn1g, bn1b, scsh1, N);

  k_scan_part<<<nb2, 256, 0, stream>>>(cntT, bsum, NB2);
  k_scan_top<<<1, 256, 0, stream>>>(bsum, nb2, rowptr, N, E);
  k_scan_down<<<nb2, 256, 0, stream>>>(cntT, bsum, scn, NB2);

  k_qkv_bucket<<<C + nQ, 256, 0, stream>>>(h, scsh1, wtq, wtk, wtv, Q, K, V, N,
                                           src, dst, scn, ebuf, B, C, E);
  k_finesort<<<B, 256, 0, stream>>>(ebuf, scn, rowptr, csr_src, B, C, N, E);

  k_sagg<<<(N + 3)/4, 256, 0, stream>>>(rowptr, csr_src, Q, K, V, wV, N);

  k_h2<<<n32, 256, 0, stream>>>(wV, wto, bo, h, h2, N);
  k_bnstats<<<nBn, 256, 0, stream>>>(h2, sums2, N);
  k_bn_final<<<1, 128, 0, stream>>>(sums2, bn2g, bn2b, scsh2, N);
  k_ffn<<<n32, 256, 0, stream>>>(h2, scsh2, wt1, b1, wt2, b2, out, N);
}

// Round 11
// 244.074 us; speedup vs baseline: 2.7424x; 1.0042x over previous
//
#include <hip/hip_runtime.h>
#include <hip/hip_bf16.h>

#define NDIM 128
#define NHEAD 8
#define EPSV 1e-5f

#if defined(__has_builtin)
#  if __has_builtin(__builtin_amdgcn_cvt_pk_fp8_f32) && __has_builtin(__builtin_amdgcn_cvt_pk_f32_fp8)
#    define HAVE_FP8 1
#  else
#    define HAVE_FP8 0
#  endif
#else
#  define HAVE_FP8 0
#endif

typedef unsigned short u16;
typedef unsigned char u8;
using bf16x8 = __attribute__((ext_vector_type(8))) short;
using f32x4  = __attribute__((ext_vector_type(4))) float;
using f32x2  = __attribute__((ext_vector_type(2))) float;
using us8    = __attribute__((ext_vector_type(8))) unsigned short;
using us4    = __attribute__((ext_vector_type(4))) unsigned short;

__device__ __forceinline__ u16 f2b(float x){
  union { float f; unsigned u; } v; v.f = x;
  unsigned r = v.u + 0x7FFFu + ((v.u >> 16) & 1u);
  return (u16)(r >> 16);
}
__device__ __forceinline__ float b2f(u16 u){
  union { unsigned u; float f; } v; v.u = ((unsigned)u) << 16; return v.f;
}
__device__ __forceinline__ float blo(unsigned u){
  union { unsigned u; float f; } v; v.u = u << 16; return v.f;
}
__device__ __forceinline__ float bhi(unsigned u){
  union { unsigned u; float f; } v; v.u = u & 0xFFFF0000u; return v.f;
}

// A-frag: lane provides A[lane%16][(lane/16)*8 + j]; B-frag: B[(lane/16)*8+j][lane%16]
// C/D: col = lane&15, row = (lane>>4)*4 + reg   (measured m89)
template<int NT, int MT, int KS, int WTLD, int XSTR>
__device__ __forceinline__ void gemm_tiles(const u16* X, const u16* __restrict__ WT,
                                           int lr, int kg, int colbase, f32x4 (&acc)[NT][MT]){
  #pragma unroll
  for (int ks = 0; ks < KS; ks++){
    bf16x8 a[MT];
    #pragma unroll
    for (int m = 0; m < MT; m++)
      a[m] = *(const bf16x8*)(X + (size_t)(m*16 + lr)*XSTR + ks*32 + kg*8);
    #pragma unroll
    for (int n = 0; n < NT; n++){
      int col = colbase + n*16 + lr;
      bf16x8 b = *(const bf16x8*)(WT + (size_t)col*WTLD + ks*32 + kg*8);
      #pragma unroll
      for (int m = 0; m < MT; m++)
        acc[n][m] = __builtin_amdgcn_mfma_f32_16x16x32_bf16(a[m], b, acc[n][m], 0, 0, 0);
    }
  }
}

// transpose one 64x64 tile of W (rows x cols, f32) into WT (cols x rows, bf16)
__device__ __forceinline__ void wconv_tile(const float* __restrict__ W, u16* __restrict__ WT,
                                           int rows, int cols, int tr, int tc, int t){
  __shared__ u16 T[64][66];
  int r0 = tr*64, c0 = tc*64;
  int r = t >> 2, cq = (t & 3) * 16;
  const float* src = W + (size_t)(r0 + r)*cols + c0 + cq;
  #pragma unroll
  for (int j = 0; j < 4; j++){
    float4 v = *(const float4*)(src + 4*j);
    us4 o; o.x = f2b(v.x); o.y = f2b(v.y); o.z = f2b(v.z); o.w = f2b(v.w);
    *(us4*)&T[r][cq + 4*j] = o;
  }
  __syncthreads();
  int c = t >> 2, rq = (t & 3) * 16;
  us8 o0, o1;
  #pragma unroll
  for (int j = 0; j < 8; j++){ o0[j] = T[rq + j][c]; o1[j] = T[rq + 8 + j][c]; }
  u16* dstp = WT + (size_t)(c0 + c)*rows + r0 + rq;
  *(us8*)dstp = o0;
  *(us8*)(dstp + 8) = o1;
}

// ============ pro: BN1 stats (nBn) + weight transpose (32) + coarse edge histogram (C chunks) ============
__global__ __launch_bounds__(256) void k_pro(
    const float* __restrict__ Wq, const float* __restrict__ Wk, const float* __restrict__ Wv,
    const float* __restrict__ Wo, const float* __restrict__ W1, const float* __restrict__ W2,
    u16* __restrict__ wtq, u16* __restrict__ wtk, u16* __restrict__ wtv,
    u16* __restrict__ wto, u16* __restrict__ wt1, u16* __restrict__ wt2,
    const float* __restrict__ h, float* __restrict__ sums,
    const int* __restrict__ dst, int* __restrict__ cntT,
    int nBn, int N, int E, int B, int C){
  __shared__ float ls[256], ls2[256];
  __shared__ int hist[256];
  int b = blockIdx.x, t = threadIdx.x;
  if (b < nBn){
    int col = t & 127, half = t >> 7;
    int r0 = b * 128; int r1 = r0 + 128; if (r1 > N) r1 = N;
    float s = 0.f, s2 = 0.f;
    for (int r = r0 + half; r < r1; r += 2){ float v = h[(size_t)r*NDIM + col]; s += v; s2 += v*v; }
    ls[t] = s; ls2[t] = s2; __syncthreads();
    if (t < 128){ atomicAdd(&sums[col], ls[t] + ls[t+128]); atomicAdd(&sums[128+col], ls2[t] + ls2[t+128]); }
    return;
  }
  b -= nBn;
  if (b < 16){
    const float* Ws[4] = {Wq, Wk, Wv, Wo};
    u16* Ts[4] = {wtq, wtk, wtv, wto};
    int wi = b >> 2, ti = b & 3;
    wconv_tile(Ws[wi], Ts[wi], 128, 128, ti >> 1, ti & 1, t);
    return;
  }
  if (b < 24){
    int ti = b - 16;
    wconv_tile(W1, wt1, 128, 256, ti >> 2, ti & 3, t);
    return;
  }
  if (b < 32){
    int ti = b - 24;
    wconv_tile(W2, wt2, 256, 128, ti & 3, ti >> 2, t);
    return;
  }
  int ci = b - 32;
  if (ci >= C) return;
  hist[t] = 0; __syncthreads();
  int e0 = ci * 4096;
  #pragma unroll
  for (int j = 0; j < 16; j++){
    int e = e0 + t + j*256;
    if (e < E) atomicAdd(&hist[dst[e] >> 8], 1);
  }
  __syncthreads();
  if (t < B) cntT[t*C + ci] = hist[t];
}

// ============ block 0: BN1 finalize; blocks 1..: scan partials over cntT ============
__global__ __launch_bounds__(256) void k_bnf_scan(
    const float* __restrict__ sums, const float* __restrict__ g, const float* __restrict__ b_,
    float* __restrict__ scsh, int N,
    const int* __restrict__ in, int* __restrict__ bsum, int len){
  __shared__ int ls[256];
  int t = threadIdx.x, b = blockIdx.x;
  if (b == 0){
    if (t < 128){
      float mean = sums[t] / (float)N;
      float var  = sums[128+t] / (float)N - mean*mean;
      float rstd = rsqrtf(var + EPSV);
      float sc = g[t] * rstd;
      scsh[t] = sc; scsh[128+t] = b_[t] - mean*sc;
    }
    return;
  }
  b -= 1;
  int i = b*256 + t;
  ls[t] = (i < len) ? in[i] : 0; __syncthreads();
  for (int off = 128; off > 0; off >>= 1){
    if (t < off) ls[t] += ls[t + off];
    __syncthreads();
  }
  if (t == 0) bsum[b] = ls[0];
}

__global__ __launch_bounds__(128) void k_bn_final(const float* __restrict__ sums, const float* __restrict__ g,
                                                  const float* __restrict__ b, float* __restrict__ scsh, int N){
  int c = threadIdx.x;
  float mean = sums[c] / (float)N;
  float var  = sums[128+c] / (float)N - mean*mean;
  float rstd = rsqrtf(var + EPSV);
  float sc = g[c] * rstd;
  scsh[c] = sc; scsh[128+c] = b[c] - mean*sc;
}

__global__ __launch_bounds__(256) void k_scan_top(int* __restrict__ bsum, int nb, int* __restrict__ rowptr, int N, int E){
  __shared__ int ls[256];
  int t = threadIdx.x;
  int v = (t < nb) ? bsum[t] : 0; ls[t] = v; __syncthreads();
  for (int off = 1; off < 256; off <<= 1){
    int add = (t >= off) ? ls[t - off] : 0;
    __syncthreads();
    ls[t] += add;
    __syncthreads();
  }
  if (t < nb) bsum[t] = ls[t] - v;
  if (t == 0) rowptr[N] = E;
}

__global__ __launch_bounds__(256) void k_scan_down(const int* __restrict__ in, const int* __restrict__ bsum,
                                                   int* __restrict__ outp, int len){
  __shared__ int ls[256];
  int t = threadIdx.x; int i = blockIdx.x*256 + t;
  int v = (i < len) ? in[i] : 0; ls[t] = v; __syncthreads();
  for (int off = 1; off < 256; off <<= 1){
    int add = (t >= off) ? ls[t - off] : 0;
    __syncthreads();
    ls[t] += add;
    __syncthreads();
  }
  if (i < len) outp[i] = ls[t] - v + bsum[blockIdx.x];
}

// ============ fine sort within bucket: rowptr + csr_src (LDS atomics only) ============
__global__ __launch_bounds__(256) void k_finesort(const int2* __restrict__ ebuf, const int* __restrict__ scn,
                                                  int* __restrict__ rowptr, int* __restrict__ csr_src,
                                                  int B, int C, int N, int E){
  __shared__ int ls[256], cur[256];
  int b = blockIdx.x, t = threadIdx.x;
  int base = scn[b*C];
  int end  = (b == B-1) ? E : scn[(b+1)*C];
  int lo = b << 8;
  cur[t] = 0; __syncthreads();
  for (int e = base + t; e < end; e += 256) atomicAdd(&cur[ebuf[e].x - lo], 1);
  __syncthreads();
  int v = cur[t]; ls[t] = v; __syncthreads();
  for (int off = 1; off < 256; off <<= 1){
    int add = (t >= off) ? ls[t - off] : 0;
    __syncthreads();
    ls[t] += add;
    __syncthreads();
  }
  int excl = ls[t] - v;
  __syncthreads();
  cur[t] = excl;
  if (lo + t < N) rowptr[lo + t] = base + excl;
  __syncthreads();
  for (int e = base + t; e < end; e += 256){
    int2 p = ebuf[e];
    int slot = base + atomicAdd(&cur[p.x - lo], 1);
    csr_src[slot] = p.y;
  }
}

// ============ merged: bucket pass (first C blocks) + BN1-apply + QKV projection (MFMA) ============
// K is emitted as fp8-e4m3 (HAVE_FP8) to halve the sagg K-gather bytes.
__global__ __launch_bounds__(256) void k_qkv_bucket(
    const float* __restrict__ h, const float* __restrict__ scsh,
    const u16* __restrict__ WTq, const u16* __restrict__ WTk, const u16* __restrict__ WTv,
    u16* __restrict__ Q, u16* __restrict__ K, u16* __restrict__ V, int N,
    const int* __restrict__ src, const int* __restrict__ dst,
    const int* __restrict__ scn, int2* __restrict__ ebuf, int B, int C, int E){
  __shared__ u16 hn[64][136];
  __shared__ u16 ob[64][136];
  __shared__ int off[256];
  int b = blockIdx.x, t = threadIdx.x;
  if (b < C){
    off[t] = (t < B) ? scn[t*C + b] : 0;
    __syncthreads();
    int e0 = b * 4096;
    #pragma unroll
    for (int j = 0; j < 16; j++){
      int e = e0 + t + j*256;
      if (e < E){
        int d = dst[e], s = src[e];
        int slot = atomicAdd(&off[d >> 8], 1);
        ebuf[slot] = make_int2(d, s);
      }
    }
    return;
  }
  int r0 = (b - C) * 64;
  {
    int row = t >> 2, c0 = (t & 3) * 32; int rr = r0 + row;
    #pragma unroll
    for (int j = 0; j < 8; j++){
      int c = c0 + 4*j;
      float4 v = make_float4(0.f,0.f,0.f,0.f);
      if (rr < N) v = *(const float4*)(h + (size_t)rr*NDIM + c);
      us4 o;
      o.x = f2b(v.x * scsh[c]   + scsh[128+c]);
      o.y = f2b(v.y * scsh[c+1] + scsh[129+c]);
      o.z = f2b(v.z * scsh[c+2] + scsh[130+c]);
      o.w = f2b(v.w * scsh[c+3] + scsh[131+c]);
      *(us4*)&hn[row][c] = o;
    }
  }
  __syncthreads();
  int lane = t & 63, w = t >> 6;
  int lr = lane & 15, kg = lane >> 4;
  int srow = t >> 2, sc0 = (t & 3) * 32;
  f32x4 zero = {0.f,0.f,0.f,0.f};

  #define DO_PASS(WT, OUT, FIRST) { \
    f32x4 acc[2][4]; \
    _Pragma("unroll") for (int n = 0; n < 2; n++) _Pragma("unroll") for (int m = 0; m < 4; m++) acc[n][m] = zero; \
    gemm_tiles<2,4,4,128,136>(&hn[0][0], WT, lr, kg, w*32, acc); \
    if (!FIRST) __syncthreads(); \
    _Pragma("unroll") for (int n = 0; n < 2; n++){ \
      int col = w*32 + n*16 + lr; \
      _Pragma("unroll") for (int m = 0; m < 4; m++) \
        _Pragma("unroll") for (int r = 0; r < 4; r++) \
          ob[m*16 + kg*4 + r][col] = f2b(acc[n][m][r]); \
    } \
    __syncthreads(); \
    if (r0 + srow < N){ \
      u16* dp = OUT + (size_t)(r0 + srow)*NDIM + sc0; \
      _Pragma("unroll") for (int j = 0; j < 4; j++) \
        *(us8*)(dp + j*8) = *(const us8*)&ob[srow][sc0 + j*8]; \
    } }

  DO_PASS(WTq, Q, true)

  // K pass: GEMM -> ob(bf16) -> fp8 (or bf16 fallback) coalesced store
  {
    f32x4 acc[2][4];
    #pragma unroll
    for (int n = 0; n < 2; n++)
      #pragma unroll
      for (int m = 0; m < 4; m++) acc[n][m] = zero;
    gemm_tiles<2,4,4,128,136>(&hn[0][0], WTk, lr, kg, w*32, acc);
    __syncthreads();
    #pragma unroll
    for (int n = 0; n < 2; n++){
      int col = w*32 + n*16 + lr;
      #pragma unroll
      for (int m = 0; m < 4; m++)
        #pragma unroll
        for (int r = 0; r < 4; r++)
          ob[m*16 + kg*4 + r][col] = f2b(acc[n][m][r]);
    }
    __syncthreads();
    if (r0 + srow < N){
#if HAVE_FP8
      u8* dp = (u8*)K + (size_t)(r0 + srow)*NDIM + sc0;
      #pragma unroll
      for (int j = 0; j < 4; j++){
        us8 v = *(const us8*)&ob[srow][sc0 + 8*j];
        int w0 = __builtin_amdgcn_cvt_pk_fp8_f32(b2f(v[0]), b2f(v[1]), 0, false);
        w0     = __builtin_amdgcn_cvt_pk_fp8_f32(b2f(v[2]), b2f(v[3]), w0, true);
        int w1 = __builtin_amdgcn_cvt_pk_fp8_f32(b2f(v[4]), b2f(v[5]), 0, false);
        w1     = __builtin_amdgcn_cvt_pk_fp8_f32(b2f(v[6]), b2f(v[7]), w1, true);
        *(uint2*)(dp + 8*j) = make_uint2((unsigned)w0, (unsigned)w1);
      }
#else
      u16* dp = K + (size_t)(r0 + srow)*NDIM + sc0;
      #pragma unroll
      for (int j = 0; j < 4; j++)
        *(us8*)(dp + j*8) = *(const us8*)&ob[srow][sc0 + j*8];
#endif
    }
  }

  DO_PASS(WTv, V, false)
  #undef DO_PASS
}

// ============ fused edge phase: score + softmax + weighted V aggregation ============
// fp8 K gather (128 B/edge), bf16 V gather (256 B/edge). Next-window scalar index prefetch.
__global__ __launch_bounds__(256) void k_sagg(const int* __restrict__ rowptr, const int* __restrict__ csr_src,
                                              const u16* __restrict__ Q, const u16* __restrict__ K,
                                              const u16* __restrict__ V, u16* __restrict__ wV, int N){
  __shared__ float wx[4][64];
  int w = threadIdx.x >> 6, l = threadIdx.x & 63;
  int n = blockIdx.x*4 + w;
  if (n >= N) return;
  int j8 = l >> 3, hh = l & 7, d0 = l * 2;

  float qf[16];
  {
    const unsigned* qp = (const unsigned*)(Q + (size_t)n*NDIM + hh*16);
    #pragma unroll
    for (int t = 0; t < 8; t++){
      unsigned u = qp[t];
      qf[2*t]   = blo(u) * 0.25f;
      qf[2*t+1] = bhi(u) * 0.25f;
    }
  }

#if HAVE_FP8
  const u8* Kb = (const u8*)K;
  #define KDOT(p, sidx) { \
    uint4 kw = *(const uint4*)(Kb + (size_t)(sidx)*NDIM + (hh << 4)); \
    { f32x2 a_ = __builtin_amdgcn_cvt_pk_f32_fp8((int)kw.x, false); \
      f32x2 b_ = __builtin_amdgcn_cvt_pk_f32_fp8((int)kw.x, true); \
      p += qf[0]*a_.x + qf[1]*a_.y + qf[2]*b_.x + qf[3]*b_.y; } \
    { f32x2 a_ = __builtin_amdgcn_cvt_pk_f32_fp8((int)kw.y, false); \
      f32x2 b_ = __builtin_amdgcn_cvt_pk_f32_fp8((int)kw.y, true); \
      p += qf[4]*a_.x + qf[5]*a_.y + qf[6]*b_.x + qf[7]*b_.y; } \
    { f32x2 a_ = __builtin_amdgcn_cvt_pk_f32_fp8((int)kw.z, false); \
      f32x2 b_ = __builtin_amdgcn_cvt_pk_f32_fp8((int)kw.z, true); \
      p += qf[8]*a_.x + qf[9]*a_.y + qf[10]*b_.x + qf[11]*b_.y; } \
    { f32x2 a_ = __builtin_amdgcn_cvt_pk_f32_fp8((int)kw.w, false); \
      f32x2 b_ = __builtin_amdgcn_cvt_pk_f32_fp8((int)kw.w, true); \
      p += qf[12]*a_.x + qf[13]*a_.y + qf[14]*b_.x + qf[15]*b_.y; } }
#else
  #define KDOT(p, sidx) { \
    const unsigned* kp = (const unsigned*)(K + (size_t)(sidx)*NDIM + hh*16); \
    _Pragma("unroll") for (int t_ = 0; t_ < 8; t_++){ \
      unsigned u_ = kp[t_]; \
      p += qf[2*t_]*blo(u_) + qf[2*t_+1]*bhi(u_); } }
#endif

  int e0 = rowptr[n], e1 = rowptr[n+1];
  int e1s = __builtin_amdgcn_readfirstlane(e1);
  float ssum_l = 0.f;
  float a0 = 0.f, a1 = 0.f;
  int i = e0;
  int i0 = __builtin_amdgcn_readfirstlane(i);

  int sc[8];
  if (i + 8 <= e1){
    #pragma unroll
    for (int j = 0; j < 8; j++) sc[j] = csr_src[i0 + j];
  }

  for (; i + 8 <= e1; ){
    int inext = i + 8, i0n = i0 + 8;
    int sn[8];
    {
      int pb = (i0n + 8 <= e1s) ? i0n : i0;     // prefetch next window (or re-read current)
      #pragma unroll
      for (int j = 0; j < 8; j++) sn[j] = csr_src[pb + j];
    }
    unsigned vv0 = *(const unsigned*)(V + (size_t)sc[0]*NDIM + d0);
    unsigned vv1 = *(const unsigned*)(V + (size_t)sc[1]*NDIM + d0);
    unsigned vv2 = *(const unsigned*)(V + (size_t)sc[2]*NDIM + d0);
    unsigned vv3 = *(const unsigned*)(V + (size_t)sc[3]*NDIM + d0);
    unsigned vv4 = *(const unsigned*)(V + (size_t)sc[4]*NDIM + d0);
    unsigned vv5 = *(const unsigned*)(V + (size_t)sc[5]*NDIM + d0);
    unsigned vv6 = *(const unsigned*)(V + (size_t)sc[6]*NDIM + d0);
    unsigned vv7 = *(const unsigned*)(V + (size_t)sc[7]*NDIM + d0);
    int sidx = csr_src[i + j8];
    float p = 0.f;
    KDOT(p, sidx)
    p = fminf(5.f, fmaxf(-5.f, p));
    float wgt = __expf(p);
    ssum_l += wgt;
    wx[w][hh*8 + j8] = wgt;
    float4 wa = *(const float4*)&wx[w][j8*8];
    float4 wb = *(const float4*)&wx[w][j8*8 + 4];
    a0 += wa.x*blo(vv0) + wa.y*blo(vv1) + wa.z*blo(vv2) + wa.w*blo(vv3)
        + wb.x*blo(vv4) + wb.y*blo(vv5) + wb.z*blo(vv6) + wb.w*blo(vv7);
    a1 += wa.x*bhi(vv0) + wa.y*bhi(vv1) + wa.z*bhi(vv2) + wa.w*bhi(vv3)
        + wb.x*bhi(vv4) + wb.y*bhi(vv5) + wb.z*bhi(vv6) + wb.w*bhi(vv7);
    #pragma unroll
    for (int j = 0; j < 8; j++) sc[j] = sn[j];
    i = inext; i0 = i0n;
  }

  int rem = e1 - i;
  if (rem > 0){
    i0 = __builtin_amdgcn_readfirstlane(i);
    int s[8];
    #pragma unroll
    for (int j = 0; j < 8; j++) s[j] = csr_src[i0 + (j < rem ? j : 0)];
    unsigned vv[8];
    #pragma unroll
    for (int j = 0; j < 8; j++) vv[j] = *(const unsigned*)(V + (size_t)s[j]*NDIM + d0);
    int sidx = csr_src[i0 + (j8 < rem ? j8 : 0)];
    float p = 0.f;
    KDOT(p, sidx)
    p = fminf(5.f, fmaxf(-5.f, p));
    float wgt = (j8 < rem) ? __expf(p) : 0.f;
    ssum_l += wgt;
    wx[w][hh*8 + j8] = wgt;
    float4 wa = *(const float4*)&wx[w][j8*8];
    float4 wb = *(const float4*)&wx[w][j8*8 + 4];
    a0 += wa.x*blo(vv[0]) + wa.y*blo(vv[1]) + wa.z*blo(vv[2]) + wa.w*blo(vv[3])
        + wb.x*blo(vv[4]) + wb.y*blo(vv[5]) + wb.z*blo(vv[6]) + wb.w*blo(vv[7]);
    a1 += wa.x*bhi(vv[0]) + wa.y*bhi(vv[1]) + wa.z*bhi(vv[2]) + wa.w*bhi(vv[3])
        + wb.x*bhi(vv[4]) + wb.y*bhi(vv[5]) + wb.z*bhi(vv[6]) + wb.w*bhi(vv[7]);
  }
  #undef KDOT

  ssum_l += __shfl_xor(ssum_l, 8);
  ssum_l += __shfl_xor(ssum_l, 16);
  ssum_l += __shfl_xor(ssum_l, 32);
  float ssum = __shfl(ssum_l, j8);
  float inv = (e1 > e0) ? 1.f/ssum : 0.f;
  unsigned pk = (unsigned)f2b(a0*inv) | (((unsigned)f2b(a1*inv)) << 16);
  *(unsigned*)(wV + (size_t)n*NDIM + d0) = pk;
}

// ============ O-projection + residual + inline BN2 column partials (MFMA, 32-row tiles) ============
__global__ __launch_bounds__(256) void k_h2(const u16* __restrict__ wV, const u16* __restrict__ WTo,
                                            const float* __restrict__ bo, const float* __restrict__ h,
                                            float* __restrict__ h2, float* __restrict__ sums2, int N){
  __shared__ u16 tw[32][136];
  __shared__ float ob[32][132];
  int t = threadIdx.x; int r0 = blockIdx.x * 32;
  int row = t >> 3, c0 = (t & 7) * 16;
  {
    int rr = r0 + row;
    us8 z = {0,0,0,0,0,0,0,0};
    const u16* sp = wV + (size_t)rr*NDIM + c0;
    *(us8*)&tw[row][c0]     = (rr < N) ? *(const us8*)sp       : z;
    *(us8*)&tw[row][c0 + 8] = (rr < N) ? *(const us8*)(sp + 8) : z;
  }
  __syncthreads();
  int lane = t & 63, w = t >> 6;
  int lr = lane & 15, kg = lane >> 4;
  f32x4 zero = {0.f,0.f,0.f,0.f};
  f32x4 acc[2][2];
  #pragma unroll
  for (int n = 0; n < 2; n++)
    #pragma unroll
    for (int m = 0; m < 2; m++) acc[n][m] = zero;
  gemm_tiles<2,2,4,128,136>(&tw[0][0], WTo, lr, kg, w*32, acc);
  #pragma unroll
  for (int n = 0; n < 2; n++){
    int col = w*32 + n*16 + lr;
    float bb = bo[col];
    #pragma unroll
    for (int m = 0; m < 2; m++)
      #pragma unroll
      for (int r = 0; r < 4; r++)
        ob[m*16 + kg*4 + r][col] = acc[n][m][r] + bb;
  }
  __syncthreads();
  if (r0 + row < N){
    const float* hp = h  + (size_t)(r0 + row)*NDIM + c0;
    float*       op = h2 + (size_t)(r0 + row)*NDIM + c0;
    #pragma unroll
    for (int j = 0; j < 4; j++){
      float4 hv = *(const float4*)(hp + 4*j);
      float4 o;
      o.x = ob[row][c0 + 4*j]     + hv.x;
      o.y = ob[row][c0 + 4*j + 1] + hv.y;
      o.z = ob[row][c0 + 4*j + 2] + hv.z;
      o.w = ob[row][c0 + 4*j + 3] + hv.w;
      *(float4*)(op + 4*j) = o;
      ob[row][c0 + 4*j]     = o.x;
      ob[row][c0 + 4*j + 1] = o.y;
      ob[row][c0 + 4*j + 2] = o.z;
      ob[row][c0 + 4*j + 3] = o.w;
    }
  } else {
    #pragma unroll
    for (int j = 0; j < 16; j++) ob[row][c0 + j] = 0.f;
  }
  __syncthreads();
  // column partials over the 32 rows, then one fire-and-forget atomic per column
  int colx = t & 127, hf = t >> 7;
  float s = 0.f, q = 0.f;
  #pragma unroll
  for (int r = 0; r < 16; r++){ float v = ob[hf*16 + r][colx]; s += v; q += v*v; }
  float* cs = (float*)&tw[0][0];
  cs[hf*256 + colx]       = s;
  cs[hf*256 + 128 + colx] = q;
  __syncthreads();
  if (t < 128){
    atomicAdd(&sums2[t],       cs[t]       + cs[256 + t]);
    atomicAdd(&sums2[128 + t], cs[128 + t] + cs[384 + t]);
  }
}

// ============ BN2-apply + FFN + residual (MFMA, 32-row tiles, coalesced epilogue) ============
__global__ __launch_bounds__(256) void k_ffn(const float* __restrict__ h2, const float* __restrict__ scsh,
                                             const u16* __restrict__ WT1, const float* __restrict__ b1,
                                             const u16* __restrict__ WT2, const float* __restrict__ b2,
                                             float* __restrict__ out, int N){
  __shared__ u16 x[32][136];
  __shared__ u16 tt[32][264];          // reused as float [32][132] after GEMM2
  int t = threadIdx.x; int r0 = blockIdx.x * 32;
  int row = t >> 3, c0 = (t & 7) * 16;
  {
    int rr = r0 + row;
    #pragma unroll
    for (int j = 0; j < 4; j++){
      int c = c0 + 4*j;
      float4 v = make_float4(0.f,0.f,0.f,0.f);
      if (rr < N) v = *(const float4*)(h2 + (size_t)rr*NDIM + c);
      us4 o;
      o.x = f2b(v.x * scsh[c]   + scsh[128+c]);
      o.y = f2b(v.y * scsh[c+1] + scsh[129+c]);
      o.z = f2b(v.z * scsh[c+2] + scsh[130+c]);
      o.w = f2b(v.w * scsh[c+3] + scsh[131+c]);
      *(us4*)&x[row][c] = o;
    }
  }
  __syncthreads();
  int lane = t & 63, w = t >> 6;
  int lr = lane & 15, kg = lane >> 4;
  f32x4 zero = {0.f,0.f,0.f,0.f};
  {
    f32x4 a1[4][2];
    #pragma unroll
    for (int n = 0; n < 4; n++)
      #pragma unroll
      for (int m = 0; m < 2; m++) a1[n][m] = zero;
    gemm_tiles<4,2,4,128,136>(&x[0][0], WT1, lr, kg, w*64, a1);
    #pragma unroll
    for (int n = 0; n < 4; n++){
      int col = w*64 + n*16 + lr;
      float bb = b1[col];
      #pragma unroll
      for (int m = 0; m < 2; m++)
        #pragma unroll
        for (int r = 0; r < 4; r++)
          tt[m*16 + kg*4 + r][col] = f2b(fmaxf(a1[n][m][r] + bb, 0.f));
    }
  }
  __syncthreads();
  f32x4 a2[2][2];
  #pragma unroll
  for (int n = 0; n < 2; n++)
    #pragma unroll
    for (int m = 0; m < 2; m++) a2[n][m] = zero;
  gemm_tiles<2,2,8,256,264>(&tt[0][0], WT2, lr, kg, w*32, a2);
  __syncthreads();
  float* ob2 = (float*)&tt[0][0];       // [32][132] overlay
  #pragma unroll
  for (int n = 0; n < 2; n++){
    int col = w*32 + n*16 + lr;
    float bb = b2[col];
    #pragma unroll
    for (int m = 0; m < 2; m++)
      #pragma unroll
      for (int r = 0; r < 4; r++)
        ob2[(m*16 + kg*4 + r)*132 + col] = a2[n][m][r] + bb;
  }
  __syncthreads();
  if (r0 + row < N){
    const float* hp = h2  + (size_t)(r0 + row)*NDIM + c0;
    float*       op = out + (size_t)(r0 + row)*NDIM + c0;
    #pragma unroll
    for (int j = 0; j < 4; j++){
      float4 hv = *(const float4*)(hp + 4*j);
      float4 o;
      o.x = ob2[row*132 + c0 + 4*j]     + hv.x;
      o.y = ob2[row*132 + c0 + 4*j + 1] + hv.y;
      o.z = ob2[row*132 + c0 + 4*j + 2] + hv.z;
      o.w = ob2[row*132 + c0 + 4*j + 3] + hv.w;
      *(float4*)(op + 4*j) = o;
    }
  }
}

extern "C" void kernel_launch(void* const* d_in, const int* in_sizes, int n_in,
                              void* d_out, int out_size, void* d_ws, size_t ws_size,
                              hipStream_t stream) {
  const float* h    = (const float*)d_in[0];
  const int*   src  = (const int*)d_in[1];
  const int*   dst  = (const int*)d_in[2];
  const float* Wq   = (const float*)d_in[3];
  const float* Wk   = (const float*)d_in[4];
  const float* Wv   = (const float*)d_in[5];
  const float* Wo   = (const float*)d_in[6];
  const float* bo   = (const float*)d_in[7];
  const float* bn1g = (const float*)d_in[8];
  const float* bn1b = (const float*)d_in[9];
  const float* bn2g = (const float*)d_in[10];
  const float* bn2b = (const float*)d_in[11];
  const float* W1   = (const float*)d_in[12];
  const float* b1   = (const float*)d_in[13];
  const float* W2   = (const float*)d_in[14];
  const float* b2   = (const float*)d_in[15];
  float* out = (float*)d_out;

  int N = in_sizes[0] / NDIM;
  int E = in_sizes[1];
  size_t fN = (size_t)N * NDIM;

  int B   = (N + 255) >> 8;       // coarse buckets (256 nodes each), <= 256
  int C   = (E + 4095) >> 12;     // edge chunks (4096 edges each)
  int NB2 = B * C;
  int nb2 = (NB2 + 255) / 256;    // <= 256

  u16* Q  = (u16*)d_ws;
  u16* K  = Q + fN;               // fp8 path uses first fN BYTES of this 2*fN-byte slot
  u16* V  = K + fN;
  u16* wV = Q;                    // reuse: each wave reads Q[n] before writing wV[n]
  float* h2   = (float*)(V + fN);
  int2* ebuf  = (int2*)(h2 + fN);
  int* rowptr = (int*)(ebuf + E);
  int* bsum   = rowptr + (N + 1);
  int* cntT   = bsum + 256;
  int* scn    = cntT + NB2;
  int* csr_src= scn + NB2;
  float* sums1 = (float*)(csr_src + E);
  float* sums2 = sums1 + 256;
  float* scsh1 = sums2 + 256;
  float* scsh2 = scsh1 + 256;
  u16* wtq = (u16*)(scsh2 + 256);
  u16* wtk = wtq + NDIM*NDIM;
  u16* wtv = wtk + NDIM*NDIM;
  u16* wto = wtv + NDIM*NDIM;
  u16* wt1 = wto + NDIM*NDIM;
  u16* wt2 = wt1 + NDIM*2*NDIM;

  hipMemsetAsync(sums1, 0, 512 * sizeof(float), stream);   // sums1 + sums2

  int nBn = (N + 127) / 128;
  int nQ  = (N + 63) / 64;
  int n32 = (N + 31) / 32;

  k_pro<<<nBn + 32 + C, 256, 0, stream>>>(Wq, Wk, Wv, Wo, W1, W2,
                                          wtq, wtk, wtv, wto, wt1, wt2,
                                          h, sums1, dst, cntT, nBn, N, E, B, C);
  k_bnf_scan<<<1 + nb2, 256, 0, stream>>>(sums1, bn1g, bn1b, scsh1, N, cntT, bsum, NB2);
  k_scan_top<<<1, 256, 0, stream>>>(bsum, nb2, rowptr, N, E);
  k_scan_down<<<nb2, 256, 0, stream>>>(cntT, bsum, scn, NB2);

  k_qkv_bucket<<<C + nQ, 256, 0, stream>>>(h, scsh1, wtq, wtk, wtv, Q, K, V, N,
                                           src, dst, scn, ebuf, B, C, E);
  k_finesort<<<B, 256, 0, stream>>>(ebuf, scn, rowptr, csr_src, B, C, N, E);

  k_sagg<<<(N + 3)/4, 256, 0, stream>>>(rowptr, csr_src, Q, K, V, wV, N);

  k_h2<<<n32, 256, 0, stream>>>(wV, wto, bo, h, h2, sums2, N);
  k_bn_final<<<1, 128, 0, stream>>>(sums2, bn2g, bn2b, scsh2, N);
  k_ffn<<<n32, 256, 0, stream>>>(h2, scsh2, wt1, b1, wt2, b2, out, N);
}

// Round 12
// 229.022 us; speedup vs baseline: 2.9226x; 1.0657x over previous
//
#include <hip/hip_runtime.h>
#include <hip/hip_bf16.h>

#define NDIM 128
#define NHEAD 8
#define EPSV 1e-5f

#if defined(__has_builtin)
#  if __has_builtin(__builtin_amdgcn_cvt_pk_fp8_f32) && __has_builtin(__builtin_amdgcn_cvt_pk_f32_fp8)
#    define HAVE_FP8 1
#  else
#    define HAVE_FP8 0
#  endif
#else
#  define HAVE_FP8 0
#endif

typedef unsigned short u16;
typedef unsigned char u8;
using bf16x8 = __attribute__((ext_vector_type(8))) short;
using f32x4  = __attribute__((ext_vector_type(4))) float;
using f32x2  = __attribute__((ext_vector_type(2))) float;
using us8    = __attribute__((ext_vector_type(8))) unsigned short;
using us4    = __attribute__((ext_vector_type(4))) unsigned short;

__device__ __forceinline__ u16 f2b(float x){
  union { float f; unsigned u; } v; v.f = x;
  unsigned r = v.u + 0x7FFFu + ((v.u >> 16) & 1u);
  return (u16)(r >> 16);
}
__device__ __forceinline__ float b2f(u16 u){
  union { unsigned u; float f; } v; v.u = ((unsigned)u) << 16; return v.f;
}
__device__ __forceinline__ float blo(unsigned u){
  union { unsigned u; float f; } v; v.u = u << 16; return v.f;
}
__device__ __forceinline__ float bhi(unsigned u){
  union { unsigned u; float f; } v; v.u = u & 0xFFFF0000u; return v.f;
}

// A-frag: lane provides A[lane%16][(lane/16)*8 + j]; B-frag: B[(lane/16)*8+j][lane%16]
// C/D: col = lane&15, row = (lane>>4)*4 + reg   (measured m89)
template<int NT, int MT, int KS, int WTLD, int XSTR>
__device__ __forceinline__ void gemm_tiles(const u16* X, const u16* __restrict__ WT,
                                           int lr, int kg, int colbase, f32x4 (&acc)[NT][MT]){
  #pragma unroll
  for (int ks = 0; ks < KS; ks++){
    bf16x8 a[MT];
    #pragma unroll
    for (int m = 0; m < MT; m++)
      a[m] = *(const bf16x8*)(X + (size_t)(m*16 + lr)*XSTR + ks*32 + kg*8);
    #pragma unroll
    for (int n = 0; n < NT; n++){
      int col = colbase + n*16 + lr;
      bf16x8 b = *(const bf16x8*)(WT + (size_t)col*WTLD + ks*32 + kg*8);
      #pragma unroll
      for (int m = 0; m < MT; m++)
        acc[n][m] = __builtin_amdgcn_mfma_f32_16x16x32_bf16(a[m], b, acc[n][m], 0, 0, 0);
    }
  }
}

// transpose one 64x64 tile of W (rows x cols, f32) into WT (cols x rows, bf16)
__device__ __forceinline__ void wconv_tile(const float* __restrict__ W, u16* __restrict__ WT,
                                           int rows, int cols, int tr, int tc, int t){
  __shared__ u16 T[64][66];
  int r0 = tr*64, c0 = tc*64;
  int r = t >> 2, cq = (t & 3) * 16;
  const float* src = W + (size_t)(r0 + r)*cols + c0 + cq;
  #pragma unroll
  for (int j = 0; j < 4; j++){
    float4 v = *(const float4*)(src + 4*j);
    us4 o; o.x = f2b(v.x); o.y = f2b(v.y); o.z = f2b(v.z); o.w = f2b(v.w);
    *(us4*)&T[r][cq + 4*j] = o;
  }
  __syncthreads();
  int c = t >> 2, rq = (t & 3) * 16;
  us8 o0, o1;
  #pragma unroll
  for (int j = 0; j < 8; j++){ o0[j] = T[rq + j][c]; o1[j] = T[rq + 8 + j][c]; }
  u16* dstp = WT + (size_t)(c0 + c)*rows + r0 + rq;
  *(us8*)dstp = o0;
  *(us8*)(dstp + 8) = o1;
}

// ============ pro: BN1 stats (nBn) + weight transpose (32) + coarse edge histogram (C chunks) ============
__global__ __launch_bounds__(256) void k_pro(
    const float* __restrict__ Wq, const float* __restrict__ Wk, const float* __restrict__ Wv,
    const float* __restrict__ Wo, const float* __restrict__ W1, const float* __restrict__ W2,
    u16* __restrict__ wtq, u16* __restrict__ wtk, u16* __restrict__ wtv,
    u16* __restrict__ wto, u16* __restrict__ wt1, u16* __restrict__ wt2,
    const float* __restrict__ h, float* __restrict__ sums,
    const int* __restrict__ dst, int* __restrict__ cntT,
    int nBn, int N, int E, int B, int C){
  __shared__ float ls[256], ls2[256];
  __shared__ int hist[256];
  int b = blockIdx.x, t = threadIdx.x;
  if (b < nBn){
    int col = t & 127, half = t >> 7;
    int r0 = b * 128; int r1 = r0 + 128; if (r1 > N) r1 = N;
    float s = 0.f, s2 = 0.f;
    for (int r = r0 + half; r < r1; r += 2){ float v = h[(size_t)r*NDIM + col]; s += v; s2 += v*v; }
    ls[t] = s; ls2[t] = s2; __syncthreads();
    if (t < 128){ atomicAdd(&sums[col], ls[t] + ls[t+128]); atomicAdd(&sums[128+col], ls2[t] + ls2[t+128]); }
    return;
  }
  b -= nBn;
  if (b < 16){
    const float* Ws[4] = {Wq, Wk, Wv, Wo};
    u16* Ts[4] = {wtq, wtk, wtv, wto};
    int wi = b >> 2, ti = b & 3;
    wconv_tile(Ws[wi], Ts[wi], 128, 128, ti >> 1, ti & 1, t);
    return;
  }
  if (b < 24){
    int ti = b - 16;
    wconv_tile(W1, wt1, 128, 256, ti >> 2, ti & 3, t);
    return;
  }
  if (b < 32){
    int ti = b - 24;
    wconv_tile(W2, wt2, 256, 128, ti & 3, ti >> 2, t);
    return;
  }
  int ci = b - 32;
  if (ci >= C) return;
  hist[t] = 0; __syncthreads();
  int e0 = ci * 4096;
  #pragma unroll
  for (int j = 0; j < 16; j++){
    int e = e0 + t + j*256;
    if (e < E) atomicAdd(&hist[dst[e] >> 8], 1);
  }
  __syncthreads();
  if (t < B) cntT[t*C + ci] = hist[t];
}

// ============ standalone BN stats over an fp32 matrix ============
__global__ __launch_bounds__(256) void k_bnstats(const float* __restrict__ x, float* __restrict__ sums, int N){
  __shared__ float ls[256], ls2[256];
  int b = blockIdx.x, t = threadIdx.x;
  int col = t & 127, half = t >> 7;
  int r0 = b * 128; int r1 = r0 + 128; if (r1 > N) r1 = N;
  float s = 0.f, s2 = 0.f;
  for (int r = r0 + half; r < r1; r += 2){ float v = x[(size_t)r*NDIM + col]; s += v; s2 += v*v; }
  ls[t] = s; ls2[t] = s2; __syncthreads();
  if (t < 128){ atomicAdd(&sums[col], ls[t] + ls[t+128]); atomicAdd(&sums[128+col], ls2[t] + ls2[t+128]); }
}

// ============ block 0: BN1 finalize; blocks 1..: scan partials over cntT ============
__global__ __launch_bounds__(256) void k_bnf_scan(
    const float* __restrict__ sums, const float* __restrict__ g, const float* __restrict__ b_,
    float* __restrict__ scsh, int N,
    const int* __restrict__ in, int* __restrict__ bsum, int len){
  __shared__ int ls[256];
  int t = threadIdx.x, b = blockIdx.x;
  if (b == 0){
    if (t < 128){
      float mean = sums[t] / (float)N;
      float var  = sums[128+t] / (float)N - mean*mean;
      float rstd = rsqrtf(var + EPSV);
      float sc = g[t] * rstd;
      scsh[t] = sc; scsh[128+t] = b_[t] - mean*sc;
    }
    return;
  }
  b -= 1;
  int i = b*256 + t;
  ls[t] = (i < len) ? in[i] : 0; __syncthreads();
  for (int off = 128; off > 0; off >>= 1){
    if (t < off) ls[t] += ls[t + off];
    __syncthreads();
  }
  if (t == 0) bsum[b] = ls[0];
}

__global__ __launch_bounds__(128) void k_bn_final(const float* __restrict__ sums, const float* __restrict__ g,
                                                  const float* __restrict__ b, float* __restrict__ scsh, int N){
  int c = threadIdx.x;
  float mean = sums[c] / (float)N;
  float var  = sums[128+c] / (float)N - mean*mean;
  float rstd = rsqrtf(var + EPSV);
  float sc = g[c] * rstd;
  scsh[c] = sc; scsh[128+c] = b[c] - mean*sc;
}

__global__ __launch_bounds__(256) void k_scan_top(int* __restrict__ bsum, int nb, int* __restrict__ rowptr, int N, int E){
  __shared__ int ls[256];
  int t = threadIdx.x;
  int v = (t < nb) ? bsum[t] : 0; ls[t] = v; __syncthreads();
  for (int off = 1; off < 256; off <<= 1){
    int add = (t >= off) ? ls[t - off] : 0;
    __syncthreads();
    ls[t] += add;
    __syncthreads();
  }
  if (t < nb) bsum[t] = ls[t] - v;
  if (t == 0) rowptr[N] = E;
}

__global__ __launch_bounds__(256) void k_scan_down(const int* __restrict__ in, const int* __restrict__ bsum,
                                                   int* __restrict__ outp, int len){
  __shared__ int ls[256];
  int t = threadIdx.x; int i = blockIdx.x*256 + t;
  int v = (i < len) ? in[i] : 0; ls[t] = v; __syncthreads();
  for (int off = 1; off < 256; off <<= 1){
    int add = (t >= off) ? ls[t - off] : 0;
    __syncthreads();
    ls[t] += add;
    __syncthreads();
  }
  if (i < len) outp[i] = ls[t] - v + bsum[blockIdx.x];
}

// ============ fine sort within bucket: rowptr + csr_src (LDS atomics only) ============
__global__ __launch_bounds__(256) void k_finesort(const int2* __restrict__ ebuf, const int* __restrict__ scn,
                                                  int* __restrict__ rowptr, int* __restrict__ csr_src,
                                                  int B, int C, int N, int E){
  __shared__ int ls[256], cur[256];
  int b = blockIdx.x, t = threadIdx.x;
  int base = scn[b*C];
  int end  = (b == B-1) ? E : scn[(b+1)*C];
  int lo = b << 8;
  cur[t] = 0; __syncthreads();
  for (int e = base + t; e < end; e += 256) atomicAdd(&cur[ebuf[e].x - lo], 1);
  __syncthreads();
  int v = cur[t]; ls[t] = v; __syncthreads();
  for (int off = 1; off < 256; off <<= 1){
    int add = (t >= off) ? ls[t - off] : 0;
    __syncthreads();
    ls[t] += add;
    __syncthreads();
  }
  int excl = ls[t] - v;
  __syncthreads();
  cur[t] = excl;
  if (lo + t < N) rowptr[lo + t] = base + excl;
  __syncthreads();
  for (int e = base + t; e < end; e += 256){
    int2 p = ebuf[e];
    int slot = base + atomicAdd(&cur[p.x - lo], 1);
    csr_src[slot] = p.y;
  }
}

// ============ merged: bucket pass (first C blocks) + BN1-apply + QKV projection (MFMA) ============
// K is emitted as fp8-e4m3 (HAVE_FP8) to halve the sagg K-gather bytes.
__global__ __launch_bounds__(256) void k_qkv_bucket(
    const float* __restrict__ h, const float* __restrict__ scsh,
    const u16* __restrict__ WTq, const u16* __restrict__ WTk, const u16* __restrict__ WTv,
    u16* __restrict__ Q, u16* __restrict__ K, u16* __restrict__ V, int N,
    const int* __restrict__ src, const int* __restrict__ dst,
    const int* __restrict__ scn, int2* __restrict__ ebuf, int B, int C, int E){
  __shared__ u16 hn[64][136];
  __shared__ u16 ob[64][136];
  __shared__ int off[256];
  int b = blockIdx.x, t = threadIdx.x;
  if (b < C){
    off[t] = (t < B) ? scn[t*C + b] : 0;
    __syncthreads();
    int e0 = b * 4096;
    #pragma unroll
    for (int j = 0; j < 16; j++){
      int e = e0 + t + j*256;
      if (e < E){
        int d = dst[e], s = src[e];
        int slot = atomicAdd(&off[d >> 8], 1);
        ebuf[slot] = make_int2(d, s);
      }
    }
    return;
  }
  int r0 = (b - C) * 64;
  {
    int row = t >> 2, c0 = (t & 3) * 32; int rr = r0 + row;
    #pragma unroll
    for (int j = 0; j < 8; j++){
      int c = c0 + 4*j;
      float4 v = make_float4(0.f,0.f,0.f,0.f);
      if (rr < N) v = *(const float4*)(h + (size_t)rr*NDIM + c);
      us4 o;
      o.x = f2b(v.x * scsh[c]   + scsh[128+c]);
      o.y = f2b(v.y * scsh[c+1] + scsh[129+c]);
      o.z = f2b(v.z * scsh[c+2] + scsh[130+c]);
      o.w = f2b(v.w * scsh[c+3] + scsh[131+c]);
      *(us4*)&hn[row][c] = o;
    }
  }
  __syncthreads();
  int lane = t & 63, w = t >> 6;
  int lr = lane & 15, kg = lane >> 4;
  int srow = t >> 2, sc0 = (t & 3) * 32;
  f32x4 zero = {0.f,0.f,0.f,0.f};

  #define DO_PASS(WT, OUT, FIRST) { \
    f32x4 acc[2][4]; \
    _Pragma("unroll") for (int n = 0; n < 2; n++) _Pragma("unroll") for (int m = 0; m < 4; m++) acc[n][m] = zero; \
    gemm_tiles<2,4,4,128,136>(&hn[0][0], WT, lr, kg, w*32, acc); \
    if (!FIRST) __syncthreads(); \
    _Pragma("unroll") for (int n = 0; n < 2; n++){ \
      int col = w*32 + n*16 + lr; \
      _Pragma("unroll") for (int m = 0; m < 4; m++) \
        _Pragma("unroll") for (int r = 0; r < 4; r++) \
          ob[m*16 + kg*4 + r][col] = f2b(acc[n][m][r]); \
    } \
    __syncthreads(); \
    if (r0 + srow < N){ \
      u16* dp = OUT + (size_t)(r0 + srow)*NDIM + sc0; \
      _Pragma("unroll") for (int j = 0; j < 4; j++) \
        *(us8*)(dp + j*8) = *(const us8*)&ob[srow][sc0 + j*8]; \
    } }

  DO_PASS(WTq, Q, true)

  // K pass: GEMM -> ob(bf16) -> fp8 (or bf16 fallback) coalesced store
  {
    f32x4 acc[2][4];
    #pragma unroll
    for (int n = 0; n < 2; n++)
      #pragma unroll
      for (int m = 0; m < 4; m++) acc[n][m] = zero;
    gemm_tiles<2,4,4,128,136>(&hn[0][0], WTk, lr, kg, w*32, acc);
    __syncthreads();
    #pragma unroll
    for (int n = 0; n < 2; n++){
      int col = w*32 + n*16 + lr;
      #pragma unroll
      for (int m = 0; m < 4; m++)
        #pragma unroll
        for (int r = 0; r < 4; r++)
          ob[m*16 + kg*4 + r][col] = f2b(acc[n][m][r]);
    }
    __syncthreads();
    if (r0 + srow < N){
#if HAVE_FP8
      u8* dp = (u8*)K + (size_t)(r0 + srow)*NDIM + sc0;
      #pragma unroll
      for (int j = 0; j < 4; j++){
        us8 v = *(const us8*)&ob[srow][sc0 + 8*j];
        int w0 = __builtin_amdgcn_cvt_pk_fp8_f32(b2f(v[0]), b2f(v[1]), 0, false);
        w0     = __builtin_amdgcn_cvt_pk_fp8_f32(b2f(v[2]), b2f(v[3]), w0, true);
        int w1 = __builtin_amdgcn_cvt_pk_fp8_f32(b2f(v[4]), b2f(v[5]), 0, false);
        w1     = __builtin_amdgcn_cvt_pk_fp8_f32(b2f(v[6]), b2f(v[7]), w1, true);
        *(uint2*)(dp + 8*j) = make_uint2((unsigned)w0, (unsigned)w1);
      }
#else
      u16* dp = K + (size_t)(r0 + srow)*NDIM + sc0;
      #pragma unroll
      for (int j = 0; j < 4; j++)
        *(us8*)(dp + j*8) = *(const us8*)&ob[srow][sc0 + j*8];
#endif
    }
  }

  DO_PASS(WTv, V, false)
  #undef DO_PASS
}

// ============ fused edge phase: score + softmax + weighted V aggregation ============
// fp8 K gather (128 B/edge), bf16 V gather (256 B/edge). Next-window scalar index prefetch.
__global__ __launch_bounds__(256) void k_sagg(const int* __restrict__ rowptr, const int* __restrict__ csr_src,
                                              const u16* __restrict__ Q, const u16* __restrict__ K,
                                              const u16* __restrict__ V, u16* __restrict__ wV, int N){
  __shared__ float wx[4][64];
  int w = threadIdx.x >> 6, l = threadIdx.x & 63;
  int n = blockIdx.x*4 + w;
  if (n >= N) return;
  int j8 = l >> 3, hh = l & 7, d0 = l * 2;

  float qf[16];
  {
    const unsigned* qp = (const unsigned*)(Q + (size_t)n*NDIM + hh*16);
    #pragma unroll
    for (int t = 0; t < 8; t++){
      unsigned u = qp[t];
      qf[2*t]   = blo(u) * 0.25f;
      qf[2*t+1] = bhi(u) * 0.25f;
    }
  }

#if HAVE_FP8
  const u8* Kb = (const u8*)K;
  #define KDOT(p, sidx) { \
    uint4 kw = *(const uint4*)(Kb + (size_t)(sidx)*NDIM + (hh << 4)); \
    { f32x2 a_ = __builtin_amdgcn_cvt_pk_f32_fp8((int)kw.x, false); \
      f32x2 b_ = __builtin_amdgcn_cvt_pk_f32_fp8((int)kw.x, true); \
      p += qf[0]*a_.x + qf[1]*a_.y + qf[2]*b_.x + qf[3]*b_.y; } \
    { f32x2 a_ = __builtin_amdgcn_cvt_pk_f32_fp8((int)kw.y, false); \
      f32x2 b_ = __builtin_amdgcn_cvt_pk_f32_fp8((int)kw.y, true); \
      p += qf[4]*a_.x + qf[5]*a_.y + qf[6]*b_.x + qf[7]*b_.y; } \
    { f32x2 a_ = __builtin_amdgcn_cvt_pk_f32_fp8((int)kw.z, false); \
      f32x2 b_ = __builtin_amdgcn_cvt_pk_f32_fp8((int)kw.z, true); \
      p += qf[8]*a_.x + qf[9]*a_.y + qf[10]*b_.x + qf[11]*b_.y; } \
    { f32x2 a_ = __builtin_amdgcn_cvt_pk_f32_fp8((int)kw.w, false); \
      f32x2 b_ = __builtin_amdgcn_cvt_pk_f32_fp8((int)kw.w, true); \
      p += qf[12]*a_.x + qf[13]*a_.y + qf[14]*b_.x + qf[15]*b_.y; } }
#else
  #define KDOT(p, sidx) { \
    const unsigned* kp = (const unsigned*)(K + (size_t)(sidx)*NDIM + hh*16); \
    _Pragma("unroll") for (int t_ = 0; t_ < 8; t_++){ \
      unsigned u_ = kp[t_]; \
      p += qf[2*t_]*blo(u_) + qf[2*t_+1]*bhi(u_); } }
#endif

  int e0 = rowptr[n], e1 = rowptr[n+1];
  int e1s = __builtin_amdgcn_readfirstlane(e1);
  float ssum_l = 0.f;
  float a0 = 0.f, a1 = 0.f;
  int i = e0;
  int i0 = __builtin_amdgcn_readfirstlane(i);

  int sc[8];
  if (i + 8 <= e1){
    #pragma unroll
    for (int j = 0; j < 8; j++) sc[j] = csr_src[i0 + j];
  }

  for (; i + 8 <= e1; ){
    int inext = i + 8, i0n = i0 + 8;
    int sn[8];
    {
      int pb = (i0n + 8 <= e1s) ? i0n : i0;     // prefetch next window (or re-read current)
      #pragma unroll
      for (int j = 0; j < 8; j++) sn[j] = csr_src[pb + j];
    }
    unsigned vv0 = *(const unsigned*)(V + (size_t)sc[0]*NDIM + d0);
    unsigned vv1 = *(const unsigned*)(V + (size_t)sc[1]*NDIM + d0);
    unsigned vv2 = *(const unsigned*)(V + (size_t)sc[2]*NDIM + d0);
    unsigned vv3 = *(const unsigned*)(V + (size_t)sc[3]*NDIM + d0);
    unsigned vv4 = *(const unsigned*)(V + (size_t)sc[4]*NDIM + d0);
    unsigned vv5 = *(const unsigned*)(V + (size_t)sc[5]*NDIM + d0);
    unsigned vv6 = *(const unsigned*)(V + (size_t)sc[6]*NDIM + d0);
    unsigned vv7 = *(const unsigned*)(V + (size_t)sc[7]*NDIM + d0);
    int sidx = csr_src[i + j8];
    float p = 0.f;
    KDOT(p, sidx)
    p = fminf(5.f, fmaxf(-5.f, p));
    float wgt = __expf(p);
    ssum_l += wgt;
    wx[w][hh*8 + j8] = wgt;
    float4 wa = *(const float4*)&wx[w][j8*8];
    float4 wb = *(const float4*)&wx[w][j8*8 + 4];
    a0 += wa.x*blo(vv0) + wa.y*blo(vv1) + wa.z*blo(vv2) + wa.w*blo(vv3)
        + wb.x*blo(vv4) + wb.y*blo(vv5) + wb.z*blo(vv6) + wb.w*blo(vv7);
    a1 += wa.x*bhi(vv0) + wa.y*bhi(vv1) + wa.z*bhi(vv2) + wa.w*bhi(vv3)
        + wb.x*bhi(vv4) + wb.y*bhi(vv5) + wb.z*bhi(vv6) + wb.w*bhi(vv7);
    #pragma unroll
    for (int j = 0; j < 8; j++) sc[j] = sn[j];
    i = inext; i0 = i0n;
  }

  int rem = e1 - i;
  if (rem > 0){
    i0 = __builtin_amdgcn_readfirstlane(i);
    int s[8];
    #pragma unroll
    for (int j = 0; j < 8; j++) s[j] = csr_src[i0 + (j < rem ? j : 0)];
    unsigned vv[8];
    #pragma unroll
    for (int j = 0; j < 8; j++) vv[j] = *(const unsigned*)(V + (size_t)s[j]*NDIM + d0);
    int sidx = csr_src[i0 + (j8 < rem ? j8 : 0)];
    float p = 0.f;
    KDOT(p, sidx)
    p = fminf(5.f, fmaxf(-5.f, p));
    float wgt = (j8 < rem) ? __expf(p) : 0.f;
    ssum_l += wgt;
    wx[w][hh*8 + j8] = wgt;
    float4 wa = *(const float4*)&wx[w][j8*8];
    float4 wb = *(const float4*)&wx[w][j8*8 + 4];
    a0 += wa.x*blo(vv[0]) + wa.y*blo(vv[1]) + wa.z*blo(vv[2]) + wa.w*blo(vv[3])
        + wb.x*blo(vv[4]) + wb.y*blo(vv[5]) + wb.z*blo(vv[6]) + wb.w*blo(vv[7]);
    a1 += wa.x*bhi(vv[0]) + wa.y*bhi(vv[1]) + wa.z*bhi(vv[2]) + wa.w*bhi(vv[3])
        + wb.x*bhi(vv[4]) + wb.y*bhi(vv[5]) + wb.z*bhi(vv[6]) + wb.w*bhi(vv[7]);
  }
  #undef KDOT

  ssum_l += __shfl_xor(ssum_l, 8);
  ssum_l += __shfl_xor(ssum_l, 16);
  ssum_l += __shfl_xor(ssum_l, 32);
  float ssum = __shfl(ssum_l, j8);
  float inv = (e1 > e0) ? 1.f/ssum : 0.f;
  unsigned pk = (unsigned)f2b(a0*inv) | (((unsigned)f2b(a1*inv)) << 16);
  *(unsigned*)(wV + (size_t)n*NDIM + d0) = pk;
}

// ============ O-projection + residual (MFMA, 32-row tiles, coalesced epilogue) ============
__global__ __launch_bounds__(256) void k_h2(const u16* __restrict__ wV, const u16* __restrict__ WTo,
                                            const float* __restrict__ bo, const float* __restrict__ h,
                                            float* __restrict__ h2, int N){
  __shared__ u16 tw[32][136];
  __shared__ float ob[32][132];
  int t = threadIdx.x; int r0 = blockIdx.x * 32;
  int row = t >> 3, c0 = (t & 7) * 16;
  {
    int rr = r0 + row;
    us8 z = {0,0,0,0,0,0,0,0};
    const u16* sp = wV + (size_t)rr*NDIM + c0;
    *(us8*)&tw[row][c0]     = (rr < N) ? *(const us8*)sp       : z;
    *(us8*)&tw[row][c0 + 8] = (rr < N) ? *(const us8*)(sp + 8) : z;
  }
  __syncthreads();
  int lane = t & 63, w = t >> 6;
  int lr = lane & 15, kg = lane >> 4;
  f32x4 zero = {0.f,0.f,0.f,0.f};
  f32x4 acc[2][2];
  #pragma unroll
  for (int n = 0; n < 2; n++)
    #pragma unroll
    for (int m = 0; m < 2; m++) acc[n][m] = zero;
  gemm_tiles<2,2,4,128,136>(&tw[0][0], WTo, lr, kg, w*32, acc);
  #pragma unroll
  for (int n = 0; n < 2; n++){
    int col = w*32 + n*16 + lr;
    float bb = bo[col];
    #pragma unroll
    for (int m = 0; m < 2; m++)
      #pragma unroll
      for (int r = 0; r < 4; r++)
        ob[m*16 + kg*4 + r][col] = acc[n][m][r] + bb;
  }
  __syncthreads();
  if (r0 + row < N){
    const float* hp = h  + (size_t)(r0 + row)*NDIM + c0;
    float*       op = h2 + (size_t)(r0 + row)*NDIM + c0;
    #pragma unroll
    for (int j = 0; j < 4; j++){
      float4 hv = *(const float4*)(hp + 4*j);
      float4 o;
      o.x = ob[row][c0 + 4*j]     + hv.x;
      o.y = ob[row][c0 + 4*j + 1] + hv.y;
      o.z = ob[row][c0 + 4*j + 2] + hv.z;
      o.w = ob[row][c0 + 4*j + 3] + hv.w;
      *(float4*)(op + 4*j) = o;
    }
  }
}

// ============ BN2-apply + FFN + residual (MFMA, 32-row tiles, coalesced epilogue) ============
__global__ __launch_bounds__(256) void k_ffn(const float* __restrict__ h2, const float* __restrict__ scsh,
                                             const u16* __restrict__ WT1, const float* __restrict__ b1,
                                             const u16* __restrict__ WT2, const float* __restrict__ b2,
                                             float* __restrict__ out, int N){
  __shared__ u16 x[32][136];
  __shared__ u16 tt[32][264];          // reused as float [32][132] after GEMM2
  int t = threadIdx.x; int r0 = blockIdx.x * 32;
  int row = t >> 3, c0 = (t & 7) * 16;
  {
    int rr = r0 + row;
    #pragma unroll
    for (int j = 0; j < 4; j++){
      int c = c0 + 4*j;
      float4 v = make_float4(0.f,0.f,0.f,0.f);
      if (rr < N) v = *(const float4*)(h2 + (size_t)rr*NDIM + c);
      us4 o;
      o.x = f2b(v.x * scsh[c]   + scsh[128+c]);
      o.y = f2b(v.y * scsh[c+1] + scsh[129+c]);
      o.z = f2b(v.z * scsh[c+2] + scsh[130+c]);
      o.w = f2b(v.w * scsh[c+3] + scsh[131+c]);
      *(us4*)&x[row][c] = o;
    }
  }
  __syncthreads();
  int lane = t & 63, w = t >> 6;
  int lr = lane & 15, kg = lane >> 4;
  f32x4 zero = {0.f,0.f,0.f,0.f};
  {
    f32x4 a1[4][2];
    #pragma unroll
    for (int n = 0; n < 4; n++)
      #pragma unroll
      for (int m = 0; m < 2; m++) a1[n][m] = zero;
    gemm_tiles<4,2,4,128,136>(&x[0][0], WT1, lr, kg, w*64, a1);
    #pragma unroll
    for (int n = 0; n < 4; n++){
      int col = w*64 + n*16 + lr;
      float bb = b1[col];
      #pragma unroll
      for (int m = 0; m < 2; m++)
        #pragma unroll
        for (int r = 0; r < 4; r++)
          tt[m*16 + kg*4 + r][col] = f2b(fmaxf(a1[n][m][r] + bb, 0.f));
    }
  }
  __syncthreads();
  f32x4 a2[2][2];
  #pragma unroll
  for (int n = 0; n < 2; n++)
    #pragma unroll
    for (int m = 0; m < 2; m++) a2[n][m] = zero;
  gemm_tiles<2,2,8,256,264>(&tt[0][0], WT2, lr, kg, w*32, a2);
  __syncthreads();
  float* ob2 = (float*)&tt[0][0];       // [32][132] overlay
  #pragma unroll
  for (int n = 0; n < 2; n++){
    int col = w*32 + n*16 + lr;
    float bb = b2[col];
    #pragma unroll
    for (int m = 0; m < 2; m++)
      #pragma unroll
      for (int r = 0; r < 4; r++)
        ob2[(m*16 + kg*4 + r)*132 + col] = a2[n][m][r] + bb;
  }
  __syncthreads();
  if (r0 + row < N){
    const float* hp = h2  + (size_t)(r0 + row)*NDIM + c0;
    float*       op = out + (size_t)(r0 + row)*NDIM + c0;
    #pragma unroll
    for (int j = 0; j < 4; j++){
      float4 hv = *(const float4*)(hp + 4*j);
      float4 o;
      o.x = ob2[row*132 + c0 + 4*j]     + hv.x;
      o.y = ob2[row*132 + c0 + 4*j + 1] + hv.y;
      o.z = ob2[row*132 + c0 + 4*j + 2] + hv.z;
      o.w = ob2[row*132 + c0 + 4*j + 3] + hv.w;
      *(float4*)(op + 4*j) = o;
    }
  }
}

extern "C" void kernel_launch(void* const* d_in, const int* in_sizes, int n_in,
                              void* d_out, int out_size, void* d_ws, size_t ws_size,
                              hipStream_t stream) {
  const float* h    = (const float*)d_in[0];
  const int*   src  = (const int*)d_in[1];
  const int*   dst  = (const int*)d_in[2];
  const float* Wq   = (const float*)d_in[3];
  const float* Wk   = (const float*)d_in[4];
  const float* Wv   = (const float*)d_in[5];
  const float* Wo   = (const float*)d_in[6];
  const float* bo   = (const float*)d_in[7];
  const float* bn1g = (const float*)d_in[8];
  const float* bn1b = (const float*)d_in[9];
  const float* bn2g = (const float*)d_in[10];
  const float* bn2b = (const float*)d_in[11];
  const float* W1   = (const float*)d_in[12];
  const float* b1   = (const float*)d_in[13];
  const float* W2   = (const float*)d_in[14];
  const float* b2   = (const float*)d_in[15];
  float* out = (float*)d_out;

  int N = in_sizes[0] / NDIM;
  int E = in_sizes[1];
  size_t fN = (size_t)N * NDIM;

  int B   = (N + 255) >> 8;       // coarse buckets (256 nodes each), <= 256
  int C   = (E + 4095) >> 12;     // edge chunks (4096 edges each)
  int NB2 = B * C;
  int nb2 = (NB2 + 255) / 256;    // <= 256

  u16* Q  = (u16*)d_ws;
  u16* K  = Q + fN;               // fp8 path uses first fN BYTES of this 2*fN-byte slot
  u16* V  = K + fN;
  u16* wV = Q;                    // reuse: each wave reads Q[n] before writing wV[n]
  float* h2   = (float*)(V + fN);
  int2* ebuf  = (int2*)(h2 + fN);
  int* rowptr = (int*)(ebuf + E);
  int* bsum   = rowptr + (N + 1);
  int* cntT   = bsum + 256;
  int* scn    = cntT + NB2;
  int* csr_src= scn + NB2;
  float* sums1 = (float*)(csr_src + E);
  float* sums2 = sums1 + 256;
  float* scsh1 = sums2 + 256;
  float* scsh2 = scsh1 + 256;
  u16* wtq = (u16*)(scsh2 + 256);
  u16* wtk = wtq + NDIM*NDIM;
  u16* wtv = wtk + NDIM*NDIM;
  u16* wto = wtv + NDIM*NDIM;
  u16* wt1 = wto + NDIM*NDIM;
  u16* wt2 = wt1 + NDIM*2*NDIM;

  hipMemsetAsync(sums1, 0, 512 * sizeof(float), stream);   // sums1 + sums2

  int nBn = (N + 127) / 128;
  int nQ  = (N + 63) / 64;
  int n32 = (N + 31) / 32;

  k_pro<<<nBn + 32 + C, 256, 0, stream>>>(Wq, Wk, Wv, Wo, W1, W2,
                                          wtq, wtk, wtv, wto, wt1, wt2,
                                          h, sums1, dst, cntT, nBn, N, E, B, C);
  k_bnf_scan<<<1 + nb2, 256, 0, stream>>>(sums1, bn1g, bn1b, scsh1, N, cntT, bsum, NB2);
  k_scan_top<<<1, 256, 0, stream>>>(bsum, nb2, rowptr, N, E);
  k_scan_down<<<nb2, 256, 0, stream>>>(cntT, bsum, scn, NB2);

  k_qkv_bucket<<<C + nQ, 256, 0, stream>>>(h, scsh1, wtq, wtk, wtv, Q, K, V, N,
                                           src, dst, scn, ebuf, B, C, E);
  k_finesort<<<B, 256, 0, stream>>>(ebuf, scn, rowptr, csr_src, B, C, N, E);

  k_sagg<<<(N + 3)/4, 256, 0, stream>>>(rowptr, csr_src, Q, K, V, wV, N);

  k_h2<<<n32, 256, 0, stream>>>(wV, wto, bo, h, h2, N);
  k_bnstats<<<nBn, 256, 0, stream>>>(h2, sums2, N);
  k_bn_final<<<1, 128, 0, stream>>>(sums2, bn2g, bn2b, scsh2, N);
  k_ffn<<<n32, 256, 0, stream>>>(h2, scsh2, wt1, b1, wt2, b2, out, N);
}

// Round 13
// 228.954 us; speedup vs baseline: 2.9235x; 1.0003x over previous
//
#include <hip/hip_runtime.h>
#include <hip/hip_bf16.h>

#define NDIM 128
#define NHEAD 8
#define EPSV 1e-5f

#if defined(__has_builtin)
#  if __has_builtin(__builtin_amdgcn_cvt_pk_fp8_f32) && __has_builtin(__builtin_amdgcn_cvt_pk_f32_fp8)
#    define HAVE_FP8 1
#  else
#    define HAVE_FP8 0
#  endif
#else
#  define HAVE_FP8 0
#endif

typedef unsigned short u16;
typedef unsigned char u8;
using bf16x8 = __attribute__((ext_vector_type(8))) short;
using f32x4  = __attribute__((ext_vector_type(4))) float;
using f32x2  = __attribute__((ext_vector_type(2))) float;
using us8    = __attribute__((ext_vector_type(8))) unsigned short;
using us4    = __attribute__((ext_vector_type(4))) unsigned short;

__device__ __forceinline__ u16 f2b(float x){
  union { float f; unsigned u; } v; v.f = x;
  unsigned r = v.u + 0x7FFFu + ((v.u >> 16) & 1u);
  return (u16)(r >> 16);
}
__device__ __forceinline__ float b2f(u16 u){
  union { unsigned u; float f; } v; v.u = ((unsigned)u) << 16; return v.f;
}
__device__ __forceinline__ float blo(unsigned u){
  union { unsigned u; float f; } v; v.u = u << 16; return v.f;
}
__device__ __forceinline__ float bhi(unsigned u){
  union { unsigned u; float f; } v; v.u = u & 0xFFFF0000u; return v.f;
}
__device__ __forceinline__ f32x2 b2f2(unsigned u){
  f32x2 r; r.x = blo(u); r.y = bhi(u); return r;
}

// A-frag: lane provides A[lane%16][(lane/16)*8 + j]; B-frag: B[(lane/16)*8+j][lane%16]
// C/D: col = lane&15, row = (lane>>4)*4 + reg   (measured m89)
template<int NT, int MT, int KS, int WTLD, int XSTR>
__device__ __forceinline__ void gemm_tiles(const u16* X, const u16* __restrict__ WT,
                                           int lr, int kg, int colbase, f32x4 (&acc)[NT][MT]){
  #pragma unroll
  for (int ks = 0; ks < KS; ks++){
    bf16x8 a[MT];
    #pragma unroll
    for (int m = 0; m < MT; m++)
      a[m] = *(const bf16x8*)(X + (size_t)(m*16 + lr)*XSTR + ks*32 + kg*8);
    #pragma unroll
    for (int n = 0; n < NT; n++){
      int col = colbase + n*16 + lr;
      bf16x8 b = *(const bf16x8*)(WT + (size_t)col*WTLD + ks*32 + kg*8);
      #pragma unroll
      for (int m = 0; m < MT; m++)
        acc[n][m] = __builtin_amdgcn_mfma_f32_16x16x32_bf16(a[m], b, acc[n][m], 0, 0, 0);
    }
  }
}

// transpose one 64x64 tile of W (rows x cols, f32) into WT (cols x rows, bf16)
__device__ __forceinline__ void wconv_tile(const float* __restrict__ W, u16* __restrict__ WT,
                                           int rows, int cols, int tr, int tc, int t){
  __shared__ u16 T[64][66];
  int r0 = tr*64, c0 = tc*64;
  int r = t >> 2, cq = (t & 3) * 16;
  const float* src = W + (size_t)(r0 + r)*cols + c0 + cq;
  #pragma unroll
  for (int j = 0; j < 4; j++){
    float4 v = *(const float4*)(src + 4*j);
    us4 o; o.x = f2b(v.x); o.y = f2b(v.y); o.z = f2b(v.z); o.w = f2b(v.w);
    *(us4*)&T[r][cq + 4*j] = o;
  }
  __syncthreads();
  int c = t >> 2, rq = (t & 3) * 16;
  us8 o0, o1;
  #pragma unroll
  for (int j = 0; j < 8; j++){ o0[j] = T[rq + j][c]; o1[j] = T[rq + 8 + j][c]; }
  u16* dstp = WT + (size_t)(c0 + c)*rows + r0 + rq;
  *(us8*)dstp = o0;
  *(us8*)(dstp + 8) = o1;
}

// ============ pro: BN1 stats (nBn) + weight transpose (32) + coarse edge histogram (C chunks) ============
__global__ __launch_bounds__(256) void k_pro(
    const float* __restrict__ Wq, const float* __restrict__ Wk, const float* __restrict__ Wv,
    const float* __restrict__ Wo, const float* __restrict__ W1, const float* __restrict__ W2,
    u16* __restrict__ wtq, u16* __restrict__ wtk, u16* __restrict__ wtv,
    u16* __restrict__ wto, u16* __restrict__ wt1, u16* __restrict__ wt2,
    const float* __restrict__ h, float* __restrict__ sums,
    const int* __restrict__ dst, int* __restrict__ cntT,
    int nBn, int N, int E, int B, int C){
  __shared__ float ls[256], ls2[256];
  __shared__ int hist[256];
  int b = blockIdx.x, t = threadIdx.x;
  if (b < nBn){
    int col = t & 127, half = t >> 7;
    int r0 = b * 128; int r1 = r0 + 128; if (r1 > N) r1 = N;
    float s = 0.f, s2 = 0.f;
    for (int r = r0 + half; r < r1; r += 2){ float v = h[(size_t)r*NDIM + col]; s += v; s2 += v*v; }
    ls[t] = s; ls2[t] = s2; __syncthreads();
    if (t < 128){ atomicAdd(&sums[col], ls[t] + ls[t+128]); atomicAdd(&sums[128+col], ls2[t] + ls2[t+128]); }
    return;
  }
  b -= nBn;
  if (b < 16){
    const float* Ws[4] = {Wq, Wk, Wv, Wo};
    u16* Ts[4] = {wtq, wtk, wtv, wto};
    int wi = b >> 2, ti = b & 3;
    wconv_tile(Ws[wi], Ts[wi], 128, 128, ti >> 1, ti & 1, t);
    return;
  }
  if (b < 24){
    int ti = b - 16;
    wconv_tile(W1, wt1, 128, 256, ti >> 2, ti & 3, t);
    return;
  }
  if (b < 32){
    int ti = b - 24;
    wconv_tile(W2, wt2, 256, 128, ti & 3, ti >> 2, t);
    return;
  }
  int ci = b - 32;
  if (ci >= C) return;
  hist[t] = 0; __syncthreads();
  int e0 = ci * 4096;
  #pragma unroll
  for (int j = 0; j < 16; j++){
    int e = e0 + t + j*256;
    if (e < E) atomicAdd(&hist[dst[e] >> 8], 1);
  }
  __syncthreads();
  if (t < B) cntT[t*C + ci] = hist[t];
}

// ============ standalone BN stats over an fp32 matrix ============
__global__ __launch_bounds__(256) void k_bnstats(const float* __restrict__ x, float* __restrict__ sums, int N){
  __shared__ float ls[256], ls2[256];
  int b = blockIdx.x, t = threadIdx.x;
  int col = t & 127, half = t >> 7;
  int r0 = b * 128; int r1 = r0 + 128; if (r1 > N) r1 = N;
  float s = 0.f, s2 = 0.f;
  for (int r = r0 + half; r < r1; r += 2){ float v = x[(size_t)r*NDIM + col]; s += v; s2 += v*v; }
  ls[t] = s; ls2[t] = s2; __syncthreads();
  if (t < 128){ atomicAdd(&sums[col], ls[t] + ls[t+128]); atomicAdd(&sums[128+col], ls2[t] + ls2[t+128]); }
}

// ============ block 0: BN1 finalize; blocks 1..: scan partials over cntT ============
__global__ __launch_bounds__(256) void k_bnf_scan(
    const float* __restrict__ sums, const float* __restrict__ g, const float* __restrict__ b_,
    float* __restrict__ scsh, int N,
    const int* __restrict__ in, int* __restrict__ bsum, int len){
  __shared__ int ls[256];
  int t = threadIdx.x, b = blockIdx.x;
  if (b == 0){
    if (t < 128){
      float mean = sums[t] / (float)N;
      float var  = sums[128+t] / (float)N - mean*mean;
      float rstd = rsqrtf(var + EPSV);
      float sc = g[t] * rstd;
      scsh[t] = sc; scsh[128+t] = b_[t] - mean*sc;
    }
    return;
  }
  b -= 1;
  int i = b*256 + t;
  ls[t] = (i < len) ? in[i] : 0; __syncthreads();
  for (int off = 128; off > 0; off >>= 1){
    if (t < off) ls[t] += ls[t + off];
    __syncthreads();
  }
  if (t == 0) bsum[b] = ls[0];
}

__global__ __launch_bounds__(128) void k_bn_final(const float* __restrict__ sums, const float* __restrict__ g,
                                                  const float* __restrict__ b, float* __restrict__ scsh, int N){
  int c = threadIdx.x;
  float mean = sums[c] / (float)N;
  float var  = sums[128+c] / (float)N - mean*mean;
  float rstd = rsqrtf(var + EPSV);
  float sc = g[c] * rstd;
  scsh[c] = sc; scsh[128+c] = b[c] - mean*sc;
}

__global__ __launch_bounds__(256) void k_scan_top(int* __restrict__ bsum, int nb, int* __restrict__ rowptr, int N, int E){
  __shared__ int ls[256];
  int t = threadIdx.x;
  int v = (t < nb) ? bsum[t] : 0; ls[t] = v; __syncthreads();
  for (int off = 1; off < 256; off <<= 1){
    int add = (t >= off) ? ls[t - off] : 0;
    __syncthreads();
    ls[t] += add;
    __syncthreads();
  }
  if (t < nb) bsum[t] = ls[t] - v;
  if (t == 0) rowptr[N] = E;
}

__global__ __launch_bounds__(256) void k_scan_down(const int* __restrict__ in, const int* __restrict__ bsum,
                                                   int* __restrict__ outp, int len){
  __shared__ int ls[256];
  int t = threadIdx.x; int i = blockIdx.x*256 + t;
  int v = (i < len) ? in[i] : 0; ls[t] = v; __syncthreads();
  for (int off = 1; off < 256; off <<= 1){
    int add = (t >= off) ? ls[t - off] : 0;
    __syncthreads();
    ls[t] += add;
    __syncthreads();
  }
  if (i < len) outp[i] = ls[t] - v + bsum[blockIdx.x];
}

// ============ fine sort within bucket: rowptr + csr_src (LDS atomics only) ============
__global__ __launch_bounds__(256) void k_finesort(const int2* __restrict__ ebuf, const int* __restrict__ scn,
                                                  int* __restrict__ rowptr, int* __restrict__ csr_src,
                                                  int B, int C, int N, int E){
  __shared__ int ls[256], cur[256];
  int b = blockIdx.x, t = threadIdx.x;
  int base = scn[b*C];
  int end  = (b == B-1) ? E : scn[(b+1)*C];
  int lo = b << 8;
  cur[t] = 0; __syncthreads();
  for (int e = base + t; e < end; e += 256) atomicAdd(&cur[ebuf[e].x - lo], 1);
  __syncthreads();
  int v = cur[t]; ls[t] = v; __syncthreads();
  for (int off = 1; off < 256; off <<= 1){
    int add = (t >= off) ? ls[t - off] : 0;
    __syncthreads();
    ls[t] += add;
    __syncthreads();
  }
  int excl = ls[t] - v;
  __syncthreads();
  cur[t] = excl;
  if (lo + t < N) rowptr[lo + t] = base + excl;
  __syncthreads();
  for (int e = base + t; e < end; e += 256){
    int2 p = ebuf[e];
    int slot = base + atomicAdd(&cur[p.x - lo], 1);
    csr_src[slot] = p.y;
  }
}

// ============ merged: bucket pass (first C blocks) + BN1-apply + QKV projection (MFMA) ============
// K is emitted as fp8-e4m3 (HAVE_FP8) to halve the sagg K-gather bytes.
__global__ __launch_bounds__(256) void k_qkv_bucket(
    const float* __restrict__ h, const float* __restrict__ scsh,
    const u16* __restrict__ WTq, const u16* __restrict__ WTk, const u16* __restrict__ WTv,
    u16* __restrict__ Q, u16* __restrict__ K, u16* __restrict__ V, int N,
    const int* __restrict__ src, const int* __restrict__ dst,
    const int* __restrict__ scn, int2* __restrict__ ebuf, int B, int C, int E){
  __shared__ u16 hn[64][136];
  __shared__ u16 ob[64][136];
  __shared__ int off[256];
  int b = blockIdx.x, t = threadIdx.x;
  if (b < C){
    off[t] = (t < B) ? scn[t*C + b] : 0;
    __syncthreads();
    int e0 = b * 4096;
    #pragma unroll
    for (int j = 0; j < 16; j++){
      int e = e0 + t + j*256;
      if (e < E){
        int d = dst[e], s = src[e];
        int slot = atomicAdd(&off[d >> 8], 1);
        ebuf[slot] = make_int2(d, s);
      }
    }
    return;
  }
  int r0 = (b - C) * 64;
  {
    int row = t >> 2, c0 = (t & 3) * 32; int rr = r0 + row;
    #pragma unroll
    for (int j = 0; j < 8; j++){
      int c = c0 + 4*j;
      float4 v = make_float4(0.f,0.f,0.f,0.f);
      if (rr < N) v = *(const float4*)(h + (size_t)rr*NDIM + c);
      us4 o;
      o.x = f2b(v.x * scsh[c]   + scsh[128+c]);
      o.y = f2b(v.y * scsh[c+1] + scsh[129+c]);
      o.z = f2b(v.z * scsh[c+2] + scsh[130+c]);
      o.w = f2b(v.w * scsh[c+3] + scsh[131+c]);
      *(us4*)&hn[row][c] = o;
    }
  }
  __syncthreads();
  int lane = t & 63, w = t >> 6;
  int lr = lane & 15, kg = lane >> 4;
  int srow = t >> 2, sc0 = (t & 3) * 32;
  f32x4 zero = {0.f,0.f,0.f,0.f};

  #define DO_PASS(WT, OUT, FIRST) { \
    f32x4 acc[2][4]; \
    _Pragma("unroll") for (int n = 0; n < 2; n++) _Pragma("unroll") for (int m = 0; m < 4; m++) acc[n][m] = zero; \
    gemm_tiles<2,4,4,128,136>(&hn[0][0], WT, lr, kg, w*32, acc); \
    if (!FIRST) __syncthreads(); \
    _Pragma("unroll") for (int n = 0; n < 2; n++){ \
      int col = w*32 + n*16 + lr; \
      _Pragma("unroll") for (int m = 0; m < 4; m++) \
        _Pragma("unroll") for (int r = 0; r < 4; r++) \
          ob[m*16 + kg*4 + r][col] = f2b(acc[n][m][r]); \
    } \
    __syncthreads(); \
    if (r0 + srow < N){ \
      u16* dp = OUT + (size_t)(r0 + srow)*NDIM + sc0; \
      _Pragma("unroll") for (int j = 0; j < 4; j++) \
        *(us8*)(dp + j*8) = *(const us8*)&ob[srow][sc0 + j*8]; \
    } }

  DO_PASS(WTq, Q, true)

  // K pass: GEMM -> ob(bf16) -> fp8 (or bf16 fallback) coalesced store
  {
    f32x4 acc[2][4];
    #pragma unroll
    for (int n = 0; n < 2; n++)
      #pragma unroll
      for (int m = 0; m < 4; m++) acc[n][m] = zero;
    gemm_tiles<2,4,4,128,136>(&hn[0][0], WTk, lr, kg, w*32, acc);
    __syncthreads();
    #pragma unroll
    for (int n = 0; n < 2; n++){
      int col = w*32 + n*16 + lr;
      #pragma unroll
      for (int m = 0; m < 4; m++)
        #pragma unroll
        for (int r = 0; r < 4; r++)
          ob[m*16 + kg*4 + r][col] = f2b(acc[n][m][r]);
    }
    __syncthreads();
    if (r0 + srow < N){
#if HAVE_FP8
      u8* dp = (u8*)K + (size_t)(r0 + srow)*NDIM + sc0;
      #pragma unroll
      for (int j = 0; j < 4; j++){
        us8 v = *(const us8*)&ob[srow][sc0 + 8*j];
        int w0 = __builtin_amdgcn_cvt_pk_fp8_f32(b2f(v[0]), b2f(v[1]), 0, false);
        w0     = __builtin_amdgcn_cvt_pk_fp8_f32(b2f(v[2]), b2f(v[3]), w0, true);
        int w1 = __builtin_amdgcn_cvt_pk_fp8_f32(b2f(v[4]), b2f(v[5]), 0, false);
        w1     = __builtin_amdgcn_cvt_pk_fp8_f32(b2f(v[6]), b2f(v[7]), w1, true);
        *(uint2*)(dp + 8*j) = make_uint2((unsigned)w0, (unsigned)w1);
      }
#else
      u16* dp = K + (size_t)(r0 + srow)*NDIM + sc0;
      #pragma unroll
      for (int j = 0; j < 4; j++)
        *(us8*)(dp + j*8) = *(const us8*)&ob[srow][sc0 + j*8];
#endif
    }
  }

  DO_PASS(WTv, V, false)
  #undef DO_PASS
}

// ============ fused edge phase: score + softmax + weighted V aggregation ============
// Depth-2 software pipeline: window w+1's V rows and K row are issued before computing
// window w. Packed f32x2 math for dot and aggregation (v_pk_fma_f32).
__global__ __launch_bounds__(256) void k_sagg(const int* __restrict__ rowptr, const int* __restrict__ csr_src,
                                              const u16* __restrict__ Q, const u16* __restrict__ K,
                                              const u16* __restrict__ V, u16* __restrict__ wV, int N){
  __shared__ float wx[4][64];
  int w = threadIdx.x >> 6, l = threadIdx.x & 63;
  int n = blockIdx.x*4 + w;
  if (n >= N) return;
  int j8 = l >> 3, hh = l & 7, d0 = l * 2;

  f32x2 qf[8];
  {
    const unsigned* qp = (const unsigned*)(Q + (size_t)n*NDIM + hh*16);
    #pragma unroll
    for (int t = 0; t < 8; t++){
      unsigned u = qp[t];
      qf[t].x = blo(u) * 0.25f;
      qf[t].y = bhi(u) * 0.25f;
    }
  }

  int e0 = rowptr[n], e1 = rowptr[n+1];
  int i0 = __builtin_amdgcn_readfirstlane(e0);
  int deg = e1 - e0;
  int nw  = deg >> 3;
  int rem = deg & 7;

  float ssum_l = 0.f;
  f32x2 a01 = {0.f, 0.f};

#if HAVE_FP8
  const u8* Kb = (const u8*)K;
  uint4 kA, kB;
  #define KLOAD(dst_, sidx) dst_ = *(const uint4*)(Kb + (size_t)(sidx)*NDIM + (hh << 4));
  #define KDOTP(p, kk) { \
    f32x2 p2 = {0.f, 0.f}; \
    p2 += qf[0] * __builtin_amdgcn_cvt_pk_f32_fp8((int)kk.x, false); \
    p2 += qf[1] * __builtin_amdgcn_cvt_pk_f32_fp8((int)kk.x, true); \
    p2 += qf[2] * __builtin_amdgcn_cvt_pk_f32_fp8((int)kk.y, false); \
    p2 += qf[3] * __builtin_amdgcn_cvt_pk_f32_fp8((int)kk.y, true); \
    p2 += qf[4] * __builtin_amdgcn_cvt_pk_f32_fp8((int)kk.z, false); \
    p2 += qf[5] * __builtin_amdgcn_cvt_pk_f32_fp8((int)kk.z, true); \
    p2 += qf[6] * __builtin_amdgcn_cvt_pk_f32_fp8((int)kk.w, false); \
    p2 += qf[7] * __builtin_amdgcn_cvt_pk_f32_fp8((int)kk.w, true); \
    p = p2.x + p2.y; }
#else
  struct krow { uint4 lo, hi; };
  krow kA, kB;
  #define KLOAD(dst_, sidx) { \
    const uint4* kp_ = (const uint4*)(K + (size_t)(sidx)*NDIM + hh*16); \
    dst_.lo = kp_[0]; dst_.hi = kp_[1]; }
  #define KDOTP(p, kk) { \
    f32x2 p2 = {0.f, 0.f}; \
    p2 += qf[0] * b2f2(kk.lo.x); p2 += qf[1] * b2f2(kk.lo.y); \
    p2 += qf[2] * b2f2(kk.lo.z); p2 += qf[3] * b2f2(kk.lo.w); \
    p2 += qf[4] * b2f2(kk.hi.x); p2 += qf[5] * b2f2(kk.hi.y); \
    p2 += qf[6] * b2f2(kk.hi.z); p2 += qf[7] * b2f2(kk.hi.w); \
    p = p2.x + p2.y; }
#endif

  unsigned vvA[8], vvB[8];

  if (nw >= 1){
    int s0=csr_src[i0+0], s1=csr_src[i0+1], s2=csr_src[i0+2], s3=csr_src[i0+3];
    int s4=csr_src[i0+4], s5=csr_src[i0+5], s6=csr_src[i0+6], s7=csr_src[i0+7];
    vvA[0] = *(const unsigned*)(V + (size_t)s0*NDIM + d0);
    vvA[1] = *(const unsigned*)(V + (size_t)s1*NDIM + d0);
    vvA[2] = *(const unsigned*)(V + (size_t)s2*NDIM + d0);
    vvA[3] = *(const unsigned*)(V + (size_t)s3*NDIM + d0);
    vvA[4] = *(const unsigned*)(V + (size_t)s4*NDIM + d0);
    vvA[5] = *(const unsigned*)(V + (size_t)s5*NDIM + d0);
    vvA[6] = *(const unsigned*)(V + (size_t)s6*NDIM + d0);
    vvA[7] = *(const unsigned*)(V + (size_t)s7*NDIM + d0);
    int sidx = csr_src[e0 + j8];
    KLOAD(kA, sidx)
  }

  for (int wi = 0; wi < nw; wi++){
    if (wi + 1 < nw){
      int ib = i0 + wi*8 + 8;
      int s0=csr_src[ib+0], s1=csr_src[ib+1], s2=csr_src[ib+2], s3=csr_src[ib+3];
      int s4=csr_src[ib+4], s5=csr_src[ib+5], s6=csr_src[ib+6], s7=csr_src[ib+7];
      vvB[0] = *(const unsigned*)(V + (size_t)s0*NDIM + d0);
      vvB[1] = *(const unsigned*)(V + (size_t)s1*NDIM + d0);
      vvB[2] = *(const unsigned*)(V + (size_t)s2*NDIM + d0);
      vvB[3] = *(const unsigned*)(V + (size_t)s3*NDIM + d0);
      vvB[4] = *(const unsigned*)(V + (size_t)s4*NDIM + d0);
      vvB[5] = *(const unsigned*)(V + (size_t)s5*NDIM + d0);
      vvB[6] = *(const unsigned*)(V + (size_t)s6*NDIM + d0);
      vvB[7] = *(const unsigned*)(V + (size_t)s7*NDIM + d0);
      int sidx = csr_src[e0 + wi*8 + 8 + j8];
      KLOAD(kB, sidx)
    }
    float p;
    KDOTP(p, kA)
    p = fminf(5.f, fmaxf(-5.f, p));
    float wgt = __expf(p);
    ssum_l += wgt;
    wx[w][hh*8 + j8] = wgt;
    float4 wa = *(const float4*)&wx[w][j8*8];
    float4 wb = *(const float4*)&wx[w][j8*8 + 4];
    a01 += b2f2(vvA[0]) * wa.x;
    a01 += b2f2(vvA[1]) * wa.y;
    a01 += b2f2(vvA[2]) * wa.z;
    a01 += b2f2(vvA[3]) * wa.w;
    a01 += b2f2(vvA[4]) * wb.x;
    a01 += b2f2(vvA[5]) * wb.y;
    a01 += b2f2(vvA[6]) * wb.z;
    a01 += b2f2(vvA[7]) * wb.w;
    if (wi + 1 < nw){
      #pragma unroll
      for (int j = 0; j < 8; j++) vvA[j] = vvB[j];
      kA = kB;
    }
  }

  if (rem > 0){
    int i0t = i0 + nw*8;
    int s[8];
    #pragma unroll
    for (int j = 0; j < 8; j++) s[j] = csr_src[i0t + (j < rem ? j : 0)];
    unsigned vv[8];
    #pragma unroll
    for (int j = 0; j < 8; j++) vv[j] = *(const unsigned*)(V + (size_t)s[j]*NDIM + d0);
    int sidx = csr_src[i0t + (j8 < rem ? j8 : 0)];
#if HAVE_FP8
    uint4 kT;
#else
    krow kT;
#endif
    KLOAD(kT, sidx)
    float p;
    KDOTP(p, kT)
    p = fminf(5.f, fmaxf(-5.f, p));
    float wgt = (j8 < rem) ? __expf(p) : 0.f;
    ssum_l += wgt;
    wx[w][hh*8 + j8] = wgt;
    float4 wa = *(const float4*)&wx[w][j8*8];
    float4 wb = *(const float4*)&wx[w][j8*8 + 4];
    a01 += b2f2(vv[0]) * wa.x;
    a01 += b2f2(vv[1]) * wa.y;
    a01 += b2f2(vv[2]) * wa.z;
    a01 += b2f2(vv[3]) * wa.w;
    a01 += b2f2(vv[4]) * wb.x;
    a01 += b2f2(vv[5]) * wb.y;
    a01 += b2f2(vv[6]) * wb.z;
    a01 += b2f2(vv[7]) * wb.w;
  }
  #undef KLOAD
  #undef KDOTP

  ssum_l += __shfl_xor(ssum_l, 8);
  ssum_l += __shfl_xor(ssum_l, 16);
  ssum_l += __shfl_xor(ssum_l, 32);
  float ssum = __shfl(ssum_l, j8);
  float inv = (e1 > e0) ? 1.f/ssum : 0.f;
  unsigned pk = (unsigned)f2b(a01.x*inv) | (((unsigned)f2b(a01.y*inv)) << 16);
  *(unsigned*)(wV + (size_t)n*NDIM + d0) = pk;
}

// ============ O-projection + residual (MFMA, 32-row tiles, coalesced epilogue) ============
__global__ __launch_bounds__(256) void k_h2(const u16* __restrict__ wV, const u16* __restrict__ WTo,
                                            const float* __restrict__ bo, const float* __restrict__ h,
                                            float* __restrict__ h2, int N){
  __shared__ u16 tw[32][136];
  __shared__ float ob[32][132];
  int t = threadIdx.x; int r0 = blockIdx.x * 32;
  int row = t >> 3, c0 = (t & 7) * 16;
  {
    int rr = r0 + row;
    us8 z = {0,0,0,0,0,0,0,0};
    const u16* sp = wV + (size_t)rr*NDIM + c0;
    *(us8*)&tw[row][c0]     = (rr < N) ? *(const us8*)sp       : z;
    *(us8*)&tw[row][c0 + 8] = (rr < N) ? *(const us8*)(sp + 8) : z;
  }
  __syncthreads();
  int lane = t & 63, w = t >> 6;
  int lr = lane & 15, kg = lane >> 4;
  f32x4 zero = {0.f,0.f,0.f,0.f};
  f32x4 acc[2][2];
  #pragma unroll
  for (int n = 0; n < 2; n++)
    #pragma unroll
    for (int m = 0; m < 2; m++) acc[n][m] = zero;
  gemm_tiles<2,2,4,128,136>(&tw[0][0], WTo, lr, kg, w*32, acc);
  #pragma unroll
  for (int n = 0; n < 2; n++){
    int col = w*32 + n*16 + lr;
    float bb = bo[col];
    #pragma unroll
    for (int m = 0; m < 2; m++)
      #pragma unroll
      for (int r = 0; r < 4; r++)
        ob[m*16 + kg*4 + r][col] = acc[n][m][r] + bb;
  }
  __syncthreads();
  if (r0 + row < N){
    const float* hp = h  + (size_t)(r0 + row)*NDIM + c0;
    float*       op = h2 + (size_t)(r0 + row)*NDIM + c0;
    #pragma unroll
    for (int j = 0; j < 4; j++){
      float4 hv = *(const float4*)(hp + 4*j);
      float4 o;
      o.x = ob[row][c0 + 4*j]     + hv.x;
      o.y = ob[row][c0 + 4*j + 1] + hv.y;
      o.z = ob[row][c0 + 4*j + 2] + hv.z;
      o.w = ob[row][c0 + 4*j + 3] + hv.w;
      *(float4*)(op + 4*j) = o;
    }
  }
}

// ============ BN2-apply + FFN + residual (MFMA, 32-row tiles, coalesced epilogue) ============
__global__ __launch_bounds__(256) void k_ffn(const float* __restrict__ h2, const float* __restrict__ scsh,
                                             const u16* __restrict__ WT1, const float* __restrict__ b1,
                                             const u16* __restrict__ WT2, const float* __restrict__ b2,
                                             float* __restrict__ out, int N){
  __shared__ u16 x[32][136];
  __shared__ u16 tt[32][264];          // reused as float [32][132] after GEMM2
  int t = threadIdx.x; int r0 = blockIdx.x * 32;
  int row = t >> 3, c0 = (t & 7) * 16;
  {
    int rr = r0 + row;
    #pragma unroll
    for (int j = 0; j < 4; j++){
      int c = c0 + 4*j;
      float4 v = make_float4(0.f,0.f,0.f,0.f);
      if (rr < N) v = *(const float4*)(h2 + (size_t)rr*NDIM + c);
      us4 o;
      o.x = f2b(v.x * scsh[c]   + scsh[128+c]);
      o.y = f2b(v.y * scsh[c+1] + scsh[129+c]);
      o.z = f2b(v.z * scsh[c+2] + scsh[130+c]);
      o.w = f2b(v.w * scsh[c+3] + scsh[131+c]);
      *(us4*)&x[row][c] = o;
    }
  }
  __syncthreads();
  int lane = t & 63, w = t >> 6;
  int lr = lane & 15, kg = lane >> 4;
  f32x4 zero = {0.f,0.f,0.f,0.f};
  {
    f32x4 a1[4][2];
    #pragma unroll
    for (int n = 0; n < 4; n++)
      #pragma unroll
      for (int m = 0; m < 2; m++) a1[n][m] = zero;
    gemm_tiles<4,2,4,128,136>(&x[0][0], WT1, lr, kg, w*64, a1);
    #pragma unroll
    for (int n = 0; n < 4; n++){
      int col = w*64 + n*16 + lr;
      float bb = b1[col];
      #pragma unroll
      for (int m = 0; m < 2; m++)
        #pragma unroll
        for (int r = 0; r < 4; r++)
          tt[m*16 + kg*4 + r][col] = f2b(fmaxf(a1[n][m][r] + bb, 0.f));
    }
  }
  __syncthreads();
  f32x4 a2[2][2];
  #pragma unroll
  for (int n = 0; n < 2; n++)
    #pragma unroll
    for (int m = 0; m < 2; m++) a2[n][m] = zero;
  gemm_tiles<2,2,8,256,264>(&tt[0][0], WT2, lr, kg, w*32, a2);
  __syncthreads();
  float* ob2 = (float*)&tt[0][0];       // [32][132] overlay
  #pragma unroll
  for (int n = 0; n < 2; n++){
    int col = w*32 + n*16 + lr;
    float bb = b2[col];
    #pragma unroll
    for (int m = 0; m < 2; m++)
      #pragma unroll
      for (int r = 0; r < 4; r++)
        ob2[(m*16 + kg*4 + r)*132 + col] = a2[n][m][r] + bb;
  }
  __syncthreads();
  if (r0 + row < N){
    const float* hp = h2  + (size_t)(r0 + row)*NDIM + c0;
    float*       op = out + (size_t)(r0 + row)*NDIM + c0;
    #pragma unroll
    for (int j = 0; j < 4; j++){
      float4 hv = *(const float4*)(hp + 4*j);
      float4 o;
      o.x = ob2[row*132 + c0 + 4*j]     + hv.x;
      o.y = ob2[row*132 + c0 + 4*j + 1] + hv.y;
      o.z = ob2[row*132 + c0 + 4*j + 2] + hv.z;
      o.w = ob2[row*132 + c0 + 4*j + 3] + hv.w;
      *(float4*)(op + 4*j) = o;
    }
  }
}

extern "C" void kernel_launch(void* const* d_in, const int* in_sizes, int n_in,
                              void* d_out, int out_size, void* d_ws, size_t ws_size,
                              hipStream_t stream) {
  const float* h    = (const float*)d_in[0];
  const int*   src  = (const int*)d_in[1];
  const int*   dst  = (const int*)d_in[2];
  const float* Wq   = (const float*)d_in[3];
  const float* Wk   = (const float*)d_in[4];
  const float* Wv   = (const float*)d_in[5];
  const float* Wo   = (const float*)d_in[6];
  const float* bo   = (const float*)d_in[7];
  const float* bn1g = (const float*)d_in[8];
  const float* bn1b = (const float*)d_in[9];
  const float* bn2g = (const float*)d_in[10];
  const float* bn2b = (const float*)d_in[11];
  const float* W1   = (const float*)d_in[12];
  const float* b1   = (const float*)d_in[13];
  const float* W2   = (const float*)d_in[14];
  const float* b2   = (const float*)d_in[15];
  float* out = (float*)d_out;

  int N = in_sizes[0] / NDIM;
  int E = in_sizes[1];
  size_t fN = (size_t)N * NDIM;

  int B   = (N + 255) >> 8;       // coarse buckets (256 nodes each), <= 256
  int C   = (E + 4095) >> 12;     // edge chunks (4096 edges each)
  int NB2 = B * C;
  int nb2 = (NB2 + 255) / 256;    // <= 256

  u16* Q  = (u16*)d_ws;
  u16* K  = Q + fN;               // fp8 path uses first fN BYTES of this 2*fN-byte slot
  u16* V  = K + fN;
  u16* wV = Q;                    // reuse: each wave reads Q[n] before writing wV[n]
  float* h2   = (float*)(V + fN);
  int2* ebuf  = (int2*)(h2 + fN);
  int* rowptr = (int*)(ebuf + E);
  int* bsum   = rowptr + (N + 1);
  int* cntT   = bsum + 256;
  int* scn    = cntT + NB2;
  int* csr_src= scn + NB2;
  float* sums1 = (float*)(csr_src + E);
  float* sums2 = sums1 + 256;
  float* scsh1 = sums2 + 256;
  float* scsh2 = scsh1 + 256;
  u16* wtq = (u16*)(scsh2 + 256);
  u16* wtk = wtq + NDIM*NDIM;
  u16* wtv = wtk + NDIM*NDIM;
  u16* wto = wtv + NDIM*NDIM;
  u16* wt1 = wto + NDIM*NDIM;
  u16* wt2 = wt1 + NDIM*2*NDIM;

  hipMemsetAsync(sums1, 0, 512 * sizeof(float), stream);   // sums1 + sums2

  int nBn = (N + 127) / 128;
  int nQ  = (N + 63) / 64;
  int n32 = (N + 31) / 32;

  k_pro<<<nBn + 32 + C, 256, 0, stream>>>(Wq, Wk, Wv, Wo, W1, W2,
                                          wtq, wtk, wtv, wto, wt1, wt2,
                                          h, sums1, dst, cntT, nBn, N, E, B, C);
  k_bnf_scan<<<1 + nb2, 256, 0, stream>>>(sums1, bn1g, bn1b, scsh1, N, cntT, bsum, NB2);
  k_scan_top<<<1, 256, 0, stream>>>(bsum, nb2, rowptr, N, E);
  k_scan_down<<<nb2, 256, 0, stream>>>(cntT, bsum, scn, NB2);

  k_qkv_bucket<<<C + nQ, 256, 0, stream>>>(h, scsh1, wtq, wtk, wtv, Q, K, V, N,
                                           src, dst, scn, ebuf, B, C, E);
  k_finesort<<<B, 256, 0, stream>>>(ebuf, scn, rowptr, csr_src, B, C, N, E);

  k_sagg<<<(N + 3)/4, 256, 0, stream>>>(rowptr, csr_src, Q, K, V, wV, N);

  k_h2<<<n32, 256, 0, stream>>>(wV, wto, bo, h, h2, N);
  k_bnstats<<<nBn, 256, 0, stream>>>(h2, sums2, N);
  k_bn_final<<<1, 128, 0, stream>>>(sums2, bn2g, bn2b, scsh2, N);
  k_ffn<<<n32, 256, 0, stream>>>(h2, scsh2, wt1, b1, wt2, b2, out, N);
}